// Round 5
// baseline (2201.817 us; speedup 1.0000x reference)
//
#include <hip/hip_runtime.h>
#include <hip/hip_bf16.h>

#define WIDTH 1024
#define BATCH 8192

typedef __attribute__((ext_vector_type(8))) short short8;
typedef __attribute__((ext_vector_type(4))) float floatx4;

__device__ __forceinline__ void split_store(float v, __hip_bfloat16* hi, __hip_bfloat16* lo, long idx) {
    __hip_bfloat16 h = __float2bfloat16(v);
    hi[idx] = h;
    lo[idx] = __float2bfloat16(v - __bfloat162float(h));
}

// ---------------- transpose W_h (fp32 1024x1024) -> Wt_hi/lo[n][k] bf16 ----------------
__global__ __launch_bounds__(256) void transpose_k(
    const float* __restrict__ W,
    __hip_bfloat16* __restrict__ Wth, __hip_bfloat16* __restrict__ Wtl)
{
    __shared__ float t[32][33];
    const int tx = threadIdx.x & 31, ty = threadIdx.x >> 5;
    const int bx = blockIdx.x << 5, by = blockIdx.y << 5;
#pragma unroll
    for (int r = 0; r < 32; r += 8)
        t[ty + r][tx] = W[(long)(by + ty + r) * WIDTH + bx + tx];
    __syncthreads();
#pragma unroll
    for (int r = 0; r < 32; r += 8)
        split_store(t[tx][ty + r], Wth, Wtl, (long)(bx + ty + r) * WIDTH + by + tx);
}

// ---------------- layer 1 (per chunk, fp32 in): Y1 hi/lo, D1 hi/lo ----------------
__global__ __launch_bounds__(256) void prep_k(
    const float* __restrict__ state,   // chunk base
    const float* __restrict__ W_in,
    const float* __restrict__ b_in,
    __hip_bfloat16* __restrict__ Y1h, __hip_bfloat16* __restrict__ Y1l,
    __hip_bfloat16* __restrict__ D1h, __hip_bfloat16* __restrict__ D1l)
{
    const int b = blockIdx.x;
    const int j0 = threadIdx.x * 4;
    float s[7];
#pragma unroll
    for (int d = 0; d < 7; ++d) s[d] = state[b * 7 + d];
    float a[4];
#pragma unroll
    for (int q = 0; q < 4; ++q) a[q] = b_in[j0 + q];
    float w[7][4];
#pragma unroll
    for (int d = 0; d < 7; ++d)
#pragma unroll
        for (int q = 0; q < 4; ++q) {
            w[d][q] = W_in[d * WIDTH + j0 + q];
            a[q] += s[d] * w[d][q];
        }
    bool gp[4];
#pragma unroll
    for (int q = 0; q < 4; ++q) {
        gp[q] = a[q] > 0.f;
        split_store(gp[q] ? a[q] : 0.f, Y1h, Y1l, (long)b * WIDTH + j0 + q);
    }
#pragma unroll
    for (int d = 0; d < 7; ++d)
#pragma unroll
        for (int q = 0; q < 4; ++q)
            split_store(gp[q] ? w[d][q] : 0.f, D1h, D1l, ((long)b * 7 + d) * WIDTH + j0 + q);
}

// ---------------- split GEMM: out = epi(A @ W), W as Wt[n][k], both hi/lo ----------------
// acc = Ah*Bh + Ah*Bl + Al*Bh (fp32 MFMA accum). EPI 0: relu(x+bias). EPI 1: mask.
#define LDSS 40
template <int EPI>
__global__ __launch_bounds__(256) void gemm_k(
    const __hip_bfloat16* __restrict__ Ah, const __hip_bfloat16* __restrict__ Al,
    const __hip_bfloat16* __restrict__ Bh, const __hip_bfloat16* __restrict__ Bl,
    const float* __restrict__ bias,
    const __hip_bfloat16* __restrict__ mask,   // hi tensor of next-layer activation
    __hip_bfloat16* __restrict__ outh, __hip_bfloat16* __restrict__ outl)
{
    __shared__ __align__(16) short Ash[128 * LDSS], Asl[128 * LDSS];
    __shared__ __align__(16) short Bsh[128 * LDSS], Bsl[128 * LDSS];
    const int tid = threadIdx.x;
    const int lane = tid & 63;
    const int wv = tid >> 6;
    const int wm = wv >> 1, wn = wv & 1;
    const int bm = blockIdx.x, bn = blockIdx.y;

    const int srow = tid >> 2;          // 0..63
    const int scol = (tid & 3) << 3;    // 0,8,16,24
    const long aoff0 = (long)(bm * 128 + srow) * WIDTH + scol;
    const long aoff1 = aoff0 + 64l * WIDTH;
    const long boff0 = (long)(bn * 128 + srow) * WIDTH + scol;
    const long boff1 = boff0 + 64l * WIDTH;
    const short* pAh = (const short*)Ah;  const short* pAl = (const short*)Al;
    const short* pBh = (const short*)Bh;  const short* pBl = (const short*)Bl;

    floatx4 acc[4][4] = {};
    const int r = lane & 15;
    const int kq = (lane >> 4) << 3;

    for (int kt = 0; kt < WIDTH; kt += 32) {
        const short8 gah0 = *reinterpret_cast<const short8*>(pAh + aoff0 + kt);
        const short8 gah1 = *reinterpret_cast<const short8*>(pAh + aoff1 + kt);
        const short8 gal0 = *reinterpret_cast<const short8*>(pAl + aoff0 + kt);
        const short8 gal1 = *reinterpret_cast<const short8*>(pAl + aoff1 + kt);
        const short8 gbh0 = *reinterpret_cast<const short8*>(pBh + boff0 + kt);
        const short8 gbh1 = *reinterpret_cast<const short8*>(pBh + boff1 + kt);
        const short8 gbl0 = *reinterpret_cast<const short8*>(pBl + boff0 + kt);
        const short8 gbl1 = *reinterpret_cast<const short8*>(pBl + boff1 + kt);
        __syncthreads();
        *reinterpret_cast<short8*>(&Ash[srow * LDSS + scol]) = gah0;
        *reinterpret_cast<short8*>(&Ash[(64 + srow) * LDSS + scol]) = gah1;
        *reinterpret_cast<short8*>(&Asl[srow * LDSS + scol]) = gal0;
        *reinterpret_cast<short8*>(&Asl[(64 + srow) * LDSS + scol]) = gal1;
        *reinterpret_cast<short8*>(&Bsh[srow * LDSS + scol]) = gbh0;
        *reinterpret_cast<short8*>(&Bsh[(64 + srow) * LDSS + scol]) = gbh1;
        *reinterpret_cast<short8*>(&Bsl[srow * LDSS + scol]) = gbl0;
        *reinterpret_cast<short8*>(&Bsl[(64 + srow) * LDSS + scol]) = gbl1;
        __syncthreads();
        short8 afh[4], afl[4], bfh[4], bfl[4];
#pragma unroll
        for (int i = 0; i < 4; ++i) {
            const int ar = (wm * 64 + i * 16 + r) * LDSS + kq;
            afh[i] = *reinterpret_cast<const short8*>(&Ash[ar]);
            afl[i] = *reinterpret_cast<const short8*>(&Asl[ar]);
        }
#pragma unroll
        for (int j = 0; j < 4; ++j) {
            const int br = (wn * 64 + j * 16 + r) * LDSS + kq;
            bfh[j] = *reinterpret_cast<const short8*>(&Bsh[br]);
            bfl[j] = *reinterpret_cast<const short8*>(&Bsl[br]);
        }
#pragma unroll
        for (int i = 0; i < 4; ++i)
#pragma unroll
            for (int j = 0; j < 4; ++j) {
                acc[i][j] = __builtin_amdgcn_mfma_f32_16x16x32_bf16(afh[i], bfh[j], acc[i][j], 0, 0, 0);
                acc[i][j] = __builtin_amdgcn_mfma_f32_16x16x32_bf16(afh[i], bfl[j], acc[i][j], 0, 0, 0);
                acc[i][j] = __builtin_amdgcn_mfma_f32_16x16x32_bf16(afl[i], bfh[j], acc[i][j], 0, 0, 0);
            }
    }

    const int r4 = (lane >> 4) << 2;
#pragma unroll
    for (int i = 0; i < 4; ++i) {
#pragma unroll
        for (int j = 0; j < 4; ++j) {
            const int col = bn * 128 + wn * 64 + j * 16 + r;
#pragma unroll
            for (int rr = 0; rr < 4; ++rr) {
                const int row = bm * 128 + wm * 64 + i * 16 + r4 + rr;
                float v = acc[i][j][rr];
                if (EPI == 0) {
                    v += bias[col];
                    v = v > 0.f ? v : 0.f;
                } else {
                    const unsigned brow = (unsigned)row / 7u;
                    if (!(__bfloat162float(mask[(long)brow * WIDTH + col]) > 0.f)) v = 0.f;
                }
                split_store(v, outh, outl, (long)row * WIDTH + col);
            }
        }
    }
}

// ---------------- heads + 7x7 algebra (fp32 throughout) ----------------
__device__ __forceinline__ int midx(int rr, int cc) {
    const int i = rr - cc;
    return i * 7 - (i * (i - 1)) / 2 + cc;
}

__global__ __launch_bounds__(256) void head_k(
    const __hip_bfloat16* __restrict__ Y3h, const __hip_bfloat16* __restrict__ Y3l,
    const __hip_bfloat16* __restrict__ D3h, const __hip_bfloat16* __restrict__ D3l,
    const float* __restrict__ vel_g,   // global base
    const float* __restrict__ acc_g,
    const float* __restrict__ W_g,
    const float* __restrict__ W_ld,
    const float* __restrict__ b_ld,
    const float* __restrict__ W_lo,
    const float* __restrict__ b_lo,
    float* __restrict__ out,
    int b0)
{
    __shared__ float y3f[WIDTH];
    __shared__ float d3f[7 * 1028];
    __shared__ float lval[28];
    __shared__ int gpv[7];
    __shared__ float derl[29 * 7];
    __shared__ float Lm[49], Mm[49], dLt[49], uu[49];
    __shared__ float wvv[7], pv[7], Cv[7], Gv[7], tauv[7], vl[7], ac[7];

    const int bl = blockIdx.x, tid = threadIdx.x;
    const int b = b0 + bl;
    for (int i = tid; i < WIDTH; i += 256)
        y3f[i] = __bfloat162float(Y3h[(long)bl * WIDTH + i]) + __bfloat162float(Y3l[(long)bl * WIDTH + i]);
    for (int i = tid; i < 7 * WIDTH; i += 256) {
        const int d = i >> 10, c = i & 1023;
        const long g = ((long)bl * 7 + d) * WIDTH + c;
        d3f[d * 1028 + c] = __bfloat162float(D3h[g]) + __bfloat162float(D3l[g]);
    }
    if (tid < 7) {
        vl[tid] = vel_g[b * 7 + tid];
        ac[tid] = acc_g[b * 7 + tid];
    }
    __syncthreads();

    if (tid < 28) {
        float s = 0.f;
        if (tid < 7) {
            for (int i = 0; i < WIDTH; ++i) s += y3f[i] * W_ld[i * 7 + tid];
            s += b_ld[tid];
            gpv[tid] = s > 0.f;
            lval[tid] = s > 0.f ? s : 0.f;
        } else {
            const int k = tid - 7;
            for (int i = 0; i < WIDTH; ++i) s += y3f[i] * W_lo[i * 21 + k];
            lval[tid] = s + b_lo[k];
        }
    }
    __syncthreads();

    if (tid < 203) {
        const int m = tid / 7, d = tid % 7;
        float s = 0.f;
        if (m < 7) {
            for (int i = 0; i < WIDTH; ++i) s += d3f[d * 1028 + i] * W_ld[i * 7 + m];
            if (!gpv[m]) s = 0.f;
        } else if (m < 28) {
            const int k = m - 7;
            for (int i = 0; i < WIDTH; ++i) s += d3f[d * 1028 + i] * W_lo[i * 21 + k];
        } else {
            for (int i = 0; i < WIDTH; ++i) s += d3f[d * 1028 + i] * W_g[i];
        }
        derl[m * 7 + d] = s;
    }
    __syncthreads();

    if (tid < 49) {
        const int rr = tid / 7, cc = tid % 7;
        Lm[tid] = (rr >= cc) ? lval[midx(rr, cc)] : 0.f;
    }
    __syncthreads();
    if (tid < 49) {
        const int rr = tid / 7, cc = tid % 7;
        float s = 0.f;
        for (int k = 0; k < 7; ++k) s += Lm[rr * 7 + k] * Lm[cc * 7 + k];
        if (rr == cc) s += 1e-5f;
        Mm[tid] = s;
        float t = 0.f;
        if (rr >= cc) {
            const int m = midx(rr, cc);
            for (int d = 0; d < 7; ++d) t += derl[m * 7 + d] * vl[d];
        }
        dLt[tid] = t;
        float u = 0.f;
        for (int r2 = cc; r2 < 7; ++r2) u += vl[r2] * derl[midx(r2, cc) * 7 + rr];
        uu[tid] = u;
    } else if (tid >= 64 && tid < 71) {
        const int j = tid - 64;
        float s = 0.f;
        for (int r2 = 0; r2 < 7; ++r2) s += Lm[r2 * 7 + j] * vl[r2];
        wvv[j] = s;
    }
    __syncthreads();
    if (tid < 7) {
        float s = 0.f;
        for (int r2 = 0; r2 < 7; ++r2) s += dLt[r2 * 7 + tid] * vl[r2];
        pv[tid] = s;
    }
    __syncthreads();
    if (tid < 7) {
        float s = 0.f, q = 0.f, md = 0.f;
        for (int c = 0; c < 7; ++c) {
            s += Lm[tid * 7 + c] * pv[c] + dLt[tid * 7 + c] * wvv[c];
            q += uu[tid * 7 + c] * wvv[c];
            md += Mm[tid * 7 + c] * ac[c];
        }
        Cv[tid] = s - q;
        Gv[tid] = derl[28 * 7 + tid];
        tauv[tid] = md + Cv[tid] + Gv[tid];
    }
    __syncthreads();
    if (tid < 49) out[57344 + (long)b * 49 + tid] = Mm[tid];
    if (tid < 7) {
        out[(long)b * 7 + tid] = tauv[tid];
        out[458752 + (long)b * 7 + tid] = Cv[tid];
        out[516096 + (long)b * 7 + tid] = Gv[tid];
    }
}

extern "C" void kernel_launch(void* const* d_in, const int* in_sizes, int n_in,
                              void* d_out, int out_size, void* d_ws, size_t ws_size,
                              hipStream_t stream)
{
    const float* state = (const float*)d_in[0];
    const float* vel   = (const float*)d_in[1];
    const float* accel = (const float*)d_in[2];
    const float* W_in  = (const float*)d_in[3];
    const float* b_in  = (const float*)d_in[4];
    const float* W_h   = (const float*)d_in[5];
    const float* b_h   = (const float*)d_in[6];
    const float* W_g   = (const float*)d_in[7];
    /* d_in[8] = b_g unused (V never output; derV unaffected by bias) */
    const float* W_ld  = (const float*)d_in[9];
    const float* b_ld  = (const float*)d_in[10];
    const float* W_lo  = (const float*)d_in[11];
    const float* b_lo  = (const float*)d_in[12];
    float* outp = (float*)d_out;

    char* ws = (char*)d_ws;
    __hip_bfloat16* Wth = (__hip_bfloat16*)ws; ws += (size_t)WIDTH * WIDTH * 2;
    __hip_bfloat16* Wtl = (__hip_bfloat16*)ws; ws += (size_t)WIDTH * WIDTH * 2;
    const size_t fixed = (size_t)(ws - (char*)d_ws);

    // per-chunk: 4 Y bufs (CH*2048 B each) + 4 D bufs (CH*14336 B each) = CH*65536 B
    int CH = 128;
    for (int cand = 8192; cand >= 128; cand >>= 1) {
        size_t need = fixed + (size_t)cand * 65536;
        if (need <= ws_size) { CH = cand; break; }
    }
    const int NCH = BATCH / CH;

    const size_t YB = (size_t)CH * WIDTH * 2;
    const size_t DB = (size_t)CH * 7 * WIDTH * 2;
    __hip_bfloat16* Yah = (__hip_bfloat16*)ws; ws += YB;
    __hip_bfloat16* Yal = (__hip_bfloat16*)ws; ws += YB;
    __hip_bfloat16* Ybh = (__hip_bfloat16*)ws; ws += YB;
    __hip_bfloat16* Ybl = (__hip_bfloat16*)ws; ws += YB;
    __hip_bfloat16* Dah = (__hip_bfloat16*)ws; ws += DB;
    __hip_bfloat16* Dal = (__hip_bfloat16*)ws; ws += DB;
    __hip_bfloat16* Dbh = (__hip_bfloat16*)ws; ws += DB;
    __hip_bfloat16* Dbl = (__hip_bfloat16*)ws; ws += DB;

    transpose_k<<<dim3(32, 32), dim3(256), 0, stream>>>(W_h, Wth, Wtl);

    for (int c = 0; c < NCH; ++c) {
        prep_k<<<dim3(CH), dim3(256), 0, stream>>>(state + (size_t)c * CH * 7, W_in, b_in,
                                                   Yah, Yal, Dah, Dal);
        gemm_k<0><<<dim3(CH / 128, 8), dim3(256), 0, stream>>>(
            Yah, Yal, Wth, Wtl, b_h, nullptr, Ybh, Ybl);                       // Y2
        gemm_k<1><<<dim3(CH * 7 / 128, 8), dim3(256), 0, stream>>>(
            Dah, Dal, Wth, Wtl, nullptr, Ybh, Dbh, Dbl);                       // D2 (mask Y2)
        gemm_k<0><<<dim3(CH / 128, 8), dim3(256), 0, stream>>>(
            Ybh, Ybl, Wth, Wtl, b_h, nullptr, Yah, Yal);                       // Y3
        gemm_k<1><<<dim3(CH * 7 / 128, 8), dim3(256), 0, stream>>>(
            Dbh, Dbl, Wth, Wtl, nullptr, Yah, Dah, Dal);                       // D3 (mask Y3)
        head_k<<<dim3(CH), dim3(256), 0, stream>>>(
            Yah, Yal, Dah, Dal, vel, accel, W_g, W_ld, b_ld, W_lo, b_lo, outp, c * CH);
    }
    (void)in_sizes; (void)n_in; (void)out_size;
}

// Round 6
// 1539.339 us; speedup vs baseline: 1.4304x; 1.4304x over previous
//
#include <hip/hip_runtime.h>
#include <hip/hip_bf16.h>

#define WIDTH 1024
#define BATCH 8192

typedef __attribute__((ext_vector_type(8))) short short8;
typedef __attribute__((ext_vector_type(4))) float floatx4;

__device__ __forceinline__ void split_store(float v, __hip_bfloat16* hi, __hip_bfloat16* lo, long idx) {
    __hip_bfloat16 h = __float2bfloat16(v);
    hi[idx] = h;
    lo[idx] = __float2bfloat16(v - __bfloat162float(h));
}

// ---------------- transpose W_h (fp32 1024x1024) -> Wt_hi/lo[n][k] bf16 ----------------
__global__ __launch_bounds__(256) void transpose_k(
    const float* __restrict__ W,
    __hip_bfloat16* __restrict__ Wth, __hip_bfloat16* __restrict__ Wtl)
{
    __shared__ float t[32][33];
    const int tx = threadIdx.x & 31, ty = threadIdx.x >> 5;
    const int bx = blockIdx.x << 5, by = blockIdx.y << 5;
#pragma unroll
    for (int r = 0; r < 32; r += 8)
        t[ty + r][tx] = W[(long)(by + ty + r) * WIDTH + bx + tx];
    __syncthreads();
#pragma unroll
    for (int r = 0; r < 32; r += 8)
        split_store(t[tx][ty + r], Wth, Wtl, (long)(bx + ty + r) * WIDTH + by + tx);
}

// ---------------- pack head weights: Wcat[32][1024] hi/lo; rows 0-6 W_ld, 7-27 W_lo, 28 W_g, 29-31 zero ----
__global__ __launch_bounds__(256) void buildwcat_k(
    const float* __restrict__ W_ld, const float* __restrict__ W_lo,
    const float* __restrict__ W_g,
    __hip_bfloat16* __restrict__ Wch, __hip_bfloat16* __restrict__ Wcl)
{
    const int idx = blockIdx.x * 256 + threadIdx.x;   // 32*1024
    const int n = idx >> 10, k = idx & 1023;
    float v = 0.f;
    if (n < 7)       v = W_ld[k * 7 + n];
    else if (n < 28) v = W_lo[k * 21 + (n - 7)];
    else if (n == 28) v = W_g[k];
    split_store(v, Wch, Wcl, idx);
}

// ---------------- layer 1 (per chunk, fp32 in): Y1 hi/lo, D1 hi/lo ----------------
__global__ __launch_bounds__(256) void prep_k(
    const float* __restrict__ state,
    const float* __restrict__ W_in,
    const float* __restrict__ b_in,
    __hip_bfloat16* __restrict__ Y1h, __hip_bfloat16* __restrict__ Y1l,
    __hip_bfloat16* __restrict__ D1h, __hip_bfloat16* __restrict__ D1l)
{
    const int b = blockIdx.x;
    const int j0 = threadIdx.x * 4;
    float s[7];
#pragma unroll
    for (int d = 0; d < 7; ++d) s[d] = state[b * 7 + d];
    float a[4];
#pragma unroll
    for (int q = 0; q < 4; ++q) a[q] = b_in[j0 + q];
    float w[7][4];
#pragma unroll
    for (int d = 0; d < 7; ++d)
#pragma unroll
        for (int q = 0; q < 4; ++q) {
            w[d][q] = W_in[d * WIDTH + j0 + q];
            a[q] += s[d] * w[d][q];
        }
    bool gp[4];
#pragma unroll
    for (int q = 0; q < 4; ++q) {
        gp[q] = a[q] > 0.f;
        split_store(gp[q] ? a[q] : 0.f, Y1h, Y1l, (long)b * WIDTH + j0 + q);
    }
#pragma unroll
    for (int d = 0; d < 7; ++d)
#pragma unroll
        for (int q = 0; q < 4; ++q)
            split_store(gp[q] ? w[d][q] : 0.f, D1h, D1l, ((long)b * 7 + d) * WIDTH + j0 + q);
}

// ---------------- split GEMM 128x128: out = epi(A @ W) ----------------
#define LDSS 40
template <int EPI>
__global__ __launch_bounds__(256) void gemm_k(
    const __hip_bfloat16* __restrict__ Ah, const __hip_bfloat16* __restrict__ Al,
    const __hip_bfloat16* __restrict__ Bh, const __hip_bfloat16* __restrict__ Bl,
    const float* __restrict__ bias,
    const __hip_bfloat16* __restrict__ mask,
    __hip_bfloat16* __restrict__ outh, __hip_bfloat16* __restrict__ outl)
{
    __shared__ __align__(16) short Ash[128 * LDSS], Asl[128 * LDSS];
    __shared__ __align__(16) short Bsh[128 * LDSS], Bsl[128 * LDSS];
    const int tid = threadIdx.x;
    const int lane = tid & 63;
    const int wv = tid >> 6;
    const int wm = wv >> 1, wn = wv & 1;
    const int bm = blockIdx.x, bn = blockIdx.y;

    const int srow = tid >> 2;
    const int scol = (tid & 3) << 3;
    const long aoff0 = (long)(bm * 128 + srow) * WIDTH + scol;
    const long aoff1 = aoff0 + 64l * WIDTH;
    const long boff0 = (long)(bn * 128 + srow) * WIDTH + scol;
    const long boff1 = boff0 + 64l * WIDTH;
    const short* pAh = (const short*)Ah;  const short* pAl = (const short*)Al;
    const short* pBh = (const short*)Bh;  const short* pBl = (const short*)Bl;

    floatx4 acc[4][4] = {};
    const int r = lane & 15;
    const int kq = (lane >> 4) << 3;

    for (int kt = 0; kt < WIDTH; kt += 32) {
        const short8 gah0 = *reinterpret_cast<const short8*>(pAh + aoff0 + kt);
        const short8 gah1 = *reinterpret_cast<const short8*>(pAh + aoff1 + kt);
        const short8 gal0 = *reinterpret_cast<const short8*>(pAl + aoff0 + kt);
        const short8 gal1 = *reinterpret_cast<const short8*>(pAl + aoff1 + kt);
        const short8 gbh0 = *reinterpret_cast<const short8*>(pBh + boff0 + kt);
        const short8 gbh1 = *reinterpret_cast<const short8*>(pBh + boff1 + kt);
        const short8 gbl0 = *reinterpret_cast<const short8*>(pBl + boff0 + kt);
        const short8 gbl1 = *reinterpret_cast<const short8*>(pBl + boff1 + kt);
        __syncthreads();
        *reinterpret_cast<short8*>(&Ash[srow * LDSS + scol]) = gah0;
        *reinterpret_cast<short8*>(&Ash[(64 + srow) * LDSS + scol]) = gah1;
        *reinterpret_cast<short8*>(&Asl[srow * LDSS + scol]) = gal0;
        *reinterpret_cast<short8*>(&Asl[(64 + srow) * LDSS + scol]) = gal1;
        *reinterpret_cast<short8*>(&Bsh[srow * LDSS + scol]) = gbh0;
        *reinterpret_cast<short8*>(&Bsh[(64 + srow) * LDSS + scol]) = gbh1;
        *reinterpret_cast<short8*>(&Bsl[srow * LDSS + scol]) = gbl0;
        *reinterpret_cast<short8*>(&Bsl[(64 + srow) * LDSS + scol]) = gbl1;
        __syncthreads();
        short8 afh[4], afl[4], bfh[4], bfl[4];
#pragma unroll
        for (int i = 0; i < 4; ++i) {
            const int ar = (wm * 64 + i * 16 + r) * LDSS + kq;
            afh[i] = *reinterpret_cast<const short8*>(&Ash[ar]);
            afl[i] = *reinterpret_cast<const short8*>(&Asl[ar]);
        }
#pragma unroll
        for (int j = 0; j < 4; ++j) {
            const int br = (wn * 64 + j * 16 + r) * LDSS + kq;
            bfh[j] = *reinterpret_cast<const short8*>(&Bsh[br]);
            bfl[j] = *reinterpret_cast<const short8*>(&Bsl[br]);
        }
#pragma unroll
        for (int i = 0; i < 4; ++i)
#pragma unroll
            for (int j = 0; j < 4; ++j) {
                acc[i][j] = __builtin_amdgcn_mfma_f32_16x16x32_bf16(afh[i], bfh[j], acc[i][j], 0, 0, 0);
                acc[i][j] = __builtin_amdgcn_mfma_f32_16x16x32_bf16(afh[i], bfl[j], acc[i][j], 0, 0, 0);
                acc[i][j] = __builtin_amdgcn_mfma_f32_16x16x32_bf16(afl[i], bfh[j], acc[i][j], 0, 0, 0);
            }
    }

    const int r4 = (lane >> 4) << 2;
#pragma unroll
    for (int i = 0; i < 4; ++i) {
#pragma unroll
        for (int j = 0; j < 4; ++j) {
            const int col = bn * 128 + wn * 64 + j * 16 + r;
#pragma unroll
            for (int rr = 0; rr < 4; ++rr) {
                const int row = bm * 128 + wm * 64 + i * 16 + r4 + rr;
                float v = acc[i][j][rr];
                if (EPI == 0) {
                    v += bias[col];
                    v = v > 0.f ? v : 0.f;
                } else {
                    const unsigned brow = (unsigned)row / 7u;
                    if (!(__bfloat162float(mask[(long)brow * WIDTH + col]) > 0.f)) v = 0.f;
                }
                split_store(v, outh, outl, (long)row * WIDTH + col);
            }
        }
    }
}

// ---------------- head-projection GEMM 128x32: P[row][32] = A @ Wcat^T (fp32 raw) ----------------
__global__ __launch_bounds__(256) void gemm_head(
    const __hip_bfloat16* __restrict__ Ah, const __hip_bfloat16* __restrict__ Al,
    const __hip_bfloat16* __restrict__ Bh, const __hip_bfloat16* __restrict__ Bl, // Wcat[32][1024]
    float* __restrict__ P)
{
    __shared__ __align__(16) short Ash[128 * LDSS], Asl[128 * LDSS];
    __shared__ __align__(16) short Bsh[32 * LDSS], Bsl[32 * LDSS];
    const int tid = threadIdx.x;
    const int lane = tid & 63;
    const int wv = tid >> 6;
    const int bm = blockIdx.x;

    const int srow = tid >> 2;
    const int scol = (tid & 3) << 3;
    const long aoff0 = (long)(bm * 128 + srow) * WIDTH + scol;
    const long aoff1 = aoff0 + 64l * WIDTH;
    const long boff  = (long)srow * WIDTH + scol;    // rows 0..31 for tid<128
    const short* pAh = (const short*)Ah;  const short* pAl = (const short*)Al;
    const short* pBh = (const short*)Bh;  const short* pBl = (const short*)Bl;

    floatx4 acc[2][2] = {};
    const int r = lane & 15;
    const int kq = (lane >> 4) << 3;

    for (int kt = 0; kt < WIDTH; kt += 32) {
        const short8 gah0 = *reinterpret_cast<const short8*>(pAh + aoff0 + kt);
        const short8 gah1 = *reinterpret_cast<const short8*>(pAh + aoff1 + kt);
        const short8 gal0 = *reinterpret_cast<const short8*>(pAl + aoff0 + kt);
        const short8 gal1 = *reinterpret_cast<const short8*>(pAl + aoff1 + kt);
        short8 gbh, gbl;
        if (tid < 128) {
            gbh = *reinterpret_cast<const short8*>(pBh + boff + kt);
            gbl = *reinterpret_cast<const short8*>(pBl + boff + kt);
        }
        __syncthreads();
        *reinterpret_cast<short8*>(&Ash[srow * LDSS + scol]) = gah0;
        *reinterpret_cast<short8*>(&Ash[(64 + srow) * LDSS + scol]) = gah1;
        *reinterpret_cast<short8*>(&Asl[srow * LDSS + scol]) = gal0;
        *reinterpret_cast<short8*>(&Asl[(64 + srow) * LDSS + scol]) = gal1;
        if (tid < 128) {
            *reinterpret_cast<short8*>(&Bsh[srow * LDSS + scol]) = gbh;
            *reinterpret_cast<short8*>(&Bsl[srow * LDSS + scol]) = gbl;
        }
        __syncthreads();
        short8 afh[2], afl[2], bfh[2], bfl[2];
#pragma unroll
        for (int i = 0; i < 2; ++i) {
            const int ar = (wv * 32 + i * 16 + r) * LDSS + kq;
            afh[i] = *reinterpret_cast<const short8*>(&Ash[ar]);
            afl[i] = *reinterpret_cast<const short8*>(&Asl[ar]);
        }
#pragma unroll
        for (int j = 0; j < 2; ++j) {
            const int br = (j * 16 + r) * LDSS + kq;
            bfh[j] = *reinterpret_cast<const short8*>(&Bsh[br]);
            bfl[j] = *reinterpret_cast<const short8*>(&Bsl[br]);
        }
#pragma unroll
        for (int i = 0; i < 2; ++i)
#pragma unroll
            for (int j = 0; j < 2; ++j) {
                acc[i][j] = __builtin_amdgcn_mfma_f32_16x16x32_bf16(afh[i], bfh[j], acc[i][j], 0, 0, 0);
                acc[i][j] = __builtin_amdgcn_mfma_f32_16x16x32_bf16(afh[i], bfl[j], acc[i][j], 0, 0, 0);
                acc[i][j] = __builtin_amdgcn_mfma_f32_16x16x32_bf16(afl[i], bfh[j], acc[i][j], 0, 0, 0);
            }
    }

    const int r4 = (lane >> 4) << 2;
#pragma unroll
    for (int i = 0; i < 2; ++i)
#pragma unroll
        for (int j = 0; j < 2; ++j) {
            const int col = j * 16 + r;
#pragma unroll
            for (int rr = 0; rr < 4; ++rr) {
                const int row = bm * 128 + wv * 32 + i * 16 + r4 + rr;
                P[(long)row * 32 + col] = acc[i][j][rr];
            }
        }
}

// ---------------- finalize: 7x7 algebra from projections (64 threads/sample) ----------------
__device__ __forceinline__ int midx(int rr, int cc) {
    const int i = rr - cc;
    return i * 7 - (i * (i - 1)) / 2 + cc;
}

__global__ __launch_bounds__(64) void finalize_k(
    const float* __restrict__ PY,     // [CH][32] raw Y3 head dots
    const float* __restrict__ PD,     // [CH*7][32] raw D3 head dots
    const float* __restrict__ vel_g,  // global base
    const float* __restrict__ acc_g,
    const float* __restrict__ b_ld,
    const float* __restrict__ b_lo,
    float* __restrict__ out,
    int b0)
{
    __shared__ float lval[28];
    __shared__ int gpv[7];
    __shared__ float derl[29 * 7];
    __shared__ float Lm[49], Mm[49], dLt[49], uu[49];
    __shared__ float wvv[7], pv[7], Cv[7], Gv[7], tauv[7], vl[7], ac[7];

    const int bl = blockIdx.x, tid = threadIdx.x;
    const int b = b0 + bl;
    if (tid < 28) {
        float s = PY[(long)bl * 32 + tid];
        if (tid < 7) {
            s += b_ld[tid];
            gpv[tid] = s > 0.f;
            lval[tid] = s > 0.f ? s : 0.f;
        } else {
            lval[tid] = s + b_lo[tid - 7];
        }
    }
    if (tid >= 28 && tid < 35) {
        vl[tid - 28] = vel_g[b * 7 + tid - 28];
        ac[tid - 28] = acc_g[b * 7 + tid - 28];
    }
    __syncthreads();
    for (int idx = tid; idx < 203; idx += 64) {
        const int m = idx / 7, d = idx % 7;
        float v = PD[((long)bl * 7 + d) * 32 + m];
        if (m < 7 && !gpv[m]) v = 0.f;
        derl[m * 7 + d] = v;
    }
    __syncthreads();
    if (tid < 49) {
        const int rr = tid / 7, cc = tid % 7;
        Lm[tid] = (rr >= cc) ? lval[midx(rr, cc)] : 0.f;
    }
    __syncthreads();
    if (tid < 49) {
        const int rr = tid / 7, cc = tid % 7;
        float s = 0.f;
        for (int k = 0; k < 7; ++k) s += Lm[rr * 7 + k] * Lm[cc * 7 + k];
        if (rr == cc) s += 1e-5f;
        Mm[tid] = s;
        float t = 0.f;
        if (rr >= cc) {
            const int m = midx(rr, cc);
            for (int d = 0; d < 7; ++d) t += derl[m * 7 + d] * vl[d];
        }
        dLt[tid] = t;
        float u = 0.f;
        for (int r2 = cc; r2 < 7; ++r2) u += vl[r2] * derl[midx(r2, cc) * 7 + rr];
        uu[tid] = u;
    } else if (tid >= 49 && tid < 56) {
        const int j = tid - 49;
        float s = 0.f;
        for (int r2 = 0; r2 < 7; ++r2) s += Lm[r2 * 7 + j] * vl[r2];
        wvv[j] = s;
    }
    __syncthreads();
    if (tid < 7) {
        float s = 0.f;
        for (int r2 = 0; r2 < 7; ++r2) s += dLt[r2 * 7 + tid] * vl[r2];
        pv[tid] = s;
    }
    __syncthreads();
    if (tid < 7) {
        float s = 0.f, q = 0.f, md = 0.f;
        for (int c = 0; c < 7; ++c) {
            s += Lm[tid * 7 + c] * pv[c] + dLt[tid * 7 + c] * wvv[c];
            q += uu[tid * 7 + c] * wvv[c];
            md += Mm[tid * 7 + c] * ac[c];
        }
        Cv[tid] = s - q;
        Gv[tid] = derl[28 * 7 + tid];
        tauv[tid] = md + Cv[tid] + Gv[tid];
    }
    __syncthreads();
    if (tid < 49) out[57344 + (long)b * 49 + tid] = Mm[tid];
    if (tid < 7) {
        out[(long)b * 7 + tid] = tauv[tid];
        out[458752 + (long)b * 7 + tid] = Cv[tid];
        out[516096 + (long)b * 7 + tid] = Gv[tid];
    }
}

extern "C" void kernel_launch(void* const* d_in, const int* in_sizes, int n_in,
                              void* d_out, int out_size, void* d_ws, size_t ws_size,
                              hipStream_t stream)
{
    const float* state = (const float*)d_in[0];
    const float* vel   = (const float*)d_in[1];
    const float* accel = (const float*)d_in[2];
    const float* W_in  = (const float*)d_in[3];
    const float* b_in  = (const float*)d_in[4];
    const float* W_h   = (const float*)d_in[5];
    const float* b_h   = (const float*)d_in[6];
    const float* W_g   = (const float*)d_in[7];
    /* d_in[8] = b_g unused */
    const float* W_ld  = (const float*)d_in[9];
    const float* b_ld  = (const float*)d_in[10];
    const float* W_lo  = (const float*)d_in[11];
    const float* b_lo  = (const float*)d_in[12];
    float* outp = (float*)d_out;

    char* ws = (char*)d_ws;
    __hip_bfloat16* Wth = (__hip_bfloat16*)ws; ws += (size_t)WIDTH * WIDTH * 2;
    __hip_bfloat16* Wtl = (__hip_bfloat16*)ws; ws += (size_t)WIDTH * WIDTH * 2;
    __hip_bfloat16* Wch = (__hip_bfloat16*)ws; ws += 32 * WIDTH * 2;
    __hip_bfloat16* Wcl = (__hip_bfloat16*)ws; ws += 32 * WIDTH * 2;
    const size_t fixed = (size_t)(ws - (char*)d_ws);

    // per-chunk: 4 Y (CH*2048 B) + 4 D (CH*14336 B) + PY (CH*128 B) + PD (CH*896 B)
    int CH = 128;
    for (int cand = 8192; cand >= 128; cand >>= 1) {
        size_t need = fixed + (size_t)cand * (65536 + 1024);
        if (need <= ws_size) { CH = cand; break; }
    }
    const int NCH = BATCH / CH;

    const size_t YB = (size_t)CH * WIDTH * 2;
    const size_t DB = (size_t)CH * 7 * WIDTH * 2;
    __hip_bfloat16* Yah = (__hip_bfloat16*)ws; ws += YB;
    __hip_bfloat16* Yal = (__hip_bfloat16*)ws; ws += YB;
    __hip_bfloat16* Ybh = (__hip_bfloat16*)ws; ws += YB;
    __hip_bfloat16* Ybl = (__hip_bfloat16*)ws; ws += YB;
    __hip_bfloat16* Dah = (__hip_bfloat16*)ws; ws += DB;
    __hip_bfloat16* Dal = (__hip_bfloat16*)ws; ws += DB;
    __hip_bfloat16* Dbh = (__hip_bfloat16*)ws; ws += DB;
    __hip_bfloat16* Dbl = (__hip_bfloat16*)ws; ws += DB;
    float* PY = (float*)ws; ws += (size_t)CH * 32 * 4;
    float* PD = (float*)ws; ws += (size_t)CH * 7 * 32 * 4;

    transpose_k<<<dim3(32, 32), dim3(256), 0, stream>>>(W_h, Wth, Wtl);
    buildwcat_k<<<dim3(128), dim3(256), 0, stream>>>(W_ld, W_lo, W_g, Wch, Wcl);

    for (int c = 0; c < NCH; ++c) {
        prep_k<<<dim3(CH), dim3(256), 0, stream>>>(state + (size_t)c * CH * 7, W_in, b_in,
                                                   Yah, Yal, Dah, Dal);
        gemm_k<0><<<dim3(CH / 128, 8), dim3(256), 0, stream>>>(
            Yah, Yal, Wth, Wtl, b_h, nullptr, Ybh, Ybl);                       // Y2
        gemm_k<1><<<dim3(CH * 7 / 128, 8), dim3(256), 0, stream>>>(
            Dah, Dal, Wth, Wtl, nullptr, Ybh, Dbh, Dbl);                       // D2 (mask Y2)
        gemm_k<0><<<dim3(CH / 128, 8), dim3(256), 0, stream>>>(
            Ybh, Ybl, Wth, Wtl, b_h, nullptr, Yah, Yal);                       // Y3
        gemm_k<1><<<dim3(CH * 7 / 128, 8), dim3(256), 0, stream>>>(
            Dbh, Dbl, Wth, Wtl, nullptr, Yah, Dah, Dal);                       // D3 (mask Y3)
        gemm_head<<<dim3(CH / 128), dim3(256), 0, stream>>>(Yah, Yal, Wch, Wcl, PY);
        gemm_head<<<dim3(CH * 7 / 128), dim3(256), 0, stream>>>(Dah, Dal, Wch, Wcl, PD);
        finalize_k<<<dim3(CH), dim3(64), 0, stream>>>(PY, PD, vel, accel, b_ld, b_lo,
                                                      outp, c * CH);
    }
    (void)in_sizes; (void)n_in; (void)out_size;
}

// Round 7
// 1435.280 us; speedup vs baseline: 1.5341x; 1.0725x over previous
//
#include <hip/hip_runtime.h>
#include <hip/hip_bf16.h>

#define WIDTH 1024
#define BATCH 8192

typedef __attribute__((ext_vector_type(8))) short short8;
typedef __attribute__((ext_vector_type(4))) float floatx4;

typedef __attribute__((address_space(1))) void gvoid;
typedef __attribute__((address_space(3))) void lvoid;

__device__ __forceinline__ void async_copy16(const void* g, void* l) {
    __builtin_amdgcn_global_load_lds((gvoid*)g, (lvoid*)l, 16, 0, 0);
}

__device__ __forceinline__ void split_store(float v, __hip_bfloat16* hi, __hip_bfloat16* lo, long idx) {
    __hip_bfloat16 h = __float2bfloat16(v);
    hi[idx] = h;
    lo[idx] = __float2bfloat16(v - __bfloat162float(h));
}

// ---------------- transpose W_h (fp32 1024x1024) -> Wt_hi/lo[n][k] bf16 ----------------
__global__ __launch_bounds__(256) void transpose_k(
    const float* __restrict__ W,
    __hip_bfloat16* __restrict__ Wth, __hip_bfloat16* __restrict__ Wtl)
{
    __shared__ float t[32][33];
    const int tx = threadIdx.x & 31, ty = threadIdx.x >> 5;
    const int bx = blockIdx.x << 5, by = blockIdx.y << 5;
#pragma unroll
    for (int r = 0; r < 32; r += 8)
        t[ty + r][tx] = W[(long)(by + ty + r) * WIDTH + bx + tx];
    __syncthreads();
#pragma unroll
    for (int r = 0; r < 32; r += 8)
        split_store(t[tx][ty + r], Wth, Wtl, (long)(bx + ty + r) * WIDTH + by + tx);
}

// ---------------- pack head weights: Wcat[32][1024] hi/lo ----------------
__global__ __launch_bounds__(256) void buildwcat_k(
    const float* __restrict__ W_ld, const float* __restrict__ W_lo,
    const float* __restrict__ W_g,
    __hip_bfloat16* __restrict__ Wch, __hip_bfloat16* __restrict__ Wcl)
{
    const int idx = blockIdx.x * 256 + threadIdx.x;   // 32*1024
    const int n = idx >> 10, k = idx & 1023;
    float v = 0.f;
    if (n < 7)       v = W_ld[k * 7 + n];
    else if (n < 28) v = W_lo[k * 21 + (n - 7)];
    else if (n == 28) v = W_g[k];
    split_store(v, Wch, Wcl, idx);
}

// ---------------- layer 1 (per chunk, fp32 in): Y1 hi/lo, D1 hi/lo ----------------
__global__ __launch_bounds__(256) void prep_k(
    const float* __restrict__ state,
    const float* __restrict__ W_in,
    const float* __restrict__ b_in,
    __hip_bfloat16* __restrict__ Y1h, __hip_bfloat16* __restrict__ Y1l,
    __hip_bfloat16* __restrict__ D1h, __hip_bfloat16* __restrict__ D1l)
{
    const int b = blockIdx.x;
    const int j0 = threadIdx.x * 4;
    float s[7];
#pragma unroll
    for (int d = 0; d < 7; ++d) s[d] = state[b * 7 + d];
    float a[4];
#pragma unroll
    for (int q = 0; q < 4; ++q) a[q] = b_in[j0 + q];
    float w[7][4];
#pragma unroll
    for (int d = 0; d < 7; ++d)
#pragma unroll
        for (int q = 0; q < 4; ++q) {
            w[d][q] = W_in[d * WIDTH + j0 + q];
            a[q] += s[d] * w[d][q];
        }
    bool gp[4];
#pragma unroll
    for (int q = 0; q < 4; ++q) {
        gp[q] = a[q] > 0.f;
        split_store(gp[q] ? a[q] : 0.f, Y1h, Y1l, (long)b * WIDTH + j0 + q);
    }
#pragma unroll
    for (int d = 0; d < 7; ++d)
#pragma unroll
        for (int q = 0; q < 4; ++q)
            split_store(gp[q] ? w[d][q] : 0.f, D1h, D1l, ((long)b * 7 + d) * WIDTH + j0 + q);
}

// ---------------- split GEMM 128x128: out = epi(A @ W), async LDS staging ----------------
// Unpadded stride 32 (required: global_load_lds dest is wave-uniform base + lane*16).
template <int EPI>
__global__ __launch_bounds__(256) void gemm_k(
    const __hip_bfloat16* __restrict__ Ah, const __hip_bfloat16* __restrict__ Al,
    const __hip_bfloat16* __restrict__ Bh, const __hip_bfloat16* __restrict__ Bl,
    const float* __restrict__ bias,
    const __hip_bfloat16* __restrict__ mask,
    __hip_bfloat16* __restrict__ outh, __hip_bfloat16* __restrict__ outl)
{
    __shared__ __align__(16) short Ash[128 * 32], Asl[128 * 32];
    __shared__ __align__(16) short Bsh[128 * 32], Bsl[128 * 32];
    const int tid = threadIdx.x;
    const int lane = tid & 63;
    const int wv = tid >> 6;
    const int wm = wv >> 1, wn = wv & 1;
    const int bm = blockIdx.x, bn = blockIdx.y;

    const int srow = tid >> 2;          // 0..63
    const int scol = (tid & 3) << 3;    // 0,8,16,24
    const short* pAh = (const short*)Ah + (long)(bm * 128 + srow) * WIDTH + scol;
    const short* pAl = (const short*)Al + (long)(bm * 128 + srow) * WIDTH + scol;
    const short* pBh = (const short*)Bh + (long)(bn * 128 + srow) * WIDTH + scol;
    const short* pBl = (const short*)Bl + (long)(bn * 128 + srow) * WIDTH + scol;
    const long half = 64l * WIDTH;

    floatx4 acc[4][4] = {};
    const int r = lane & 15;
    const int kq = (lane >> 4) << 3;

    for (int kt = 0; kt < WIDTH; kt += 32) {
        __syncthreads();   // prior iteration's fragment reads complete
        async_copy16(pAh + kt,        Ash + wv * 512);
        async_copy16(pAh + half + kt, Ash + 2048 + wv * 512);
        async_copy16(pAl + kt,        Asl + wv * 512);
        async_copy16(pAl + half + kt, Asl + 2048 + wv * 512);
        async_copy16(pBh + kt,        Bsh + wv * 512);
        async_copy16(pBh + half + kt, Bsh + 2048 + wv * 512);
        async_copy16(pBl + kt,        Bsl + wv * 512);
        async_copy16(pBl + half + kt, Bsl + 2048 + wv * 512);
        __syncthreads();   // staging complete (vmcnt drained at barrier)
        short8 afh[4], afl[4], bfh[4], bfl[4];
#pragma unroll
        for (int i = 0; i < 4; ++i) {
            const int ar = (wm * 64 + i * 16 + r) * 32 + kq;
            afh[i] = *reinterpret_cast<const short8*>(&Ash[ar]);
            afl[i] = *reinterpret_cast<const short8*>(&Asl[ar]);
        }
#pragma unroll
        for (int j = 0; j < 4; ++j) {
            const int br = (wn * 64 + j * 16 + r) * 32 + kq;
            bfh[j] = *reinterpret_cast<const short8*>(&Bsh[br]);
            bfl[j] = *reinterpret_cast<const short8*>(&Bsl[br]);
        }
#pragma unroll
        for (int i = 0; i < 4; ++i)
#pragma unroll
            for (int j = 0; j < 4; ++j) {
                acc[i][j] = __builtin_amdgcn_mfma_f32_16x16x32_bf16(afh[i], bfh[j], acc[i][j], 0, 0, 0);
                acc[i][j] = __builtin_amdgcn_mfma_f32_16x16x32_bf16(afh[i], bfl[j], acc[i][j], 0, 0, 0);
                acc[i][j] = __builtin_amdgcn_mfma_f32_16x16x32_bf16(afl[i], bfh[j], acc[i][j], 0, 0, 0);
            }
    }

    const int r4 = (lane >> 4) << 2;
#pragma unroll
    for (int i = 0; i < 4; ++i) {
#pragma unroll
        for (int j = 0; j < 4; ++j) {
            const int col = bn * 128 + wn * 64 + j * 16 + r;
#pragma unroll
            for (int rr = 0; rr < 4; ++rr) {
                const int row = bm * 128 + wm * 64 + i * 16 + r4 + rr;
                float v = acc[i][j][rr];
                if (EPI == 0) {
                    v += bias[col];
                    v = v > 0.f ? v : 0.f;
                } else {
                    const unsigned brow = (unsigned)row / 7u;
                    if (!(__bfloat162float(mask[(long)brow * WIDTH + col]) > 0.f)) v = 0.f;
                }
                split_store(v, outh, outl, (long)row * WIDTH + col);
            }
        }
    }
}

// ---------------- head-projection GEMM 128x32: P[row][32] = A @ Wcat^T ----------------
__global__ __launch_bounds__(256) void gemm_head(
    const __hip_bfloat16* __restrict__ Ah, const __hip_bfloat16* __restrict__ Al,
    const __hip_bfloat16* __restrict__ Bh, const __hip_bfloat16* __restrict__ Bl, // Wcat[32][1024]
    float* __restrict__ P)
{
    __shared__ __align__(16) short Ash[128 * 32], Asl[128 * 32];
    __shared__ __align__(16) short Bsh[32 * 32], Bsl[32 * 32];
    const int tid = threadIdx.x;
    const int lane = tid & 63;
    const int wv = tid >> 6;
    const int bm = blockIdx.x;

    const int srow = tid >> 2;
    const int scol = (tid & 3) << 3;
    const short* pAh = (const short*)Ah + (long)(bm * 128 + srow) * WIDTH + scol;
    const short* pAl = (const short*)Al + (long)(bm * 128 + srow) * WIDTH + scol;
    const long boff = (long)srow * WIDTH + scol;    // rows 0..31 for tid<128
    const short* pBh = (const short*)Bh;  const short* pBl = (const short*)Bl;
    const long half = 64l * WIDTH;

    floatx4 acc[2][2] = {};
    const int r = lane & 15;
    const int kq = (lane >> 4) << 3;

    for (int kt = 0; kt < WIDTH; kt += 32) {
        short8 gbh, gbl;
        if (tid < 128) {
            gbh = *reinterpret_cast<const short8*>(pBh + boff + kt);
            gbl = *reinterpret_cast<const short8*>(pBl + boff + kt);
        }
        __syncthreads();
        async_copy16(pAh + kt,        Ash + wv * 512);
        async_copy16(pAh + half + kt, Ash + 2048 + wv * 512);
        async_copy16(pAl + kt,        Asl + wv * 512);
        async_copy16(pAl + half + kt, Asl + 2048 + wv * 512);
        if (tid < 128) {
            *reinterpret_cast<short8*>(&Bsh[srow * 32 + scol]) = gbh;
            *reinterpret_cast<short8*>(&Bsl[srow * 32 + scol]) = gbl;
        }
        __syncthreads();
        short8 afh[2], afl[2], bfh[2], bfl[2];
#pragma unroll
        for (int i = 0; i < 2; ++i) {
            const int ar = (wv * 32 + i * 16 + r) * 32 + kq;
            afh[i] = *reinterpret_cast<const short8*>(&Ash[ar]);
            afl[i] = *reinterpret_cast<const short8*>(&Asl[ar]);
        }
#pragma unroll
        for (int j = 0; j < 2; ++j) {
            const int br = (j * 16 + r) * 32 + kq;
            bfh[j] = *reinterpret_cast<const short8*>(&Bsh[br]);
            bfl[j] = *reinterpret_cast<const short8*>(&Bsl[br]);
        }
#pragma unroll
        for (int i = 0; i < 2; ++i)
#pragma unroll
            for (int j = 0; j < 2; ++j) {
                acc[i][j] = __builtin_amdgcn_mfma_f32_16x16x32_bf16(afh[i], bfh[j], acc[i][j], 0, 0, 0);
                acc[i][j] = __builtin_amdgcn_mfma_f32_16x16x32_bf16(afh[i], bfl[j], acc[i][j], 0, 0, 0);
                acc[i][j] = __builtin_amdgcn_mfma_f32_16x16x32_bf16(afl[i], bfh[j], acc[i][j], 0, 0, 0);
            }
    }

    const int r4 = (lane >> 4) << 2;
#pragma unroll
    for (int i = 0; i < 2; ++i)
#pragma unroll
        for (int j = 0; j < 2; ++j) {
            const int col = j * 16 + r;
#pragma unroll
            for (int rr = 0; rr < 4; ++rr) {
                const int row = bm * 128 + wv * 32 + i * 16 + r4 + rr;
                P[(long)row * 32 + col] = acc[i][j][rr];
            }
        }
}

// ---------------- finalize: 7x7 algebra from projections ----------------
__device__ __forceinline__ int midx(int rr, int cc) {
    const int i = rr - cc;
    return i * 7 - (i * (i - 1)) / 2 + cc;
}

__global__ __launch_bounds__(64) void finalize_k(
    const float* __restrict__ PY,
    const float* __restrict__ PD,
    const float* __restrict__ vel_g,
    const float* __restrict__ acc_g,
    const float* __restrict__ b_ld,
    const float* __restrict__ b_lo,
    float* __restrict__ out,
    int b0)
{
    __shared__ float lval[28];
    __shared__ int gpv[7];
    __shared__ float derl[29 * 7];
    __shared__ float Lm[49], Mm[49], dLt[49], uu[49];
    __shared__ float wvv[7], pv[7], Cv[7], Gv[7], tauv[7], vl[7], ac[7];

    const int bl = blockIdx.x, tid = threadIdx.x;
    const int b = b0 + bl;
    if (tid < 28) {
        float s = PY[(long)bl * 32 + tid];
        if (tid < 7) {
            s += b_ld[tid];
            gpv[tid] = s > 0.f;
            lval[tid] = s > 0.f ? s : 0.f;
        } else {
            lval[tid] = s + b_lo[tid - 7];
        }
    }
    if (tid >= 28 && tid < 35) {
        vl[tid - 28] = vel_g[b * 7 + tid - 28];
        ac[tid - 28] = acc_g[b * 7 + tid - 28];
    }
    __syncthreads();
    for (int idx = tid; idx < 203; idx += 64) {
        const int m = idx / 7, d = idx % 7;
        float v = PD[((long)bl * 7 + d) * 32 + m];
        if (m < 7 && !gpv[m]) v = 0.f;
        derl[m * 7 + d] = v;
    }
    __syncthreads();
    if (tid < 49) {
        const int rr = tid / 7, cc = tid % 7;
        Lm[tid] = (rr >= cc) ? lval[midx(rr, cc)] : 0.f;
    }
    __syncthreads();
    if (tid < 49) {
        const int rr = tid / 7, cc = tid % 7;
        float s = 0.f;
        for (int k = 0; k < 7; ++k) s += Lm[rr * 7 + k] * Lm[cc * 7 + k];
        if (rr == cc) s += 1e-5f;
        Mm[tid] = s;
        float t = 0.f;
        if (rr >= cc) {
            const int m = midx(rr, cc);
            for (int d = 0; d < 7; ++d) t += derl[m * 7 + d] * vl[d];
        }
        dLt[tid] = t;
        float u = 0.f;
        for (int r2 = cc; r2 < 7; ++r2) u += vl[r2] * derl[midx(r2, cc) * 7 + rr];
        uu[tid] = u;
    } else if (tid >= 49 && tid < 56) {
        const int j = tid - 49;
        float s = 0.f;
        for (int r2 = 0; r2 < 7; ++r2) s += Lm[r2 * 7 + j] * vl[r2];
        wvv[j] = s;
    }
    __syncthreads();
    if (tid < 7) {
        float s = 0.f;
        for (int r2 = 0; r2 < 7; ++r2) s += dLt[r2 * 7 + tid] * vl[r2];
        pv[tid] = s;
    }
    __syncthreads();
    if (tid < 7) {
        float s = 0.f, q = 0.f, md = 0.f;
        for (int c = 0; c < 7; ++c) {
            s += Lm[tid * 7 + c] * pv[c] + dLt[tid * 7 + c] * wvv[c];
            q += uu[tid * 7 + c] * wvv[c];
            md += Mm[tid * 7 + c] * ac[c];
        }
        Cv[tid] = s - q;
        Gv[tid] = derl[28 * 7 + tid];
        tauv[tid] = md + Cv[tid] + Gv[tid];
    }
    __syncthreads();
    if (tid < 49) out[57344 + (long)b * 49 + tid] = Mm[tid];
    if (tid < 7) {
        out[(long)b * 7 + tid] = tauv[tid];
        out[458752 + (long)b * 7 + tid] = Cv[tid];
        out[516096 + (long)b * 7 + tid] = Gv[tid];
    }
}

extern "C" void kernel_launch(void* const* d_in, const int* in_sizes, int n_in,
                              void* d_out, int out_size, void* d_ws, size_t ws_size,
                              hipStream_t stream)
{
    const float* state = (const float*)d_in[0];
    const float* vel   = (const float*)d_in[1];
    const float* accel = (const float*)d_in[2];
    const float* W_in  = (const float*)d_in[3];
    const float* b_in  = (const float*)d_in[4];
    const float* W_h   = (const float*)d_in[5];
    const float* b_h   = (const float*)d_in[6];
    const float* W_g   = (const float*)d_in[7];
    /* d_in[8] = b_g unused */
    const float* W_ld  = (const float*)d_in[9];
    const float* b_ld  = (const float*)d_in[10];
    const float* W_lo  = (const float*)d_in[11];
    const float* b_lo  = (const float*)d_in[12];
    float* outp = (float*)d_out;

    char* ws = (char*)d_ws;
    __hip_bfloat16* Wth = (__hip_bfloat16*)ws; ws += (size_t)WIDTH * WIDTH * 2;
    __hip_bfloat16* Wtl = (__hip_bfloat16*)ws; ws += (size_t)WIDTH * WIDTH * 2;
    __hip_bfloat16* Wch = (__hip_bfloat16*)ws; ws += 32 * WIDTH * 2;
    __hip_bfloat16* Wcl = (__hip_bfloat16*)ws; ws += 32 * WIDTH * 2;
    const size_t fixed = (size_t)(ws - (char*)d_ws);

    int CH = 128;
    for (int cand = 8192; cand >= 128; cand >>= 1) {
        size_t need = fixed + (size_t)cand * (65536 + 1024);
        if (need <= ws_size) { CH = cand; break; }
    }
    const int NCH = BATCH / CH;

    const size_t YB = (size_t)CH * WIDTH * 2;
    const size_t DB = (size_t)CH * 7 * WIDTH * 2;
    __hip_bfloat16* Yah = (__hip_bfloat16*)ws; ws += YB;
    __hip_bfloat16* Yal = (__hip_bfloat16*)ws; ws += YB;
    __hip_bfloat16* Ybh = (__hip_bfloat16*)ws; ws += YB;
    __hip_bfloat16* Ybl = (__hip_bfloat16*)ws; ws += YB;
    __hip_bfloat16* Dah = (__hip_bfloat16*)ws; ws += DB;
    __hip_bfloat16* Dal = (__hip_bfloat16*)ws; ws += DB;
    __hip_bfloat16* Dbh = (__hip_bfloat16*)ws; ws += DB;
    __hip_bfloat16* Dbl = (__hip_bfloat16*)ws; ws += DB;
    float* PY = (float*)ws; ws += (size_t)CH * 32 * 4;
    float* PD = (float*)ws; ws += (size_t)CH * 7 * 32 * 4;

    transpose_k<<<dim3(32, 32), dim3(256), 0, stream>>>(W_h, Wth, Wtl);
    buildwcat_k<<<dim3(128), dim3(256), 0, stream>>>(W_ld, W_lo, W_g, Wch, Wcl);

    for (int c = 0; c < NCH; ++c) {
        prep_k<<<dim3(CH), dim3(256), 0, stream>>>(state + (size_t)c * CH * 7, W_in, b_in,
                                                   Yah, Yal, Dah, Dal);
        gemm_k<0><<<dim3(CH / 128, 8), dim3(256), 0, stream>>>(
            Yah, Yal, Wth, Wtl, b_h, nullptr, Ybh, Ybl);                       // Y2
        gemm_k<1><<<dim3(CH * 7 / 128, 8), dim3(256), 0, stream>>>(
            Dah, Dal, Wth, Wtl, nullptr, Ybh, Dbh, Dbl);                       // D2 (mask Y2)
        gemm_k<0><<<dim3(CH / 128, 8), dim3(256), 0, stream>>>(
            Ybh, Ybl, Wth, Wtl, b_h, nullptr, Yah, Yal);                       // Y3
        gemm_k<1><<<dim3(CH * 7 / 128, 8), dim3(256), 0, stream>>>(
            Dbh, Dbl, Wth, Wtl, nullptr, Yah, Dah, Dal);                       // D3 (mask Y3)
        gemm_head<<<dim3(CH / 128), dim3(256), 0, stream>>>(Yah, Yal, Wch, Wcl, PY);
        gemm_head<<<dim3(CH * 7 / 128), dim3(256), 0, stream>>>(Dah, Dal, Wch, Wcl, PD);
        finalize_k<<<dim3(CH), dim3(64), 0, stream>>>(PY, PD, vel, accel, b_ld, b_lo,
                                                      outp, c * CH);
    }
    (void)in_sizes; (void)n_in; (void)out_size;
}

// Round 8
// 962.250 us; speedup vs baseline: 2.2882x; 1.4916x over previous
//
#include <hip/hip_runtime.h>
#include <hip/hip_bf16.h>

#define WIDTH 1024
#define BATCH 8192

typedef __attribute__((ext_vector_type(8))) short short8;
typedef __attribute__((ext_vector_type(4))) float floatx4;

typedef __attribute__((address_space(1))) void gvoid;
typedef __attribute__((address_space(3))) void lvoid;

__device__ __forceinline__ void async_copy16(const void* g, void* l) {
    __builtin_amdgcn_global_load_lds((gvoid*)g, (lvoid*)l, 16, 0, 0);
}

__device__ __forceinline__ void split_store(float v, __hip_bfloat16* hi, __hip_bfloat16* lo, long idx) {
    __hip_bfloat16 h = __float2bfloat16(v);
    hi[idx] = h;
    lo[idx] = __float2bfloat16(v - __bfloat162float(h));
}

// ---------------- transpose W_h (fp32) -> Wt_hi/lo[n][k] bf16 ----------------
__global__ __launch_bounds__(256) void transpose_k(
    const float* __restrict__ W,
    __hip_bfloat16* __restrict__ Wth, __hip_bfloat16* __restrict__ Wtl)
{
    __shared__ float t[32][33];
    const int tx = threadIdx.x & 31, ty = threadIdx.x >> 5;
    const int bx = blockIdx.x << 5, by = blockIdx.y << 5;
#pragma unroll
    for (int r = 0; r < 32; r += 8)
        t[ty + r][tx] = W[(long)(by + ty + r) * WIDTH + bx + tx];
    __syncthreads();
#pragma unroll
    for (int r = 0; r < 32; r += 8)
        split_store(t[tx][ty + r], Wth, Wtl, (long)(bx + ty + r) * WIDTH + by + tx);
}

// ---------------- pack head weights: Wcat[32][1024] hi/lo ----------------
__global__ __launch_bounds__(256) void buildwcat_k(
    const float* __restrict__ W_ld, const float* __restrict__ W_lo,
    const float* __restrict__ W_g,
    __hip_bfloat16* __restrict__ Wch, __hip_bfloat16* __restrict__ Wcl)
{
    const int idx = blockIdx.x * 256 + threadIdx.x;   // 32*1024
    const int n = idx >> 10, k = idx & 1023;
    float v = 0.f;
    if (n < 7)       v = W_ld[k * 7 + n];
    else if (n < 28) v = W_lo[k * 21 + (n - 7)];
    else if (n == 28) v = W_g[k];
    split_store(v, Wch, Wcl, idx);
}

// ---------------- layer 1: Y1 split, D1 hi-only ----------------
__global__ __launch_bounds__(256) void prep_k(
    const float* __restrict__ state,
    const float* __restrict__ W_in,
    const float* __restrict__ b_in,
    __hip_bfloat16* __restrict__ Y1h, __hip_bfloat16* __restrict__ Y1l,
    __hip_bfloat16* __restrict__ D1h)
{
    const int b = blockIdx.x;
    const int j0 = threadIdx.x * 4;
    float s[7];
#pragma unroll
    for (int d = 0; d < 7; ++d) s[d] = state[b * 7 + d];
    float a[4];
#pragma unroll
    for (int q = 0; q < 4; ++q) a[q] = b_in[j0 + q];
    float w[7][4];
#pragma unroll
    for (int d = 0; d < 7; ++d)
#pragma unroll
        for (int q = 0; q < 4; ++q) {
            w[d][q] = W_in[d * WIDTH + j0 + q];
            a[q] += s[d] * w[d][q];
        }
    bool gp[4];
#pragma unroll
    for (int q = 0; q < 4; ++q) {
        gp[q] = a[q] > 0.f;
        split_store(gp[q] ? a[q] : 0.f, Y1h, Y1l, (long)b * WIDTH + j0 + q);
    }
    union { unsigned long long u64; unsigned short h[4]; } pk;
#pragma unroll
    for (int d = 0; d < 7; ++d) {
#pragma unroll
        for (int q = 0; q < 4; ++q) {
            __hip_bfloat16 v = __float2bfloat16(gp[q] ? w[d][q] : 0.f);
            pk.h[q] = *reinterpret_cast<unsigned short*>(&v);
        }
        *reinterpret_cast<unsigned long long*>(&D1h[((long)b * 7 + d) * WIDTH + j0]) = pk.u64;
    }
}

// ---------------- Y GEMM (3-pass split, relu+bias epi, split out) ----------------
__global__ __launch_bounds__(256) void gemm_y(
    const __hip_bfloat16* __restrict__ Ah, const __hip_bfloat16* __restrict__ Al,
    const __hip_bfloat16* __restrict__ Bh, const __hip_bfloat16* __restrict__ Bl,
    const float* __restrict__ bias,
    __hip_bfloat16* __restrict__ outh, __hip_bfloat16* __restrict__ outl)
{
    __shared__ __align__(16) short Ash[128 * 32], Asl[128 * 32];
    __shared__ __align__(16) short Bsh[128 * 32], Bsl[128 * 32];
    const int tid = threadIdx.x;
    const int lane = tid & 63;
    const int wv = tid >> 6;
    const int wm = wv >> 1, wn = wv & 1;
    const int bm = blockIdx.x, bn = blockIdx.y;

    const int srow = tid >> 2;
    const int scol = (tid & 3) << 3;
    const short* pAh = (const short*)Ah + (long)(bm * 128 + srow) * WIDTH + scol;
    const short* pAl = (const short*)Al + (long)(bm * 128 + srow) * WIDTH + scol;
    const short* pBh = (const short*)Bh + (long)(bn * 128 + srow) * WIDTH + scol;
    const short* pBl = (const short*)Bl + (long)(bn * 128 + srow) * WIDTH + scol;
    const long half = 64l * WIDTH;

    floatx4 acc[4][4] = {};
    const int r = lane & 15;
    const int kq = (lane >> 4) << 3;

    for (int kt = 0; kt < WIDTH; kt += 32) {
        __syncthreads();
        async_copy16(pAh + kt,        Ash + wv * 512);
        async_copy16(pAh + half + kt, Ash + 2048 + wv * 512);
        async_copy16(pAl + kt,        Asl + wv * 512);
        async_copy16(pAl + half + kt, Asl + 2048 + wv * 512);
        async_copy16(pBh + kt,        Bsh + wv * 512);
        async_copy16(pBh + half + kt, Bsh + 2048 + wv * 512);
        async_copy16(pBl + kt,        Bsl + wv * 512);
        async_copy16(pBl + half + kt, Bsl + 2048 + wv * 512);
        __syncthreads();
        short8 afh[4], afl[4], bfh[4], bfl[4];
#pragma unroll
        for (int i = 0; i < 4; ++i) {
            const int ar = (wm * 64 + i * 16 + r) * 32 + kq;
            afh[i] = *reinterpret_cast<const short8*>(&Ash[ar]);
            afl[i] = *reinterpret_cast<const short8*>(&Asl[ar]);
        }
#pragma unroll
        for (int j = 0; j < 4; ++j) {
            const int br = (wn * 64 + j * 16 + r) * 32 + kq;
            bfh[j] = *reinterpret_cast<const short8*>(&Bsh[br]);
            bfl[j] = *reinterpret_cast<const short8*>(&Bsl[br]);
        }
#pragma unroll
        for (int i = 0; i < 4; ++i)
#pragma unroll
            for (int j = 0; j < 4; ++j) {
                acc[i][j] = __builtin_amdgcn_mfma_f32_16x16x32_bf16(afh[i], bfh[j], acc[i][j], 0, 0, 0);
                acc[i][j] = __builtin_amdgcn_mfma_f32_16x16x32_bf16(afh[i], bfl[j], acc[i][j], 0, 0, 0);
                acc[i][j] = __builtin_amdgcn_mfma_f32_16x16x32_bf16(afl[i], bfh[j], acc[i][j], 0, 0, 0);
            }
    }

    const int r4 = (lane >> 4) << 2;
#pragma unroll
    for (int i = 0; i < 4; ++i)
#pragma unroll
        for (int j = 0; j < 4; ++j) {
            const int col = bn * 128 + wn * 64 + j * 16 + r;
#pragma unroll
            for (int rr = 0; rr < 4; ++rr) {
                const int row = bm * 128 + wm * 64 + i * 16 + r4 + rr;
                float v = acc[i][j][rr] + bias[col];
                v = v > 0.f ? v : 0.f;
                split_store(v, outh, outl, (long)row * WIDTH + col);
            }
        }
}

// ---------------- D GEMM (2-pass: Ah*Bh + Ah*Bl; A bf16-only; mask epi; hi out) ----------------
__global__ __launch_bounds__(256) void gemm_d(
    const __hip_bfloat16* __restrict__ Ah,
    const __hip_bfloat16* __restrict__ Bh, const __hip_bfloat16* __restrict__ Bl,
    const __hip_bfloat16* __restrict__ mask,
    __hip_bfloat16* __restrict__ outh)
{
    __shared__ __align__(16) short Ash[128 * 32];
    __shared__ __align__(16) short Bsh[128 * 32], Bsl[128 * 32];
    const int tid = threadIdx.x;
    const int lane = tid & 63;
    const int wv = tid >> 6;
    const int wm = wv >> 1, wn = wv & 1;
    const int bm = blockIdx.x, bn = blockIdx.y;

    const int srow = tid >> 2;
    const int scol = (tid & 3) << 3;
    const short* pAh = (const short*)Ah + (long)(bm * 128 + srow) * WIDTH + scol;
    const short* pBh = (const short*)Bh + (long)(bn * 128 + srow) * WIDTH + scol;
    const short* pBl = (const short*)Bl + (long)(bn * 128 + srow) * WIDTH + scol;
    const long half = 64l * WIDTH;

    floatx4 acc[4][4] = {};
    const int r = lane & 15;
    const int kq = (lane >> 4) << 3;

    for (int kt = 0; kt < WIDTH; kt += 32) {
        __syncthreads();
        async_copy16(pAh + kt,        Ash + wv * 512);
        async_copy16(pAh + half + kt, Ash + 2048 + wv * 512);
        async_copy16(pBh + kt,        Bsh + wv * 512);
        async_copy16(pBh + half + kt, Bsh + 2048 + wv * 512);
        async_copy16(pBl + kt,        Bsl + wv * 512);
        async_copy16(pBl + half + kt, Bsl + 2048 + wv * 512);
        __syncthreads();
        short8 afh[4], bfh[4], bfl[4];
#pragma unroll
        for (int i = 0; i < 4; ++i)
            afh[i] = *reinterpret_cast<const short8*>(&Ash[(wm * 64 + i * 16 + r) * 32 + kq]);
#pragma unroll
        for (int j = 0; j < 4; ++j) {
            const int br = (wn * 64 + j * 16 + r) * 32 + kq;
            bfh[j] = *reinterpret_cast<const short8*>(&Bsh[br]);
            bfl[j] = *reinterpret_cast<const short8*>(&Bsl[br]);
        }
#pragma unroll
        for (int i = 0; i < 4; ++i)
#pragma unroll
            for (int j = 0; j < 4; ++j) {
                acc[i][j] = __builtin_amdgcn_mfma_f32_16x16x32_bf16(afh[i], bfh[j], acc[i][j], 0, 0, 0);
                acc[i][j] = __builtin_amdgcn_mfma_f32_16x16x32_bf16(afh[i], bfl[j], acc[i][j], 0, 0, 0);
            }
    }

    const int r4 = (lane >> 4) << 2;
#pragma unroll
    for (int i = 0; i < 4; ++i)
#pragma unroll
        for (int j = 0; j < 4; ++j) {
            const int col = bn * 128 + wn * 64 + j * 16 + r;
#pragma unroll
            for (int rr = 0; rr < 4; ++rr) {
                const int row = bm * 128 + wm * 64 + i * 16 + r4 + rr;
                float v = acc[i][j][rr];
                const unsigned brow = (unsigned)row / 7u;
                if (!(__bfloat162float(mask[(long)brow * WIDTH + col]) > 0.f)) v = 0.f;
                outh[(long)row * WIDTH + col] = __float2bfloat16(v);
            }
        }
}

// ---------------- head-projection GEMM 128x32 ----------------
// SPLITA=1: A split (3-pass, for Y3). SPLITA=0: A hi-only (2-pass, for D3).
template <int SPLITA>
__global__ __launch_bounds__(256) void gemm_head(
    const __hip_bfloat16* __restrict__ Ah, const __hip_bfloat16* __restrict__ Al,
    const __hip_bfloat16* __restrict__ Bh, const __hip_bfloat16* __restrict__ Bl, // Wcat[32][1024]
    float* __restrict__ P)
{
    __shared__ __align__(16) short Ash[128 * 32], Asl[SPLITA ? 128 * 32 : 16];
    __shared__ __align__(16) short Bsh[32 * 32], Bsl[32 * 32];
    const int tid = threadIdx.x;
    const int lane = tid & 63;
    const int wv = tid >> 6;
    const int bm = blockIdx.x;

    const int srow = tid >> 2;
    const int scol = (tid & 3) << 3;
    const short* pAh = (const short*)Ah + (long)(bm * 128 + srow) * WIDTH + scol;
    const short* pAl = (const short*)Al + (long)(bm * 128 + srow) * WIDTH + scol;
    const long boff = (long)srow * WIDTH + scol;
    const short* pBh = (const short*)Bh;  const short* pBl = (const short*)Bl;
    const long half = 64l * WIDTH;

    floatx4 acc[2][2] = {};
    const int r = lane & 15;
    const int kq = (lane >> 4) << 3;

    for (int kt = 0; kt < WIDTH; kt += 32) {
        short8 gbh, gbl;
        if (tid < 128) {
            gbh = *reinterpret_cast<const short8*>(pBh + boff + kt);
            gbl = *reinterpret_cast<const short8*>(pBl + boff + kt);
        }
        __syncthreads();
        async_copy16(pAh + kt,        Ash + wv * 512);
        async_copy16(pAh + half + kt, Ash + 2048 + wv * 512);
        if (SPLITA) {
            async_copy16(pAl + kt,        Asl + wv * 512);
            async_copy16(pAl + half + kt, Asl + 2048 + wv * 512);
        }
        if (tid < 128) {
            *reinterpret_cast<short8*>(&Bsh[srow * 32 + scol]) = gbh;
            *reinterpret_cast<short8*>(&Bsl[srow * 32 + scol]) = gbl;
        }
        __syncthreads();
        short8 afh[2], afl[2], bfh[2], bfl[2];
#pragma unroll
        for (int i = 0; i < 2; ++i) {
            const int ar = (wv * 32 + i * 16 + r) * 32 + kq;
            afh[i] = *reinterpret_cast<const short8*>(&Ash[ar]);
            if (SPLITA) afl[i] = *reinterpret_cast<const short8*>(&Asl[ar]);
        }
#pragma unroll
        for (int j = 0; j < 2; ++j) {
            const int br = (j * 16 + r) * 32 + kq;
            bfh[j] = *reinterpret_cast<const short8*>(&Bsh[br]);
            bfl[j] = *reinterpret_cast<const short8*>(&Bsl[br]);
        }
#pragma unroll
        for (int i = 0; i < 2; ++i)
#pragma unroll
            for (int j = 0; j < 2; ++j) {
                acc[i][j] = __builtin_amdgcn_mfma_f32_16x16x32_bf16(afh[i], bfh[j], acc[i][j], 0, 0, 0);
                acc[i][j] = __builtin_amdgcn_mfma_f32_16x16x32_bf16(afh[i], bfl[j], acc[i][j], 0, 0, 0);
                if (SPLITA)
                    acc[i][j] = __builtin_amdgcn_mfma_f32_16x16x32_bf16(afl[i], bfh[j], acc[i][j], 0, 0, 0);
            }
    }

    const int r4 = (lane >> 4) << 2;
#pragma unroll
    for (int i = 0; i < 2; ++i)
#pragma unroll
        for (int j = 0; j < 2; ++j) {
            const int col = j * 16 + r;
#pragma unroll
            for (int rr = 0; rr < 4; ++rr) {
                const int row = bm * 128 + wv * 32 + i * 16 + r4 + rr;
                P[(long)row * 32 + col] = acc[i][j][rr];
            }
        }
}

// ---------------- finalize: 7x7 algebra from projections ----------------
__device__ __forceinline__ int midx(int rr, int cc) {
    const int i = rr - cc;
    return i * 7 - (i * (i - 1)) / 2 + cc;
}

__global__ __launch_bounds__(64) void finalize_k(
    const float* __restrict__ PY,
    const float* __restrict__ PD,
    const float* __restrict__ vel_g,
    const float* __restrict__ acc_g,
    const float* __restrict__ b_ld,
    const float* __restrict__ b_lo,
    float* __restrict__ out,
    int b0)
{
    __shared__ float lval[28];
    __shared__ int gpv[7];
    __shared__ float derl[29 * 7];
    __shared__ float Lm[49], Mm[49], dLt[49], uu[49];
    __shared__ float wvv[7], pv[7], Cv[7], Gv[7], tauv[7], vl[7], ac[7];

    const int bl = blockIdx.x, tid = threadIdx.x;
    const int b = b0 + bl;
    if (tid < 28) {
        float s = PY[(long)bl * 32 + tid];
        if (tid < 7) {
            s += b_ld[tid];
            gpv[tid] = s > 0.f;
            lval[tid] = s > 0.f ? s : 0.f;
        } else {
            lval[tid] = s + b_lo[tid - 7];
        }
    }
    if (tid >= 28 && tid < 35) {
        vl[tid - 28] = vel_g[b * 7 + tid - 28];
        ac[tid - 28] = acc_g[b * 7 + tid - 28];
    }
    __syncthreads();
    for (int idx = tid; idx < 203; idx += 64) {
        const int m = idx / 7, d = idx % 7;
        float v = PD[((long)bl * 7 + d) * 32 + m];
        if (m < 7 && !gpv[m]) v = 0.f;
        derl[m * 7 + d] = v;
    }
    __syncthreads();
    if (tid < 49) {
        const int rr = tid / 7, cc = tid % 7;
        Lm[tid] = (rr >= cc) ? lval[midx(rr, cc)] : 0.f;
    }
    __syncthreads();
    if (tid < 49) {
        const int rr = tid / 7, cc = tid % 7;
        float s = 0.f;
        for (int k = 0; k < 7; ++k) s += Lm[rr * 7 + k] * Lm[cc * 7 + k];
        if (rr == cc) s += 1e-5f;
        Mm[tid] = s;
        float t = 0.f;
        if (rr >= cc) {
            const int m = midx(rr, cc);
            for (int d = 0; d < 7; ++d) t += derl[m * 7 + d] * vl[d];
        }
        dLt[tid] = t;
        float u = 0.f;
        for (int r2 = cc; r2 < 7; ++r2) u += vl[r2] * derl[midx(r2, cc) * 7 + rr];
        uu[tid] = u;
    } else if (tid >= 49 && tid < 56) {
        const int j = tid - 49;
        float s = 0.f;
        for (int r2 = 0; r2 < 7; ++r2) s += Lm[r2 * 7 + j] * vl[r2];
        wvv[j] = s;
    }
    __syncthreads();
    if (tid < 7) {
        float s = 0.f;
        for (int r2 = 0; r2 < 7; ++r2) s += dLt[r2 * 7 + tid] * vl[r2];
        pv[tid] = s;
    }
    __syncthreads();
    if (tid < 7) {
        float s = 0.f, q = 0.f, md = 0.f;
        for (int c = 0; c < 7; ++c) {
            s += Lm[tid * 7 + c] * pv[c] + dLt[tid * 7 + c] * wvv[c];
            q += uu[tid * 7 + c] * wvv[c];
            md += Mm[tid * 7 + c] * ac[c];
        }
        Cv[tid] = s - q;
        Gv[tid] = derl[28 * 7 + tid];
        tauv[tid] = md + Cv[tid] + Gv[tid];
    }
    __syncthreads();
    if (tid < 49) out[57344 + (long)b * 49 + tid] = Mm[tid];
    if (tid < 7) {
        out[(long)b * 7 + tid] = tauv[tid];
        out[458752 + (long)b * 7 + tid] = Cv[tid];
        out[516096 + (long)b * 7 + tid] = Gv[tid];
    }
}

extern "C" void kernel_launch(void* const* d_in, const int* in_sizes, int n_in,
                              void* d_out, int out_size, void* d_ws, size_t ws_size,
                              hipStream_t stream)
{
    const float* state = (const float*)d_in[0];
    const float* vel   = (const float*)d_in[1];
    const float* accel = (const float*)d_in[2];
    const float* W_in  = (const float*)d_in[3];
    const float* b_in  = (const float*)d_in[4];
    const float* W_h   = (const float*)d_in[5];
    const float* b_h   = (const float*)d_in[6];
    const float* W_g   = (const float*)d_in[7];
    /* d_in[8] = b_g unused */
    const float* W_ld  = (const float*)d_in[9];
    const float* b_ld  = (const float*)d_in[10];
    const float* W_lo  = (const float*)d_in[11];
    const float* b_lo  = (const float*)d_in[12];
    float* outp = (float*)d_out;

    char* ws = (char*)d_ws;
    __hip_bfloat16* Wth = (__hip_bfloat16*)ws; ws += (size_t)WIDTH * WIDTH * 2;
    __hip_bfloat16* Wtl = (__hip_bfloat16*)ws; ws += (size_t)WIDTH * WIDTH * 2;
    __hip_bfloat16* Wch = (__hip_bfloat16*)ws; ws += 32 * WIDTH * 2;
    __hip_bfloat16* Wcl = (__hip_bfloat16*)ws; ws += 32 * WIDTH * 2;
    const size_t fixed = (size_t)(ws - (char*)d_ws);

    // per-sample ws: Y 4*2048 + D 2*14336 + P 1024 = 37888 B
    int CH = 128;
    for (int cand = 8192; cand >= 128; cand >>= 1) {
        size_t need = fixed + (size_t)cand * 37888;
        if (need <= ws_size) { CH = cand; break; }
    }
    const int NCH = BATCH / CH;

    const size_t YB = (size_t)CH * WIDTH * 2;
    const size_t DB = (size_t)CH * 7 * WIDTH * 2;
    __hip_bfloat16* Yah = (__hip_bfloat16*)ws; ws += YB;   // Y1 -> Y3
    __hip_bfloat16* Yal = (__hip_bfloat16*)ws; ws += YB;
    __hip_bfloat16* Ybh = (__hip_bfloat16*)ws; ws += YB;   // Y2
    __hip_bfloat16* Ybl = (__hip_bfloat16*)ws; ws += YB;
    __hip_bfloat16* Dah = (__hip_bfloat16*)ws; ws += DB;   // D1 -> D3 (hi only)
    __hip_bfloat16* Dbh = (__hip_bfloat16*)ws; ws += DB;   // D2 (hi only)
    float* PY = (float*)ws; ws += (size_t)CH * 32 * 4;
    float* PD = (float*)ws; ws += (size_t)CH * 7 * 32 * 4;

    transpose_k<<<dim3(32, 32), dim3(256), 0, stream>>>(W_h, Wth, Wtl);
    buildwcat_k<<<dim3(128), dim3(256), 0, stream>>>(W_ld, W_lo, W_g, Wch, Wcl);

    for (int c = 0; c < NCH; ++c) {
        prep_k<<<dim3(CH), dim3(256), 0, stream>>>(state + (size_t)c * CH * 7, W_in, b_in,
                                                   Yah, Yal, Dah);
        gemm_y<<<dim3(CH / 128, 8), dim3(256), 0, stream>>>(
            Yah, Yal, Wth, Wtl, b_h, Ybh, Ybl);                                // Y2
        gemm_d<<<dim3(CH * 7 / 128, 8), dim3(256), 0, stream>>>(
            Dah, Wth, Wtl, Ybh, Dbh);                                          // D2 (mask Y2)
        gemm_y<<<dim3(CH / 128, 8), dim3(256), 0, stream>>>(
            Ybh, Ybl, Wth, Wtl, b_h, Yah, Yal);                                // Y3
        gemm_d<<<dim3(CH * 7 / 128, 8), dim3(256), 0, stream>>>(
            Dbh, Wth, Wtl, Yah, Dah);                                          // D3 (mask Y3)
        gemm_head<1><<<dim3(CH / 128), dim3(256), 0, stream>>>(Yah, Yal, Wch, Wcl, PY);
        gemm_head<0><<<dim3(CH * 7 / 128), dim3(256), 0, stream>>>(Dah, nullptr, Wch, Wcl, PD);
        finalize_k<<<dim3(CH), dim3(64), 0, stream>>>(PY, PD, vel, accel, b_ld, b_lo,
                                                      outp, c * CH);
    }
    (void)in_sizes; (void)n_in; (void)out_size;
}

// Round 9
// 728.556 us; speedup vs baseline: 3.0222x; 1.3208x over previous
//
#include <hip/hip_runtime.h>
#include <hip/hip_bf16.h>

#define WIDTH 1024
#define BATCH 8192

typedef __attribute__((ext_vector_type(8))) short short8;
typedef __attribute__((ext_vector_type(4))) float floatx4;

typedef __attribute__((address_space(1))) void gvoid;
typedef __attribute__((address_space(3))) void lvoid;

__device__ __forceinline__ void async_copy16(const void* g, void* l) {
    __builtin_amdgcn_global_load_lds((gvoid*)g, (lvoid*)l, 16, 0, 0);
}

__device__ __forceinline__ void split_store(float v, __hip_bfloat16* hi, __hip_bfloat16* lo, long idx) {
    __hip_bfloat16 h = __float2bfloat16(v);
    hi[idx] = h;
    lo[idx] = __float2bfloat16(v - __bfloat162float(h));
}

// ---------------- transpose W_h (fp32) -> Wt_hi/lo[n][k] bf16 ----------------
__global__ __launch_bounds__(256) void transpose_k(
    const float* __restrict__ W,
    __hip_bfloat16* __restrict__ Wth, __hip_bfloat16* __restrict__ Wtl)
{
    __shared__ float t[32][33];
    const int tx = threadIdx.x & 31, ty = threadIdx.x >> 5;
    const int bx = blockIdx.x << 5, by = blockIdx.y << 5;
#pragma unroll
    for (int r = 0; r < 32; r += 8)
        t[ty + r][tx] = W[(long)(by + ty + r) * WIDTH + bx + tx];
    __syncthreads();
#pragma unroll
    for (int r = 0; r < 32; r += 8)
        split_store(t[tx][ty + r], Wth, Wtl, (long)(bx + ty + r) * WIDTH + by + tx);
}

// ---------------- pack head weights: Wcat[32][1024] hi/lo ----------------
__global__ __launch_bounds__(256) void buildwcat_k(
    const float* __restrict__ W_ld, const float* __restrict__ W_lo,
    const float* __restrict__ W_g,
    __hip_bfloat16* __restrict__ Wch, __hip_bfloat16* __restrict__ Wcl)
{
    const int idx = blockIdx.x * 256 + threadIdx.x;   // 32*1024
    const int n = idx >> 10, k = idx & 1023;
    float v = 0.f;
    if (n < 7)       v = W_ld[k * 7 + n];
    else if (n < 28) v = W_lo[k * 21 + (n - 7)];
    else if (n == 28) v = W_g[k];
    split_store(v, Wch, Wcl, idx);
}

// ---------------- layer 1: Y1 split, D1 hi-only ----------------
__global__ __launch_bounds__(256) void prep_k(
    const float* __restrict__ state,
    const float* __restrict__ W_in,
    const float* __restrict__ b_in,
    __hip_bfloat16* __restrict__ Y1h, __hip_bfloat16* __restrict__ Y1l,
    __hip_bfloat16* __restrict__ D1h)
{
    const int b = blockIdx.x;
    const int j0 = threadIdx.x * 4;
    float s[7];
#pragma unroll
    for (int d = 0; d < 7; ++d) s[d] = state[b * 7 + d];
    float a[4];
#pragma unroll
    for (int q = 0; q < 4; ++q) a[q] = b_in[j0 + q];
    float w[7][4];
#pragma unroll
    for (int d = 0; d < 7; ++d)
#pragma unroll
        for (int q = 0; q < 4; ++q) {
            w[d][q] = W_in[d * WIDTH + j0 + q];
            a[q] += s[d] * w[d][q];
        }
    bool gp[4];
#pragma unroll
    for (int q = 0; q < 4; ++q) {
        gp[q] = a[q] > 0.f;
        split_store(gp[q] ? a[q] : 0.f, Y1h, Y1l, (long)b * WIDTH + j0 + q);
    }
    union { unsigned long long u64; unsigned short h[4]; } pk;
#pragma unroll
    for (int d = 0; d < 7; ++d) {
#pragma unroll
        for (int q = 0; q < 4; ++q) {
            __hip_bfloat16 v = __float2bfloat16(gp[q] ? w[d][q] : 0.f);
            pk.h[q] = *reinterpret_cast<unsigned short*>(&v);
        }
        *reinterpret_cast<unsigned long long*>(&D1h[((long)b * 7 + d) * WIDTH + j0]) = pk.u64;
    }
}

// ---------------- Y GEMM (3-pass split, relu+bias epi, split out) ----------------
__global__ __launch_bounds__(256) void gemm_y(
    const __hip_bfloat16* __restrict__ Ah, const __hip_bfloat16* __restrict__ Al,
    const __hip_bfloat16* __restrict__ Bh, const __hip_bfloat16* __restrict__ Bl,
    const float* __restrict__ bias,
    __hip_bfloat16* __restrict__ outh, __hip_bfloat16* __restrict__ outl)
{
    __shared__ __align__(16) short Ash[128 * 32], Asl[128 * 32];
    __shared__ __align__(16) short Bsh[128 * 32], Bsl[128 * 32];
    const int tid = threadIdx.x;
    const int lane = tid & 63;
    const int wv = tid >> 6;
    const int wm = wv >> 1, wn = wv & 1;
    const int bm = blockIdx.x, bn = blockIdx.y;

    const int srow = tid >> 2;
    const int scol = (tid & 3) << 3;
    const short* pAh = (const short*)Ah + (long)(bm * 128 + srow) * WIDTH + scol;
    const short* pAl = (const short*)Al + (long)(bm * 128 + srow) * WIDTH + scol;
    const short* pBh = (const short*)Bh + (long)(bn * 128 + srow) * WIDTH + scol;
    const short* pBl = (const short*)Bl + (long)(bn * 128 + srow) * WIDTH + scol;
    const long half = 64l * WIDTH;

    floatx4 acc[4][4] = {};
    const int r = lane & 15;
    const int kq = (lane >> 4) << 3;

    for (int kt = 0; kt < WIDTH; kt += 32) {
        __syncthreads();
        async_copy16(pAh + kt,        Ash + wv * 512);
        async_copy16(pAh + half + kt, Ash + 2048 + wv * 512);
        async_copy16(pAl + kt,        Asl + wv * 512);
        async_copy16(pAl + half + kt, Asl + 2048 + wv * 512);
        async_copy16(pBh + kt,        Bsh + wv * 512);
        async_copy16(pBh + half + kt, Bsh + 2048 + wv * 512);
        async_copy16(pBl + kt,        Bsl + wv * 512);
        async_copy16(pBl + half + kt, Bsl + 2048 + wv * 512);
        __syncthreads();
        short8 afh[4], afl[4], bfh[4], bfl[4];
#pragma unroll
        for (int i = 0; i < 4; ++i) {
            const int ar = (wm * 64 + i * 16 + r) * 32 + kq;
            afh[i] = *reinterpret_cast<const short8*>(&Ash[ar]);
            afl[i] = *reinterpret_cast<const short8*>(&Asl[ar]);
        }
#pragma unroll
        for (int j = 0; j < 4; ++j) {
            const int br = (wn * 64 + j * 16 + r) * 32 + kq;
            bfh[j] = *reinterpret_cast<const short8*>(&Bsh[br]);
            bfl[j] = *reinterpret_cast<const short8*>(&Bsl[br]);
        }
#pragma unroll
        for (int i = 0; i < 4; ++i)
#pragma unroll
            for (int j = 0; j < 4; ++j) {
                acc[i][j] = __builtin_amdgcn_mfma_f32_16x16x32_bf16(afh[i], bfh[j], acc[i][j], 0, 0, 0);
                acc[i][j] = __builtin_amdgcn_mfma_f32_16x16x32_bf16(afh[i], bfl[j], acc[i][j], 0, 0, 0);
                acc[i][j] = __builtin_amdgcn_mfma_f32_16x16x32_bf16(afl[i], bfh[j], acc[i][j], 0, 0, 0);
            }
    }

    const int r4 = (lane >> 4) << 2;
#pragma unroll
    for (int i = 0; i < 4; ++i)
#pragma unroll
        for (int j = 0; j < 4; ++j) {
            const int col = bn * 128 + wn * 64 + j * 16 + r;
#pragma unroll
            for (int rr = 0; rr < 4; ++rr) {
                const int row = bm * 128 + wm * 64 + i * 16 + r4 + rr;
                float v = acc[i][j][rr] + bias[col];
                v = v > 0.f ? v : 0.f;
                split_store(v, outh, outl, (long)row * WIDTH + col);
            }
        }
}

// ---------------- D GEMM (1-pass: Ah*Bh, pure bf16; mask epi; hi out) ----------------
__global__ __launch_bounds__(256) void gemm_d(
    const __hip_bfloat16* __restrict__ Ah,
    const __hip_bfloat16* __restrict__ Bh,
    const __hip_bfloat16* __restrict__ mask,
    __hip_bfloat16* __restrict__ outh)
{
    __shared__ __align__(16) short Ash[128 * 32];
    __shared__ __align__(16) short Bsh[128 * 32];
    const int tid = threadIdx.x;
    const int lane = tid & 63;
    const int wv = tid >> 6;
    const int wm = wv >> 1, wn = wv & 1;
    const int bm = blockIdx.x, bn = blockIdx.y;

    const int srow = tid >> 2;
    const int scol = (tid & 3) << 3;
    const short* pAh = (const short*)Ah + (long)(bm * 128 + srow) * WIDTH + scol;
    const short* pBh = (const short*)Bh + (long)(bn * 128 + srow) * WIDTH + scol;
    const long half = 64l * WIDTH;

    floatx4 acc[4][4] = {};
    const int r = lane & 15;
    const int kq = (lane >> 4) << 3;

    for (int kt = 0; kt < WIDTH; kt += 32) {
        __syncthreads();
        async_copy16(pAh + kt,        Ash + wv * 512);
        async_copy16(pAh + half + kt, Ash + 2048 + wv * 512);
        async_copy16(pBh + kt,        Bsh + wv * 512);
        async_copy16(pBh + half + kt, Bsh + 2048 + wv * 512);
        __syncthreads();
        short8 afh[4], bfh[4];
#pragma unroll
        for (int i = 0; i < 4; ++i)
            afh[i] = *reinterpret_cast<const short8*>(&Ash[(wm * 64 + i * 16 + r) * 32 + kq]);
#pragma unroll
        for (int j = 0; j < 4; ++j)
            bfh[j] = *reinterpret_cast<const short8*>(&Bsh[(wn * 64 + j * 16 + r) * 32 + kq]);
#pragma unroll
        for (int i = 0; i < 4; ++i)
#pragma unroll
            for (int j = 0; j < 4; ++j)
                acc[i][j] = __builtin_amdgcn_mfma_f32_16x16x32_bf16(afh[i], bfh[j], acc[i][j], 0, 0, 0);
    }

    const int r4 = (lane >> 4) << 2;
#pragma unroll
    for (int i = 0; i < 4; ++i)
#pragma unroll
        for (int j = 0; j < 4; ++j) {
            const int col = bn * 128 + wn * 64 + j * 16 + r;
#pragma unroll
            for (int rr = 0; rr < 4; ++rr) {
                const int row = bm * 128 + wm * 64 + i * 16 + r4 + rr;
                float v = acc[i][j][rr];
                const unsigned brow = (unsigned)row / 7u;
                if (!(__bfloat162float(mask[(long)brow * WIDTH + col]) > 0.f)) v = 0.f;
                outh[(long)row * WIDTH + col] = __float2bfloat16(v);
            }
        }
}

// ---------------- head-projection GEMM 128x32 ----------------
// SPLITA=1: A split (3-pass, for Y3). SPLITA=0: A hi-only (2-pass, for D3).
template <int SPLITA>
__global__ __launch_bounds__(256) void gemm_head(
    const __hip_bfloat16* __restrict__ Ah, const __hip_bfloat16* __restrict__ Al,
    const __hip_bfloat16* __restrict__ Bh, const __hip_bfloat16* __restrict__ Bl, // Wcat[32][1024]
    float* __restrict__ P)
{
    __shared__ __align__(16) short Ash[128 * 32], Asl[SPLITA ? 128 * 32 : 16];
    __shared__ __align__(16) short Bsh[32 * 32], Bsl[32 * 32];
    const int tid = threadIdx.x;
    const int lane = tid & 63;
    const int wv = tid >> 6;
    const int bm = blockIdx.x;

    const int srow = tid >> 2;
    const int scol = (tid & 3) << 3;
    const short* pAh = (const short*)Ah + (long)(bm * 128 + srow) * WIDTH + scol;
    const short* pAl = (const short*)Al + (long)(bm * 128 + srow) * WIDTH + scol;
    const long boff = (long)srow * WIDTH + scol;
    const short* pBh = (const short*)Bh;  const short* pBl = (const short*)Bl;
    const long half = 64l * WIDTH;

    floatx4 acc[2][2] = {};
    const int r = lane & 15;
    const int kq = (lane >> 4) << 3;

    for (int kt = 0; kt < WIDTH; kt += 32) {
        short8 gbh, gbl;
        if (tid < 128) {
            gbh = *reinterpret_cast<const short8*>(pBh + boff + kt);
            gbl = *reinterpret_cast<const short8*>(pBl + boff + kt);
        }
        __syncthreads();
        async_copy16(pAh + kt,        Ash + wv * 512);
        async_copy16(pAh + half + kt, Ash + 2048 + wv * 512);
        if (SPLITA) {
            async_copy16(pAl + kt,        Asl + wv * 512);
            async_copy16(pAl + half + kt, Asl + 2048 + wv * 512);
        }
        if (tid < 128) {
            *reinterpret_cast<short8*>(&Bsh[srow * 32 + scol]) = gbh;
            *reinterpret_cast<short8*>(&Bsl[srow * 32 + scol]) = gbl;
        }
        __syncthreads();
        short8 afh[2], afl[2], bfh[2], bfl[2];
#pragma unroll
        for (int i = 0; i < 2; ++i) {
            const int ar = (wv * 32 + i * 16 + r) * 32 + kq;
            afh[i] = *reinterpret_cast<const short8*>(&Ash[ar]);
            if (SPLITA) afl[i] = *reinterpret_cast<const short8*>(&Asl[ar]);
        }
#pragma unroll
        for (int j = 0; j < 2; ++j) {
            const int br = (j * 16 + r) * 32 + kq;
            bfh[j] = *reinterpret_cast<const short8*>(&Bsh[br]);
            bfl[j] = *reinterpret_cast<const short8*>(&Bsl[br]);
        }
#pragma unroll
        for (int i = 0; i < 2; ++i)
#pragma unroll
            for (int j = 0; j < 2; ++j) {
                acc[i][j] = __builtin_amdgcn_mfma_f32_16x16x32_bf16(afh[i], bfh[j], acc[i][j], 0, 0, 0);
                acc[i][j] = __builtin_amdgcn_mfma_f32_16x16x32_bf16(afh[i], bfl[j], acc[i][j], 0, 0, 0);
                if (SPLITA)
                    acc[i][j] = __builtin_amdgcn_mfma_f32_16x16x32_bf16(afl[i], bfh[j], acc[i][j], 0, 0, 0);
            }
    }

    const int r4 = (lane >> 4) << 2;
#pragma unroll
    for (int i = 0; i < 2; ++i)
#pragma unroll
        for (int j = 0; j < 2; ++j) {
            const int col = j * 16 + r;
#pragma unroll
            for (int rr = 0; rr < 4; ++rr) {
                const int row = bm * 128 + wv * 32 + i * 16 + r4 + rr;
                P[(long)row * 32 + col] = acc[i][j][rr];
            }
        }
}

// ---------------- finalize: 7x7 algebra from projections ----------------
__device__ __forceinline__ int midx(int rr, int cc) {
    const int i = rr - cc;
    return i * 7 - (i * (i - 1)) / 2 + cc;
}

__global__ __launch_bounds__(64) void finalize_k(
    const float* __restrict__ PY,
    const float* __restrict__ PD,
    const float* __restrict__ vel_g,
    const float* __restrict__ acc_g,
    const float* __restrict__ b_ld,
    const float* __restrict__ b_lo,
    float* __restrict__ out,
    int b0)
{
    __shared__ float lval[28];
    __shared__ int gpv[7];
    __shared__ float derl[29 * 7];
    __shared__ float Lm[49], Mm[49], dLt[49], uu[49];
    __shared__ float wvv[7], pv[7], Cv[7], Gv[7], tauv[7], vl[7], ac[7];

    const int bl = blockIdx.x, tid = threadIdx.x;
    const int b = b0 + bl;
    if (tid < 28) {
        float s = PY[(long)bl * 32 + tid];
        if (tid < 7) {
            s += b_ld[tid];
            gpv[tid] = s > 0.f;
            lval[tid] = s > 0.f ? s : 0.f;
        } else {
            lval[tid] = s + b_lo[tid - 7];
        }
    }
    if (tid >= 28 && tid < 35) {
        vl[tid - 28] = vel_g[b * 7 + tid - 28];
        ac[tid - 28] = acc_g[b * 7 + tid - 28];
    }
    __syncthreads();
    for (int idx = tid; idx < 203; idx += 64) {
        const int m = idx / 7, d = idx % 7;
        float v = PD[((long)bl * 7 + d) * 32 + m];
        if (m < 7 && !gpv[m]) v = 0.f;
        derl[m * 7 + d] = v;
    }
    __syncthreads();
    if (tid < 49) {
        const int rr = tid / 7, cc = tid % 7;
        Lm[tid] = (rr >= cc) ? lval[midx(rr, cc)] : 0.f;
    }
    __syncthreads();
    if (tid < 49) {
        const int rr = tid / 7, cc = tid % 7;
        float s = 0.f;
        for (int k = 0; k < 7; ++k) s += Lm[rr * 7 + k] * Lm[cc * 7 + k];
        if (rr == cc) s += 1e-5f;
        Mm[tid] = s;
        float t = 0.f;
        if (rr >= cc) {
            const int m = midx(rr, cc);
            for (int d = 0; d < 7; ++d) t += derl[m * 7 + d] * vl[d];
        }
        dLt[tid] = t;
        float u = 0.f;
        for (int r2 = cc; r2 < 7; ++r2) u += vl[r2] * derl[midx(r2, cc) * 7 + rr];
        uu[tid] = u;
    } else if (tid >= 49 && tid < 56) {
        const int j = tid - 49;
        float s = 0.f;
        for (int r2 = 0; r2 < 7; ++r2) s += Lm[r2 * 7 + j] * vl[r2];
        wvv[j] = s;
    }
    __syncthreads();
    if (tid < 7) {
        float s = 0.f;
        for (int r2 = 0; r2 < 7; ++r2) s += dLt[r2 * 7 + tid] * vl[r2];
        pv[tid] = s;
    }
    __syncthreads();
    if (tid < 7) {
        float s = 0.f, q = 0.f, md = 0.f;
        for (int c = 0; c < 7; ++c) {
            s += Lm[tid * 7 + c] * pv[c] + dLt[tid * 7 + c] * wvv[c];
            q += uu[tid * 7 + c] * wvv[c];
            md += Mm[tid * 7 + c] * ac[c];
        }
        Cv[tid] = s - q;
        Gv[tid] = derl[28 * 7 + tid];
        tauv[tid] = md + Cv[tid] + Gv[tid];
    }
    __syncthreads();
    if (tid < 49) out[57344 + (long)b * 49 + tid] = Mm[tid];
    if (tid < 7) {
        out[(long)b * 7 + tid] = tauv[tid];
        out[458752 + (long)b * 7 + tid] = Cv[tid];
        out[516096 + (long)b * 7 + tid] = Gv[tid];
    }
}

extern "C" void kernel_launch(void* const* d_in, const int* in_sizes, int n_in,
                              void* d_out, int out_size, void* d_ws, size_t ws_size,
                              hipStream_t stream)
{
    const float* state = (const float*)d_in[0];
    const float* vel   = (const float*)d_in[1];
    const float* accel = (const float*)d_in[2];
    const float* W_in  = (const float*)d_in[3];
    const float* b_in  = (const float*)d_in[4];
    const float* W_h   = (const float*)d_in[5];
    const float* b_h   = (const float*)d_in[6];
    const float* W_g   = (const float*)d_in[7];
    /* d_in[8] = b_g unused */
    const float* W_ld  = (const float*)d_in[9];
    const float* b_ld  = (const float*)d_in[10];
    const float* W_lo  = (const float*)d_in[11];
    const float* b_lo  = (const float*)d_in[12];
    float* outp = (float*)d_out;

    char* ws = (char*)d_ws;
    __hip_bfloat16* Wth = (__hip_bfloat16*)ws; ws += (size_t)WIDTH * WIDTH * 2;
    __hip_bfloat16* Wtl = (__hip_bfloat16*)ws; ws += (size_t)WIDTH * WIDTH * 2;
    __hip_bfloat16* Wch = (__hip_bfloat16*)ws; ws += 32 * WIDTH * 2;
    __hip_bfloat16* Wcl = (__hip_bfloat16*)ws; ws += 32 * WIDTH * 2;
    const size_t fixed = (size_t)(ws - (char*)d_ws);

    // per-sample ws: Y 4*2048 + D 2*14336 + P 1024 = 37888 B
    int CH = 128;
    for (int cand = 8192; cand >= 128; cand >>= 1) {
        size_t need = fixed + (size_t)cand * 37888;
        if (need <= ws_size) { CH = cand; break; }
    }
    const int NCH = BATCH / CH;

    const size_t YB = (size_t)CH * WIDTH * 2;
    const size_t DB = (size_t)CH * 7 * WIDTH * 2;
    __hip_bfloat16* Yah = (__hip_bfloat16*)ws; ws += YB;   // Y1 -> Y3
    __hip_bfloat16* Yal = (__hip_bfloat16*)ws; ws += YB;
    __hip_bfloat16* Ybh = (__hip_bfloat16*)ws; ws += YB;   // Y2
    __hip_bfloat16* Ybl = (__hip_bfloat16*)ws; ws += YB;
    __hip_bfloat16* Dah = (__hip_bfloat16*)ws; ws += DB;   // D1 -> D3 (hi only)
    __hip_bfloat16* Dbh = (__hip_bfloat16*)ws; ws += DB;   // D2 (hi only)
    float* PY = (float*)ws; ws += (size_t)CH * 32 * 4;
    float* PD = (float*)ws; ws += (size_t)CH * 7 * 32 * 4;

    transpose_k<<<dim3(32, 32), dim3(256), 0, stream>>>(W_h, Wth, Wtl);
    buildwcat_k<<<dim3(128), dim3(256), 0, stream>>>(W_ld, W_lo, W_g, Wch, Wcl);

    for (int c = 0; c < NCH; ++c) {
        prep_k<<<dim3(CH), dim3(256), 0, stream>>>(state + (size_t)c * CH * 7, W_in, b_in,
                                                   Yah, Yal, Dah);
        gemm_y<<<dim3(CH / 128, 8), dim3(256), 0, stream>>>(
            Yah, Yal, Wth, Wtl, b_h, Ybh, Ybl);                                // Y2
        gemm_d<<<dim3(CH * 7 / 128, 8), dim3(256), 0, stream>>>(
            Dah, Wth, Ybh, Dbh);                                               // D2 (mask Y2)
        gemm_y<<<dim3(CH / 128, 8), dim3(256), 0, stream>>>(
            Ybh, Ybl, Wth, Wtl, b_h, Yah, Yal);                                // Y3
        gemm_d<<<dim3(CH * 7 / 128, 8), dim3(256), 0, stream>>>(
            Dbh, Wth, Yah, Dah);                                               // D3 (mask Y3)
        gemm_head<1><<<dim3(CH / 128), dim3(256), 0, stream>>>(Yah, Yal, Wch, Wcl, PY);
        gemm_head<0><<<dim3(CH * 7 / 128), dim3(256), 0, stream>>>(Dah, nullptr, Wch, Wcl, PD);
        finalize_k<<<dim3(CH), dim3(64), 0, stream>>>(PY, PD, vel, accel, b_ld, b_lo,
                                                      outp, c * CH);
    }
    (void)in_sizes; (void)n_in; (void)out_size;
}

// Round 10
// 726.386 us; speedup vs baseline: 3.0312x; 1.0030x over previous
//
#include <hip/hip_runtime.h>
#include <hip/hip_bf16.h>

#define WIDTH 1024
#define BATCH 8192

typedef __attribute__((ext_vector_type(8))) short short8;
typedef __attribute__((ext_vector_type(4))) float floatx4;

typedef __attribute__((address_space(1))) void gvoid;
typedef __attribute__((address_space(3))) void lvoid;

__device__ __forceinline__ void async_copy16(const void* g, void* l) {
    __builtin_amdgcn_global_load_lds((gvoid*)g, (lvoid*)l, 16, 0, 0);
}

__device__ __forceinline__ void split_store(float v, __hip_bfloat16* hi, __hip_bfloat16* lo, long idx) {
    __hip_bfloat16 h = __float2bfloat16(v);
    hi[idx] = h;
    lo[idx] = __float2bfloat16(v - __bfloat162float(h));
}

// ---------------- transpose W_h (fp32) -> Wt_hi/lo[n][k] bf16 ----------------
__global__ __launch_bounds__(256) void transpose_k(
    const float* __restrict__ W,
    __hip_bfloat16* __restrict__ Wth, __hip_bfloat16* __restrict__ Wtl)
{
    __shared__ float t[32][33];
    const int tx = threadIdx.x & 31, ty = threadIdx.x >> 5;
    const int bx = blockIdx.x << 5, by = blockIdx.y << 5;
#pragma unroll
    for (int r = 0; r < 32; r += 8)
        t[ty + r][tx] = W[(long)(by + ty + r) * WIDTH + bx + tx];
    __syncthreads();
#pragma unroll
    for (int r = 0; r < 32; r += 8)
        split_store(t[tx][ty + r], Wth, Wtl, (long)(bx + ty + r) * WIDTH + by + tx);
}

// ---------------- pack head weights: Wcat[32][1024] hi/lo ----------------
__global__ __launch_bounds__(256) void buildwcat_k(
    const float* __restrict__ W_ld, const float* __restrict__ W_lo,
    const float* __restrict__ W_g,
    __hip_bfloat16* __restrict__ Wch, __hip_bfloat16* __restrict__ Wcl)
{
    const int idx = blockIdx.x * 256 + threadIdx.x;   // 32*1024
    const int n = idx >> 10, k = idx & 1023;
    float v = 0.f;
    if (n < 7)       v = W_ld[k * 7 + n];
    else if (n < 28) v = W_lo[k * 21 + (n - 7)];
    else if (n == 28) v = W_g[k];
    split_store(v, Wch, Wcl, idx);
}

// ---------------- layer 1: Y1 split, D1 hi-only ----------------
__global__ __launch_bounds__(256) void prep_k(
    const float* __restrict__ state,
    const float* __restrict__ W_in,
    const float* __restrict__ b_in,
    __hip_bfloat16* __restrict__ Y1h, __hip_bfloat16* __restrict__ Y1l,
    __hip_bfloat16* __restrict__ D1h)
{
    const int b = blockIdx.x;
    const int j0 = threadIdx.x * 4;
    float s[7];
#pragma unroll
    for (int d = 0; d < 7; ++d) s[d] = state[b * 7 + d];
    float a[4];
#pragma unroll
    for (int q = 0; q < 4; ++q) a[q] = b_in[j0 + q];
    float w[7][4];
#pragma unroll
    for (int d = 0; d < 7; ++d)
#pragma unroll
        for (int q = 0; q < 4; ++q) {
            w[d][q] = W_in[d * WIDTH + j0 + q];
            a[q] += s[d] * w[d][q];
        }
    bool gp[4];
#pragma unroll
    for (int q = 0; q < 4; ++q) {
        gp[q] = a[q] > 0.f;
        split_store(gp[q] ? a[q] : 0.f, Y1h, Y1l, (long)b * WIDTH + j0 + q);
    }
    union { unsigned long long u64; unsigned short h[4]; } pk;
#pragma unroll
    for (int d = 0; d < 7; ++d) {
#pragma unroll
        for (int q = 0; q < 4; ++q) {
            __hip_bfloat16 v = __float2bfloat16(gp[q] ? w[d][q] : 0.f);
            pk.h[q] = *reinterpret_cast<unsigned short*>(&v);
        }
        *reinterpret_cast<unsigned long long*>(&D1h[((long)b * 7 + d) * WIDTH + j0]) = pk.u64;
    }
}

// ---------------- Y GEMM (3-pass split, relu+bias epi, split out) ----------------
__global__ __launch_bounds__(256) void gemm_y(
    const __hip_bfloat16* __restrict__ Ah, const __hip_bfloat16* __restrict__ Al,
    const __hip_bfloat16* __restrict__ Bh, const __hip_bfloat16* __restrict__ Bl,
    const float* __restrict__ bias,
    __hip_bfloat16* __restrict__ outh, __hip_bfloat16* __restrict__ outl)
{
    __shared__ __align__(16) short Ash[128 * 32], Asl[128 * 32];
    __shared__ __align__(16) short Bsh[128 * 32], Bsl[128 * 32];
    const int tid = threadIdx.x;
    const int lane = tid & 63;
    const int wv = tid >> 6;
    const int wm = wv >> 1, wn = wv & 1;
    const int bm = blockIdx.x, bn = blockIdx.y;

    const int srow = tid >> 2;
    const int scol = (tid & 3) << 3;
    const short* pAh = (const short*)Ah + (long)(bm * 128 + srow) * WIDTH + scol;
    const short* pAl = (const short*)Al + (long)(bm * 128 + srow) * WIDTH + scol;
    const short* pBh = (const short*)Bh + (long)(bn * 128 + srow) * WIDTH + scol;
    const short* pBl = (const short*)Bl + (long)(bn * 128 + srow) * WIDTH + scol;
    const long half = 64l * WIDTH;

    floatx4 acc[4][4] = {};
    const int r = lane & 15;
    const int kq = (lane >> 4) << 3;

    for (int kt = 0; kt < WIDTH; kt += 32) {
        __syncthreads();
        async_copy16(pAh + kt,        Ash + wv * 512);
        async_copy16(pAh + half + kt, Ash + 2048 + wv * 512);
        async_copy16(pAl + kt,        Asl + wv * 512);
        async_copy16(pAl + half + kt, Asl + 2048 + wv * 512);
        async_copy16(pBh + kt,        Bsh + wv * 512);
        async_copy16(pBh + half + kt, Bsh + 2048 + wv * 512);
        async_copy16(pBl + kt,        Bsl + wv * 512);
        async_copy16(pBl + half + kt, Bsl + 2048 + wv * 512);
        __syncthreads();
        short8 afh[4], afl[4], bfh[4], bfl[4];
#pragma unroll
        for (int i = 0; i < 4; ++i) {
            const int ar = (wm * 64 + i * 16 + r) * 32 + kq;
            afh[i] = *reinterpret_cast<const short8*>(&Ash[ar]);
            afl[i] = *reinterpret_cast<const short8*>(&Asl[ar]);
        }
#pragma unroll
        for (int j = 0; j < 4; ++j) {
            const int br = (wn * 64 + j * 16 + r) * 32 + kq;
            bfh[j] = *reinterpret_cast<const short8*>(&Bsh[br]);
            bfl[j] = *reinterpret_cast<const short8*>(&Bsl[br]);
        }
#pragma unroll
        for (int i = 0; i < 4; ++i)
#pragma unroll
            for (int j = 0; j < 4; ++j) {
                acc[i][j] = __builtin_amdgcn_mfma_f32_16x16x32_bf16(afh[i], bfh[j], acc[i][j], 0, 0, 0);
                acc[i][j] = __builtin_amdgcn_mfma_f32_16x16x32_bf16(afh[i], bfl[j], acc[i][j], 0, 0, 0);
                acc[i][j] = __builtin_amdgcn_mfma_f32_16x16x32_bf16(afl[i], bfh[j], acc[i][j], 0, 0, 0);
            }
    }

    const int r4 = (lane >> 4) << 2;
#pragma unroll
    for (int i = 0; i < 4; ++i)
#pragma unroll
        for (int j = 0; j < 4; ++j) {
            const int col = bn * 128 + wn * 64 + j * 16 + r;
#pragma unroll
            for (int rr = 0; rr < 4; ++rr) {
                const int row = bm * 128 + wm * 64 + i * 16 + r4 + rr;
                float v = acc[i][j][rr] + bias[col];
                v = v > 0.f ? v : 0.f;
                split_store(v, outh, outl, (long)row * WIDTH + col);
            }
        }
}

// ---------------- D GEMM (1-pass bf16, BK=64 as two stride-32 sub-tiles; mask epi) ----------------
__global__ __launch_bounds__(256) void gemm_d(
    const __hip_bfloat16* __restrict__ Ah,
    const __hip_bfloat16* __restrict__ Bh,
    const __hip_bfloat16* __restrict__ mask,
    __hip_bfloat16* __restrict__ outh)
{
    __shared__ __align__(16) short Ash[2][128 * 32];
    __shared__ __align__(16) short Bsh[2][128 * 32];
    const int tid = threadIdx.x;
    const int lane = tid & 63;
    const int wv = tid >> 6;
    const int wm = wv >> 1, wn = wv & 1;
    const int bm = blockIdx.x, bn = blockIdx.y;

    const int srow = tid >> 2;
    const int scol = (tid & 3) << 3;
    const short* pAh = (const short*)Ah + (long)(bm * 128 + srow) * WIDTH + scol;
    const short* pBh = (const short*)Bh + (long)(bn * 128 + srow) * WIDTH + scol;
    const long half = 64l * WIDTH;

    floatx4 acc[4][4] = {};
    const int r = lane & 15;
    const int kq = (lane >> 4) << 3;

    for (int kt = 0; kt < WIDTH; kt += 64) {
        __syncthreads();
        async_copy16(pAh + kt,             Ash[0] + wv * 512);
        async_copy16(pAh + half + kt,      Ash[0] + 2048 + wv * 512);
        async_copy16(pAh + kt + 32,        Ash[1] + wv * 512);
        async_copy16(pAh + half + kt + 32, Ash[1] + 2048 + wv * 512);
        async_copy16(pBh + kt,             Bsh[0] + wv * 512);
        async_copy16(pBh + half + kt,      Bsh[0] + 2048 + wv * 512);
        async_copy16(pBh + kt + 32,        Bsh[1] + wv * 512);
        async_copy16(pBh + half + kt + 32, Bsh[1] + 2048 + wv * 512);
        __syncthreads();
#pragma unroll
        for (int s = 0; s < 2; ++s) {
            short8 afh[4], bfh[4];
#pragma unroll
            for (int i = 0; i < 4; ++i)
                afh[i] = *reinterpret_cast<const short8*>(&Ash[s][(wm * 64 + i * 16 + r) * 32 + kq]);
#pragma unroll
            for (int j = 0; j < 4; ++j)
                bfh[j] = *reinterpret_cast<const short8*>(&Bsh[s][(wn * 64 + j * 16 + r) * 32 + kq]);
#pragma unroll
            for (int i = 0; i < 4; ++i)
#pragma unroll
                for (int j = 0; j < 4; ++j)
                    acc[i][j] = __builtin_amdgcn_mfma_f32_16x16x32_bf16(afh[i], bfh[j], acc[i][j], 0, 0, 0);
        }
    }

    const int r4 = (lane >> 4) << 2;
#pragma unroll
    for (int i = 0; i < 4; ++i)
#pragma unroll
        for (int j = 0; j < 4; ++j) {
            const int col = bn * 128 + wn * 64 + j * 16 + r;
#pragma unroll
            for (int rr = 0; rr < 4; ++rr) {
                const int row = bm * 128 + wm * 64 + i * 16 + r4 + rr;
                float v = acc[i][j][rr];
                const unsigned brow = (unsigned)row / 7u;
                if (!(__bfloat162float(mask[(long)brow * WIDTH + col]) > 0.f)) v = 0.f;
                outh[(long)row * WIDTH + col] = __float2bfloat16(v);
            }
        }
}

// ---------------- head-projection GEMM 128x32 ----------------
// SPLITA=1: A split (3-pass, for Y3). SPLITA=0: A hi-only (2-pass, for D3).
template <int SPLITA>
__global__ __launch_bounds__(256) void gemm_head(
    const __hip_bfloat16* __restrict__ Ah, const __hip_bfloat16* __restrict__ Al,
    const __hip_bfloat16* __restrict__ Bh, const __hip_bfloat16* __restrict__ Bl, // Wcat[32][1024]
    float* __restrict__ P)
{
    __shared__ __align__(16) short Ash[128 * 32], Asl[SPLITA ? 128 * 32 : 16];
    __shared__ __align__(16) short Bsh[32 * 32], Bsl[32 * 32];
    const int tid = threadIdx.x;
    const int lane = tid & 63;
    const int wv = tid >> 6;
    const int bm = blockIdx.x;

    const int srow = tid >> 2;
    const int scol = (tid & 3) << 3;
    const short* pAh = (const short*)Ah + (long)(bm * 128 + srow) * WIDTH + scol;
    const short* pAl = (const short*)Al + (long)(bm * 128 + srow) * WIDTH + scol;
    const long boff = (long)srow * WIDTH + scol;
    const short* pBh = (const short*)Bh;  const short* pBl = (const short*)Bl;
    const long half = 64l * WIDTH;

    floatx4 acc[2][2] = {};
    const int r = lane & 15;
    const int kq = (lane >> 4) << 3;

    for (int kt = 0; kt < WIDTH; kt += 32) {
        short8 gbh, gbl;
        if (tid < 128) {
            gbh = *reinterpret_cast<const short8*>(pBh + boff + kt);
            gbl = *reinterpret_cast<const short8*>(pBl + boff + kt);
        }
        __syncthreads();
        async_copy16(pAh + kt,        Ash + wv * 512);
        async_copy16(pAh + half + kt, Ash + 2048 + wv * 512);
        if (SPLITA) {
            async_copy16(pAl + kt,        Asl + wv * 512);
            async_copy16(pAl + half + kt, Asl + 2048 + wv * 512);
        }
        if (tid < 128) {
            *reinterpret_cast<short8*>(&Bsh[srow * 32 + scol]) = gbh;
            *reinterpret_cast<short8*>(&Bsl[srow * 32 + scol]) = gbl;
        }
        __syncthreads();
        short8 afh[2], afl[2], bfh[2], bfl[2];
#pragma unroll
        for (int i = 0; i < 2; ++i) {
            const int ar = (wv * 32 + i * 16 + r) * 32 + kq;
            afh[i] = *reinterpret_cast<const short8*>(&Ash[ar]);
            if (SPLITA) afl[i] = *reinterpret_cast<const short8*>(&Asl[ar]);
        }
#pragma unroll
        for (int j = 0; j < 2; ++j) {
            const int br = (j * 16 + r) * 32 + kq;
            bfh[j] = *reinterpret_cast<const short8*>(&Bsh[br]);
            bfl[j] = *reinterpret_cast<const short8*>(&Bsl[br]);
        }
#pragma unroll
        for (int i = 0; i < 2; ++i)
#pragma unroll
            for (int j = 0; j < 2; ++j) {
                acc[i][j] = __builtin_amdgcn_mfma_f32_16x16x32_bf16(afh[i], bfh[j], acc[i][j], 0, 0, 0);
                acc[i][j] = __builtin_amdgcn_mfma_f32_16x16x32_bf16(afh[i], bfl[j], acc[i][j], 0, 0, 0);
                if (SPLITA)
                    acc[i][j] = __builtin_amdgcn_mfma_f32_16x16x32_bf16(afl[i], bfh[j], acc[i][j], 0, 0, 0);
            }
    }

    const int r4 = (lane >> 4) << 2;
#pragma unroll
    for (int i = 0; i < 2; ++i)
#pragma unroll
        for (int j = 0; j < 2; ++j) {
            const int col = j * 16 + r;
#pragma unroll
            for (int rr = 0; rr < 4; ++rr) {
                const int row = bm * 128 + wv * 32 + i * 16 + r4 + rr;
                P[(long)row * 32 + col] = acc[i][j][rr];
            }
        }
}

// ---------------- finalize: 7x7 algebra from projections ----------------
__device__ __forceinline__ int midx(int rr, int cc) {
    const int i = rr - cc;
    return i * 7 - (i * (i - 1)) / 2 + cc;
}

__global__ __launch_bounds__(64) void finalize_k(
    const float* __restrict__ PY,
    const float* __restrict__ PD,
    const float* __restrict__ vel_g,
    const float* __restrict__ acc_g,
    const float* __restrict__ b_ld,
    const float* __restrict__ b_lo,
    float* __restrict__ out,
    int b0)
{
    __shared__ float lval[28];
    __shared__ int gpv[7];
    __shared__ float derl[29 * 7];
    __shared__ float Lm[49], Mm[49], dLt[49], uu[49];
    __shared__ float wvv[7], pv[7], Cv[7], Gv[7], tauv[7], vl[7], ac[7];

    const int bl = blockIdx.x, tid = threadIdx.x;
    const int b = b0 + bl;
    if (tid < 28) {
        float s = PY[(long)bl * 32 + tid];
        if (tid < 7) {
            s += b_ld[tid];
            gpv[tid] = s > 0.f;
            lval[tid] = s > 0.f ? s : 0.f;
        } else {
            lval[tid] = s + b_lo[tid - 7];
        }
    }
    if (tid >= 28 && tid < 35) {
        vl[tid - 28] = vel_g[b * 7 + tid - 28];
        ac[tid - 28] = acc_g[b * 7 + tid - 28];
    }
    __syncthreads();
    for (int idx = tid; idx < 203; idx += 64) {
        const int m = idx / 7, d = idx % 7;
        float v = PD[((long)bl * 7 + d) * 32 + m];
        if (m < 7 && !gpv[m]) v = 0.f;
        derl[m * 7 + d] = v;
    }
    __syncthreads();
    if (tid < 49) {
        const int rr = tid / 7, cc = tid % 7;
        Lm[tid] = (rr >= cc) ? lval[midx(rr, cc)] : 0.f;
    }
    __syncthreads();
    if (tid < 49) {
        const int rr = tid / 7, cc = tid % 7;
        float s = 0.f;
        for (int k = 0; k < 7; ++k) s += Lm[rr * 7 + k] * Lm[cc * 7 + k];
        if (rr == cc) s += 1e-5f;
        Mm[tid] = s;
        float t = 0.f;
        if (rr >= cc) {
            const int m = midx(rr, cc);
            for (int d = 0; d < 7; ++d) t += derl[m * 7 + d] * vl[d];
        }
        dLt[tid] = t;
        float u = 0.f;
        for (int r2 = cc; r2 < 7; ++r2) u += vl[r2] * derl[midx(r2, cc) * 7 + rr];
        uu[tid] = u;
    } else if (tid >= 49 && tid < 56) {
        const int j = tid - 49;
        float s = 0.f;
        for (int r2 = 0; r2 < 7; ++r2) s += Lm[r2 * 7 + j] * vl[r2];
        wvv[j] = s;
    }
    __syncthreads();
    if (tid < 7) {
        float s = 0.f;
        for (int r2 = 0; r2 < 7; ++r2) s += dLt[r2 * 7 + tid] * vl[r2];
        pv[tid] = s;
    }
    __syncthreads();
    if (tid < 7) {
        float s = 0.f, q = 0.f, md = 0.f;
        for (int c = 0; c < 7; ++c) {
            s += Lm[tid * 7 + c] * pv[c] + dLt[tid * 7 + c] * wvv[c];
            q += uu[tid * 7 + c] * wvv[c];
            md += Mm[tid * 7 + c] * ac[c];
        }
        Cv[tid] = s - q;
        Gv[tid] = derl[28 * 7 + tid];
        tauv[tid] = md + Cv[tid] + Gv[tid];
    }
    __syncthreads();
    if (tid < 49) out[57344 + (long)b * 49 + tid] = Mm[tid];
    if (tid < 7) {
        out[(long)b * 7 + tid] = tauv[tid];
        out[458752 + (long)b * 7 + tid] = Cv[tid];
        out[516096 + (long)b * 7 + tid] = Gv[tid];
    }
}

extern "C" void kernel_launch(void* const* d_in, const int* in_sizes, int n_in,
                              void* d_out, int out_size, void* d_ws, size_t ws_size,
                              hipStream_t stream)
{
    const float* state = (const float*)d_in[0];
    const float* vel   = (const float*)d_in[1];
    const float* accel = (const float*)d_in[2];
    const float* W_in  = (const float*)d_in[3];
    const float* b_in  = (const float*)d_in[4];
    const float* W_h   = (const float*)d_in[5];
    const float* b_h   = (const float*)d_in[6];
    const float* W_g   = (const float*)d_in[7];
    /* d_in[8] = b_g unused */
    const float* W_ld  = (const float*)d_in[9];
    const float* b_ld  = (const float*)d_in[10];
    const float* W_lo  = (const float*)d_in[11];
    const float* b_lo  = (const float*)d_in[12];
    float* outp = (float*)d_out;

    char* ws = (char*)d_ws;
    __hip_bfloat16* Wth = (__hip_bfloat16*)ws; ws += (size_t)WIDTH * WIDTH * 2;
    __hip_bfloat16* Wtl = (__hip_bfloat16*)ws; ws += (size_t)WIDTH * WIDTH * 2;
    __hip_bfloat16* Wch = (__hip_bfloat16*)ws; ws += 32 * WIDTH * 2;
    __hip_bfloat16* Wcl = (__hip_bfloat16*)ws; ws += 32 * WIDTH * 2;
    const size_t fixed = (size_t)(ws - (char*)d_ws);

    // per-sample ws: Y 4*2048 + D 2*14336 + P 1024 = 37888 B
    int CH = 128;
    for (int cand = 8192; cand >= 128; cand >>= 1) {
        size_t need = fixed + (size_t)cand * 37888;
        if (need <= ws_size) { CH = cand; break; }
    }
    const int NCH = BATCH / CH;

    const size_t YB = (size_t)CH * WIDTH * 2;
    const size_t DB = (size_t)CH * 7 * WIDTH * 2;
    __hip_bfloat16* Yah = (__hip_bfloat16*)ws; ws += YB;   // Y1 -> Y3
    __hip_bfloat16* Yal = (__hip_bfloat16*)ws; ws += YB;
    __hip_bfloat16* Ybh = (__hip_bfloat16*)ws; ws += YB;   // Y2
    __hip_bfloat16* Ybl = (__hip_bfloat16*)ws; ws += YB;
    __hip_bfloat16* Dah = (__hip_bfloat16*)ws; ws += DB;   // D1 -> D3 (hi only)
    __hip_bfloat16* Dbh = (__hip_bfloat16*)ws; ws += DB;   // D2 (hi only)
    float* PY = (float*)ws; ws += (size_t)CH * 32 * 4;
    float* PD = (float*)ws; ws += (size_t)CH * 7 * 32 * 4;

    transpose_k<<<dim3(32, 32), dim3(256), 0, stream>>>(W_h, Wth, Wtl);
    buildwcat_k<<<dim3(128), dim3(256), 0, stream>>>(W_ld, W_lo, W_g, Wch, Wcl);

    for (int c = 0; c < NCH; ++c) {
        prep_k<<<dim3(CH), dim3(256), 0, stream>>>(state + (size_t)c * CH * 7, W_in, b_in,
                                                   Yah, Yal, Dah);
        gemm_y<<<dim3(CH / 128, 8), dim3(256), 0, stream>>>(
            Yah, Yal, Wth, Wtl, b_h, Ybh, Ybl);                                // Y2
        gemm_d<<<dim3(CH * 7 / 128, 8), dim3(256), 0, stream>>>(
            Dah, Wth, Ybh, Dbh);                                               // D2 (mask Y2)
        gemm_y<<<dim3(CH / 128, 8), dim3(256), 0, stream>>>(
            Ybh, Ybl, Wth, Wtl, b_h, Yah, Yal);                                // Y3
        gemm_d<<<dim3(CH * 7 / 128, 8), dim3(256), 0, stream>>>(
            Dbh, Wth, Yah, Dah);                                               // D3 (mask Y3)
        gemm_head<1><<<dim3(CH / 128), dim3(256), 0, stream>>>(Yah, Yal, Wch, Wcl, PY);
        gemm_head<0><<<dim3(CH * 7 / 128), dim3(256), 0, stream>>>(Dah, nullptr, Wch, Wcl, PD);
        finalize_k<<<dim3(CH), dim3(64), 0, stream>>>(PY, PD, vel, accel, b_ld, b_lo,
                                                      outp, c * CH);
    }
    (void)in_sizes; (void)n_in; (void)out_size;
}

// Round 11
// 716.080 us; speedup vs baseline: 3.0748x; 1.0144x over previous
//
#include <hip/hip_runtime.h>
#include <hip/hip_bf16.h>

#define WIDTH 1024
#define BATCH 8192

typedef __attribute__((ext_vector_type(8))) short short8;
typedef __attribute__((ext_vector_type(4))) float floatx4;

typedef __attribute__((address_space(1))) void gvoid;
typedef __attribute__((address_space(3))) void lvoid;

__device__ __forceinline__ void async_copy16(const void* g, void* l) {
    __builtin_amdgcn_global_load_lds((gvoid*)g, (lvoid*)l, 16, 0, 0);
}

__device__ __forceinline__ void split_store(float v, __hip_bfloat16* hi, __hip_bfloat16* lo, long idx) {
    __hip_bfloat16 h = __float2bfloat16(v);
    hi[idx] = h;
    lo[idx] = __float2bfloat16(v - __bfloat162float(h));
}

// ---------------- transpose W_h (fp32) -> Wt_hi/lo[n][k] bf16 ----------------
__global__ __launch_bounds__(256) void transpose_k(
    const float* __restrict__ W,
    __hip_bfloat16* __restrict__ Wth, __hip_bfloat16* __restrict__ Wtl)
{
    __shared__ float t[32][33];
    const int tx = threadIdx.x & 31, ty = threadIdx.x >> 5;
    const int bx = blockIdx.x << 5, by = blockIdx.y << 5;
#pragma unroll
    for (int r = 0; r < 32; r += 8)
        t[ty + r][tx] = W[(long)(by + ty + r) * WIDTH + bx + tx];
    __syncthreads();
#pragma unroll
    for (int r = 0; r < 32; r += 8)
        split_store(t[tx][ty + r], Wth, Wtl, (long)(bx + ty + r) * WIDTH + by + tx);
}

// ---------------- pack head weights: Wcat[32][1024] hi/lo ----------------
__global__ __launch_bounds__(256) void buildwcat_k(
    const float* __restrict__ W_ld, const float* __restrict__ W_lo,
    const float* __restrict__ W_g,
    __hip_bfloat16* __restrict__ Wch, __hip_bfloat16* __restrict__ Wcl)
{
    const int idx = blockIdx.x * 256 + threadIdx.x;   // 32*1024
    const int n = idx >> 10, k = idx & 1023;
    float v = 0.f;
    if (n < 7)       v = W_ld[k * 7 + n];
    else if (n < 28) v = W_lo[k * 21 + (n - 7)];
    else if (n == 28) v = W_g[k];
    split_store(v, Wch, Wcl, idx);
}

// ---------------- layer 1: Y1 split, D1 hi-only ----------------
__global__ __launch_bounds__(256) void prep_k(
    const float* __restrict__ state,
    const float* __restrict__ W_in,
    const float* __restrict__ b_in,
    __hip_bfloat16* __restrict__ Y1h, __hip_bfloat16* __restrict__ Y1l,
    __hip_bfloat16* __restrict__ D1h)
{
    const int b = blockIdx.x;
    const int j0 = threadIdx.x * 4;
    float s[7];
#pragma unroll
    for (int d = 0; d < 7; ++d) s[d] = state[b * 7 + d];
    float a[4];
#pragma unroll
    for (int q = 0; q < 4; ++q) a[q] = b_in[j0 + q];
    float w[7][4];
#pragma unroll
    for (int d = 0; d < 7; ++d)
#pragma unroll
        for (int q = 0; q < 4; ++q) {
            w[d][q] = W_in[d * WIDTH + j0 + q];
            a[q] += s[d] * w[d][q];
        }
    bool gp[4];
#pragma unroll
    for (int q = 0; q < 4; ++q) {
        gp[q] = a[q] > 0.f;
        split_store(gp[q] ? a[q] : 0.f, Y1h, Y1l, (long)b * WIDTH + j0 + q);
    }
    union { unsigned long long u64; unsigned short h[4]; } pk;
#pragma unroll
    for (int d = 0; d < 7; ++d) {
#pragma unroll
        for (int q = 0; q < 4; ++q) {
            __hip_bfloat16 v = __float2bfloat16(gp[q] ? w[d][q] : 0.f);
            pk.h[q] = *reinterpret_cast<unsigned short*>(&v);
        }
        *reinterpret_cast<unsigned long long*>(&D1h[((long)b * 7 + d) * WIDTH + j0]) = pk.u64;
    }
}

// ---------------- Y GEMM (3-pass split, relu+bias epi, split out) ----------------
__global__ __launch_bounds__(256) void gemm_y(
    const __hip_bfloat16* __restrict__ Ah, const __hip_bfloat16* __restrict__ Al,
    const __hip_bfloat16* __restrict__ Bh, const __hip_bfloat16* __restrict__ Bl,
    const float* __restrict__ bias,
    __hip_bfloat16* __restrict__ outh, __hip_bfloat16* __restrict__ outl)
{
    __shared__ __align__(16) short Ash[128 * 32], Asl[128 * 32];
    __shared__ __align__(16) short Bsh[128 * 32], Bsl[128 * 32];
    const int tid = threadIdx.x;
    const int lane = tid & 63;
    const int wv = tid >> 6;
    const int wm = wv >> 1, wn = wv & 1;
    const int bm = blockIdx.x, bn = blockIdx.y;

    const int srow = tid >> 2;
    const int scol = (tid & 3) << 3;
    const short* pAh = (const short*)Ah + (long)(bm * 128 + srow) * WIDTH + scol;
    const short* pAl = (const short*)Al + (long)(bm * 128 + srow) * WIDTH + scol;
    const short* pBh = (const short*)Bh + (long)(bn * 128 + srow) * WIDTH + scol;
    const short* pBl = (const short*)Bl + (long)(bn * 128 + srow) * WIDTH + scol;
    const long half = 64l * WIDTH;

    floatx4 acc[4][4] = {};
    const int r = lane & 15;
    const int kq = (lane >> 4) << 3;

    for (int kt = 0; kt < WIDTH; kt += 32) {
        __syncthreads();
        async_copy16(pAh + kt,        Ash + wv * 512);
        async_copy16(pAh + half + kt, Ash + 2048 + wv * 512);
        async_copy16(pAl + kt,        Asl + wv * 512);
        async_copy16(pAl + half + kt, Asl + 2048 + wv * 512);
        async_copy16(pBh + kt,        Bsh + wv * 512);
        async_copy16(pBh + half + kt, Bsh + 2048 + wv * 512);
        async_copy16(pBl + kt,        Bsl + wv * 512);
        async_copy16(pBl + half + kt, Bsl + 2048 + wv * 512);
        __syncthreads();
        short8 afh[4], afl[4], bfh[4], bfl[4];
#pragma unroll
        for (int i = 0; i < 4; ++i) {
            const int ar = (wm * 64 + i * 16 + r) * 32 + kq;
            afh[i] = *reinterpret_cast<const short8*>(&Ash[ar]);
            afl[i] = *reinterpret_cast<const short8*>(&Asl[ar]);
        }
#pragma unroll
        for (int j = 0; j < 4; ++j) {
            const int br = (wn * 64 + j * 16 + r) * 32 + kq;
            bfh[j] = *reinterpret_cast<const short8*>(&Bsh[br]);
            bfl[j] = *reinterpret_cast<const short8*>(&Bsl[br]);
        }
#pragma unroll
        for (int i = 0; i < 4; ++i)
#pragma unroll
            for (int j = 0; j < 4; ++j) {
                acc[i][j] = __builtin_amdgcn_mfma_f32_16x16x32_bf16(afh[i], bfh[j], acc[i][j], 0, 0, 0);
                acc[i][j] = __builtin_amdgcn_mfma_f32_16x16x32_bf16(afh[i], bfl[j], acc[i][j], 0, 0, 0);
                acc[i][j] = __builtin_amdgcn_mfma_f32_16x16x32_bf16(afl[i], bfh[j], acc[i][j], 0, 0, 0);
            }
    }

    const int r4 = (lane >> 4) << 2;
#pragma unroll
    for (int i = 0; i < 4; ++i)
#pragma unroll
        for (int j = 0; j < 4; ++j) {
            const int col = bn * 128 + wn * 64 + j * 16 + r;
#pragma unroll
            for (int rr = 0; rr < 4; ++rr) {
                const int row = bm * 128 + wm * 64 + i * 16 + r4 + rr;
                float v = acc[i][j][rr] + bias[col];
                v = v > 0.f ? v : 0.f;
                split_store(v, outh, outl, (long)row * WIDTH + col);
            }
        }
}

// ---------------- D2 GEMM (1-pass bf16, BK=64, bn-fastest grid; mask epi; hi out) ----------------
__global__ __launch_bounds__(256) void gemm_d2(
    const __hip_bfloat16* __restrict__ Ah,
    const __hip_bfloat16* __restrict__ Bh,
    const __hip_bfloat16* __restrict__ mask,
    __hip_bfloat16* __restrict__ outh)
{
    __shared__ __align__(16) short Ash[2][128 * 32];
    __shared__ __align__(16) short Bsh[2][128 * 32];
    const int tid = threadIdx.x;
    const int lane = tid & 63;
    const int wv = tid >> 6;
    const int wm = wv >> 1, wn = wv & 1;
    const int bn = blockIdx.x, bm = blockIdx.y;   // bn fastest: blocks sharing A-tile run together

    const int srow = tid >> 2;
    const int scol = (tid & 3) << 3;
    const short* pAh = (const short*)Ah + (long)(bm * 128 + srow) * WIDTH + scol;
    const short* pBh = (const short*)Bh + (long)(bn * 128 + srow) * WIDTH + scol;
    const long half = 64l * WIDTH;

    floatx4 acc[4][4] = {};
    const int r = lane & 15;
    const int kq = (lane >> 4) << 3;

    for (int kt = 0; kt < WIDTH; kt += 64) {
        __syncthreads();
        async_copy16(pAh + kt,             Ash[0] + wv * 512);
        async_copy16(pAh + half + kt,      Ash[0] + 2048 + wv * 512);
        async_copy16(pAh + kt + 32,        Ash[1] + wv * 512);
        async_copy16(pAh + half + kt + 32, Ash[1] + 2048 + wv * 512);
        async_copy16(pBh + kt,             Bsh[0] + wv * 512);
        async_copy16(pBh + half + kt,      Bsh[0] + 2048 + wv * 512);
        async_copy16(pBh + kt + 32,        Bsh[1] + wv * 512);
        async_copy16(pBh + half + kt + 32, Bsh[1] + 2048 + wv * 512);
        __syncthreads();
#pragma unroll
        for (int s = 0; s < 2; ++s) {
            short8 afh[4], bfh[4];
#pragma unroll
            for (int i = 0; i < 4; ++i)
                afh[i] = *reinterpret_cast<const short8*>(&Ash[s][(wm * 64 + i * 16 + r) * 32 + kq]);
#pragma unroll
            for (int j = 0; j < 4; ++j)
                bfh[j] = *reinterpret_cast<const short8*>(&Bsh[s][(wn * 64 + j * 16 + r) * 32 + kq]);
#pragma unroll
            for (int i = 0; i < 4; ++i)
#pragma unroll
                for (int j = 0; j < 4; ++j)
                    acc[i][j] = __builtin_amdgcn_mfma_f32_16x16x32_bf16(afh[i], bfh[j], acc[i][j], 0, 0, 0);
        }
    }

    const int r4 = (lane >> 4) << 2;
#pragma unroll
    for (int i = 0; i < 4; ++i)
#pragma unroll
        for (int j = 0; j < 4; ++j) {
            const int col = bn * 128 + wn * 64 + j * 16 + r;
#pragma unroll
            for (int rr = 0; rr < 4; ++rr) {
                const int row = bm * 128 + wm * 64 + i * 16 + r4 + rr;
                float v = acc[i][j][rr];
                const unsigned brow = (unsigned)row / 7u;
                if (!(__bfloat162float(mask[(long)brow * WIDTH + col]) > 0.f)) v = 0.f;
                outh[(long)row * WIDTH + col] = __float2bfloat16(v);
            }
        }
}

// ---------------- D3 GEMM + fused PD projection ----------------
// Same K-loop as gemm_d2, but instead of storing D3, the masked bf16 tile goes to
// LDS (stride 136: 2-way-free fragment reads) and is projected onto the block's
// 128-col Wcat slice (2-pass hi/lo, identical numerics to old gemm_head<0>).
// Partials land in PDpart[bn][row][32]; reduce_pd sums over bn.
__global__ __launch_bounds__(256) void gemm_d3(
    const __hip_bfloat16* __restrict__ Ah,
    const __hip_bfloat16* __restrict__ Bh,
    const __hip_bfloat16* __restrict__ mask,
    const __hip_bfloat16* __restrict__ Wch,
    const __hip_bfloat16* __restrict__ Wcl,
    float* __restrict__ PDpart, int Mrows)
{
    __shared__ __align__(16) short SM[26112];  // staging 16384 | proj: T 17408 + Wc 2*4352
    short* Ash0 = SM;
    short* Ash1 = SM + 4096;
    short* Bsh0 = SM + 8192;
    short* Bsh1 = SM + 12288;
    short* T    = SM;            // 128 x 136
    short* WcH  = SM + 17408;    // 32 x 136
    short* WcL  = SM + 21760;    // 32 x 136

    const int tid = threadIdx.x;
    const int lane = tid & 63;
    const int wv = tid >> 6;
    const int wm = wv >> 1, wn = wv & 1;
    const int bn = blockIdx.x, bm = blockIdx.y;

    const int srow = tid >> 2;
    const int scol = (tid & 3) << 3;
    const short* pAh = (const short*)Ah + (long)(bm * 128 + srow) * WIDTH + scol;
    const short* pBh = (const short*)Bh + (long)(bn * 128 + srow) * WIDTH + scol;
    const long half = 64l * WIDTH;

    floatx4 acc[4][4] = {};
    const int r = lane & 15;
    const int kq = (lane >> 4) << 3;

    for (int kt = 0; kt < WIDTH; kt += 64) {
        __syncthreads();
        async_copy16(pAh + kt,             Ash0 + wv * 512);
        async_copy16(pAh + half + kt,      Ash0 + 2048 + wv * 512);
        async_copy16(pAh + kt + 32,        Ash1 + wv * 512);
        async_copy16(pAh + half + kt + 32, Ash1 + 2048 + wv * 512);
        async_copy16(pBh + kt,             Bsh0 + wv * 512);
        async_copy16(pBh + half + kt,      Bsh0 + 2048 + wv * 512);
        async_copy16(pBh + kt + 32,        Bsh1 + wv * 512);
        async_copy16(pBh + half + kt + 32, Bsh1 + 2048 + wv * 512);
        __syncthreads();
#pragma unroll
        for (int s = 0; s < 2; ++s) {
            const short* As = s ? Ash1 : Ash0;
            const short* Bs = s ? Bsh1 : Bsh0;
            short8 afh[4], bfh[4];
#pragma unroll
            for (int i = 0; i < 4; ++i)
                afh[i] = *reinterpret_cast<const short8*>(&As[(wm * 64 + i * 16 + r) * 32 + kq]);
#pragma unroll
            for (int j = 0; j < 4; ++j)
                bfh[j] = *reinterpret_cast<const short8*>(&Bs[(wn * 64 + j * 16 + r) * 32 + kq]);
#pragma unroll
            for (int i = 0; i < 4; ++i)
#pragma unroll
                for (int j = 0; j < 4; ++j)
                    acc[i][j] = __builtin_amdgcn_mfma_f32_16x16x32_bf16(afh[i], bfh[j], acc[i][j], 0, 0, 0);
        }
    }

    // mask + write bf16 tile to LDS (D3 values, never hit HBM)
    __syncthreads();
    const int r4 = (lane >> 4) << 2;
#pragma unroll
    for (int i = 0; i < 4; ++i)
#pragma unroll
        for (int j = 0; j < 4; ++j) {
            const int coll = wn * 64 + j * 16 + r;
            const int colg = bn * 128 + coll;
#pragma unroll
            for (int rr = 0; rr < 4; ++rr) {
                const int rowl = wm * 64 + i * 16 + r4 + rr;
                const int rowg = bm * 128 + rowl;
                float v = acc[i][j][rr];
                const unsigned brow = (unsigned)rowg / 7u;
                if (!(__bfloat162float(mask[(long)brow * WIDTH + colg]) > 0.f)) v = 0.f;
                __hip_bfloat16 hb = __float2bfloat16(v);
                T[rowl * 136 + coll] = *reinterpret_cast<short*>(&hb);
            }
        }
    // stage Wcat slice (32 heads x 128 k)
    {
        const int n = tid >> 4, k8 = (tid & 15) * 8;
        const short* wh = (const short*)Wch;
        const short* wl = (const short*)Wcl;
        *reinterpret_cast<short8*>(&WcH[n * 136 + k8]) =
            *reinterpret_cast<const short8*>(wh + n * WIDTH + bn * 128 + k8);
        *reinterpret_cast<short8*>(&WcH[(n + 16) * 136 + k8]) =
            *reinterpret_cast<const short8*>(wh + (n + 16) * WIDTH + bn * 128 + k8);
        *reinterpret_cast<short8*>(&WcL[n * 136 + k8]) =
            *reinterpret_cast<const short8*>(wl + n * WIDTH + bn * 128 + k8);
        *reinterpret_cast<short8*>(&WcL[(n + 16) * 136 + k8]) =
            *reinterpret_cast<const short8*>(wl + (n + 16) * WIDTH + bn * 128 + k8);
    }
    __syncthreads();

    // projection: (128 x 128) @ (128 x 32)^T, each wave does 32 rows
    floatx4 accp[2][2] = {};
#pragma unroll
    for (int kk = 0; kk < 128; kk += 32) {
        short8 af[2], bh8[2], bl8[2];
#pragma unroll
        for (int i = 0; i < 2; ++i)
            af[i] = *reinterpret_cast<const short8*>(&T[(wv * 32 + i * 16 + r) * 136 + kk + kq]);
#pragma unroll
        for (int j = 0; j < 2; ++j) {
            bh8[j] = *reinterpret_cast<const short8*>(&WcH[(j * 16 + r) * 136 + kk + kq]);
            bl8[j] = *reinterpret_cast<const short8*>(&WcL[(j * 16 + r) * 136 + kk + kq]);
        }
#pragma unroll
        for (int i = 0; i < 2; ++i)
#pragma unroll
            for (int j = 0; j < 2; ++j) {
                accp[i][j] = __builtin_amdgcn_mfma_f32_16x16x32_bf16(af[i], bh8[j], accp[i][j], 0, 0, 0);
                accp[i][j] = __builtin_amdgcn_mfma_f32_16x16x32_bf16(af[i], bl8[j], accp[i][j], 0, 0, 0);
            }
    }
#pragma unroll
    for (int i = 0; i < 2; ++i)
#pragma unroll
        for (int j = 0; j < 2; ++j)
#pragma unroll
            for (int rr = 0; rr < 4; ++rr) {
                const int rowg = bm * 128 + wv * 32 + i * 16 + r4 + rr;
                PDpart[((long)bn * Mrows + rowg) * 32 + j * 16 + r] = accp[i][j][rr];
            }
}

// ---------------- reduce PD partials over bn ----------------
__global__ __launch_bounds__(256) void reduce_pd(
    const float* __restrict__ PDpart, float* __restrict__ PD, int Mrows)
{
    const long idx = (long)blockIdx.x * 256 + threadIdx.x;
    if (idx < (long)Mrows * 32) {
        float s = 0.f;
#pragma unroll
        for (int b = 0; b < 8; ++b) s += PDpart[(long)b * Mrows * 32 + idx];
        PD[idx] = s;
    }
}

// ---------------- head-projection GEMM 128x32 (Y3 path, 3-pass) ----------------
__global__ __launch_bounds__(256) void gemm_heady(
    const __hip_bfloat16* __restrict__ Ah, const __hip_bfloat16* __restrict__ Al,
    const __hip_bfloat16* __restrict__ Bh, const __hip_bfloat16* __restrict__ Bl,
    float* __restrict__ P)
{
    __shared__ __align__(16) short Ash[128 * 32], Asl[128 * 32];
    __shared__ __align__(16) short Bsh[32 * 32], Bsl[32 * 32];
    const int tid = threadIdx.x;
    const int lane = tid & 63;
    const int wv = tid >> 6;
    const int bm = blockIdx.x;

    const int srow = tid >> 2;
    const int scol = (tid & 3) << 3;
    const short* pAh = (const short*)Ah + (long)(bm * 128 + srow) * WIDTH + scol;
    const short* pAl = (const short*)Al + (long)(bm * 128 + srow) * WIDTH + scol;
    const long boff = (long)srow * WIDTH + scol;
    const short* pBh = (const short*)Bh;  const short* pBl = (const short*)Bl;
    const long half = 64l * WIDTH;

    floatx4 acc[2][2] = {};
    const int r = lane & 15;
    const int kq = (lane >> 4) << 3;

    for (int kt = 0; kt < WIDTH; kt += 32) {
        short8 gbh, gbl;
        if (tid < 128) {
            gbh = *reinterpret_cast<const short8*>(pBh + boff + kt);
            gbl = *reinterpret_cast<const short8*>(pBl + boff + kt);
        }
        __syncthreads();
        async_copy16(pAh + kt,        Ash + wv * 512);
        async_copy16(pAh + half + kt, Ash + 2048 + wv * 512);
        async_copy16(pAl + kt,        Asl + wv * 512);
        async_copy16(pAl + half + kt, Asl + 2048 + wv * 512);
        if (tid < 128) {
            *reinterpret_cast<short8*>(&Bsh[srow * 32 + scol]) = gbh;
            *reinterpret_cast<short8*>(&Bsl[srow * 32 + scol]) = gbl;
        }
        __syncthreads();
        short8 afh[2], afl[2], bfh[2], bfl[2];
#pragma unroll
        for (int i = 0; i < 2; ++i) {
            const int ar = (wv * 32 + i * 16 + r) * 32 + kq;
            afh[i] = *reinterpret_cast<const short8*>(&Ash[ar]);
            afl[i] = *reinterpret_cast<const short8*>(&Asl[ar]);
        }
#pragma unroll
        for (int j = 0; j < 2; ++j) {
            const int br = (j * 16 + r) * 32 + kq;
            bfh[j] = *reinterpret_cast<const short8*>(&Bsh[br]);
            bfl[j] = *reinterpret_cast<const short8*>(&Bsl[br]);
        }
#pragma unroll
        for (int i = 0; i < 2; ++i)
#pragma unroll
            for (int j = 0; j < 2; ++j) {
                acc[i][j] = __builtin_amdgcn_mfma_f32_16x16x32_bf16(afh[i], bfh[j], acc[i][j], 0, 0, 0);
                acc[i][j] = __builtin_amdgcn_mfma_f32_16x16x32_bf16(afh[i], bfl[j], acc[i][j], 0, 0, 0);
                acc[i][j] = __builtin_amdgcn_mfma_f32_16x16x32_bf16(afl[i], bfh[j], acc[i][j], 0, 0, 0);
            }
    }

    const int r4 = (lane >> 4) << 2;
#pragma unroll
    for (int i = 0; i < 2; ++i)
#pragma unroll
        for (int j = 0; j < 2; ++j) {
            const int col = j * 16 + r;
#pragma unroll
            for (int rr = 0; rr < 4; ++rr) {
                const int row = bm * 128 + wv * 32 + i * 16 + r4 + rr;
                P[(long)row * 32 + col] = acc[i][j][rr];
            }
        }
}

// ---------------- finalize: 7x7 algebra from projections ----------------
__device__ __forceinline__ int midx(int rr, int cc) {
    const int i = rr - cc;
    return i * 7 - (i * (i - 1)) / 2 + cc;
}

__global__ __launch_bounds__(64) void finalize_k(
    const float* __restrict__ PY,
    const float* __restrict__ PD,
    const float* __restrict__ vel_g,
    const float* __restrict__ acc_g,
    const float* __restrict__ b_ld,
    const float* __restrict__ b_lo,
    float* __restrict__ out,
    int b0)
{
    __shared__ float lval[28];
    __shared__ int gpv[7];
    __shared__ float derl[29 * 7];
    __shared__ float Lm[49], Mm[49], dLt[49], uu[49];
    __shared__ float wvv[7], pv[7], Cv[7], Gv[7], tauv[7], vl[7], ac[7];

    const int bl = blockIdx.x, tid = threadIdx.x;
    const int b = b0 + bl;
    if (tid < 28) {
        float s = PY[(long)bl * 32 + tid];
        if (tid < 7) {
            s += b_ld[tid];
            gpv[tid] = s > 0.f;
            lval[tid] = s > 0.f ? s : 0.f;
        } else {
            lval[tid] = s + b_lo[tid - 7];
        }
    }
    if (tid >= 28 && tid < 35) {
        vl[tid - 28] = vel_g[b * 7 + tid - 28];
        ac[tid - 28] = acc_g[b * 7 + tid - 28];
    }
    __syncthreads();
    for (int idx = tid; idx < 203; idx += 64) {
        const int m = idx / 7, d = idx % 7;
        float v = PD[((long)bl * 7 + d) * 32 + m];
        if (m < 7 && !gpv[m]) v = 0.f;
        derl[m * 7 + d] = v;
    }
    __syncthreads();
    if (tid < 49) {
        const int rr = tid / 7, cc = tid % 7;
        Lm[tid] = (rr >= cc) ? lval[midx(rr, cc)] : 0.f;
    }
    __syncthreads();
    if (tid < 49) {
        const int rr = tid / 7, cc = tid % 7;
        float s = 0.f;
        for (int k = 0; k < 7; ++k) s += Lm[rr * 7 + k] * Lm[cc * 7 + k];
        if (rr == cc) s += 1e-5f;
        Mm[tid] = s;
        float t = 0.f;
        if (rr >= cc) {
            const int m = midx(rr, cc);
            for (int d = 0; d < 7; ++d) t += derl[m * 7 + d] * vl[d];
        }
        dLt[tid] = t;
        float u = 0.f;
        for (int r2 = cc; r2 < 7; ++r2) u += vl[r2] * derl[midx(r2, cc) * 7 + rr];
        uu[tid] = u;
    } else if (tid >= 49 && tid < 56) {
        const int j = tid - 49;
        float s = 0.f;
        for (int r2 = 0; r2 < 7; ++r2) s += Lm[r2 * 7 + j] * vl[r2];
        wvv[j] = s;
    }
    __syncthreads();
    if (tid < 7) {
        float s = 0.f;
        for (int r2 = 0; r2 < 7; ++r2) s += dLt[r2 * 7 + tid] * vl[r2];
        pv[tid] = s;
    }
    __syncthreads();
    if (tid < 7) {
        float s = 0.f, q = 0.f, md = 0.f;
        for (int c = 0; c < 7; ++c) {
            s += Lm[tid * 7 + c] * pv[c] + dLt[tid * 7 + c] * wvv[c];
            q += uu[tid * 7 + c] * wvv[c];
            md += Mm[tid * 7 + c] * ac[c];
        }
        Cv[tid] = s - q;
        Gv[tid] = derl[28 * 7 + tid];
        tauv[tid] = md + Cv[tid] + Gv[tid];
    }
    __syncthreads();
    if (tid < 49) out[57344 + (long)b * 49 + tid] = Mm[tid];
    if (tid < 7) {
        out[(long)b * 7 + tid] = tauv[tid];
        out[458752 + (long)b * 7 + tid] = Cv[tid];
        out[516096 + (long)b * 7 + tid] = Gv[tid];
    }
}

extern "C" void kernel_launch(void* const* d_in, const int* in_sizes, int n_in,
                              void* d_out, int out_size, void* d_ws, size_t ws_size,
                              hipStream_t stream)
{
    const float* state = (const float*)d_in[0];
    const float* vel   = (const float*)d_in[1];
    const float* accel = (const float*)d_in[2];
    const float* W_in  = (const float*)d_in[3];
    const float* b_in  = (const float*)d_in[4];
    const float* W_h   = (const float*)d_in[5];
    const float* b_h   = (const float*)d_in[6];
    const float* W_g   = (const float*)d_in[7];
    /* d_in[8] = b_g unused */
    const float* W_ld  = (const float*)d_in[9];
    const float* b_ld  = (const float*)d_in[10];
    const float* W_lo  = (const float*)d_in[11];
    const float* b_lo  = (const float*)d_in[12];
    float* outp = (float*)d_out;

    char* ws = (char*)d_ws;
    __hip_bfloat16* Wth = (__hip_bfloat16*)ws; ws += (size_t)WIDTH * WIDTH * 2;
    __hip_bfloat16* Wtl = (__hip_bfloat16*)ws; ws += (size_t)WIDTH * WIDTH * 2;
    __hip_bfloat16* Wch = (__hip_bfloat16*)ws; ws += 32 * WIDTH * 2;
    __hip_bfloat16* Wcl = (__hip_bfloat16*)ws; ws += 32 * WIDTH * 2;
    const size_t fixed = (size_t)(ws - (char*)d_ws);

    // per-sample ws: Y 4*2048 + D1 14336 + D2 14336 + PY 128 + PD 896 = 37888 B
    // (PDpart[8][7*CH][32] fp32 = 7168 B/sample aliases the idle D1 buffer during D3)
    int CH = 128;
    for (int cand = 8192; cand >= 128; cand >>= 1) {
        size_t need = fixed + (size_t)cand * 37888;
        if (need <= ws_size) { CH = cand; break; }
    }
    const int NCH = BATCH / CH;

    const size_t YB = (size_t)CH * WIDTH * 2;
    const size_t DB = (size_t)CH * 7 * WIDTH * 2;
    __hip_bfloat16* Yah = (__hip_bfloat16*)ws; ws += YB;   // Y1 -> Y3
    __hip_bfloat16* Yal = (__hip_bfloat16*)ws; ws += YB;
    __hip_bfloat16* Ybh = (__hip_bfloat16*)ws; ws += YB;   // Y2
    __hip_bfloat16* Ybl = (__hip_bfloat16*)ws; ws += YB;
    __hip_bfloat16* Dah = (__hip_bfloat16*)ws; ws += DB;   // D1 (aliased as PDpart in D3 phase)
    __hip_bfloat16* Dbh = (__hip_bfloat16*)ws; ws += DB;   // D2
    float* PY = (float*)ws; ws += (size_t)CH * 32 * 4;
    float* PD = (float*)ws; ws += (size_t)CH * 7 * 32 * 4;
    float* PDpart = (float*)Dah;   // 8 * (7*CH) * 32 * 4 = CH*7168 B <= DB

    const int Mrows = CH * 7;

    transpose_k<<<dim3(32, 32), dim3(256), 0, stream>>>(W_h, Wth, Wtl);
    buildwcat_k<<<dim3(128), dim3(256), 0, stream>>>(W_ld, W_lo, W_g, Wch, Wcl);

    for (int c = 0; c < NCH; ++c) {
        prep_k<<<dim3(CH), dim3(256), 0, stream>>>(state + (size_t)c * CH * 7, W_in, b_in,
                                                   Yah, Yal, Dah);
        gemm_y<<<dim3(CH / 128, 8), dim3(256), 0, stream>>>(
            Yah, Yal, Wth, Wtl, b_h, Ybh, Ybl);                                // Y2
        gemm_d2<<<dim3(8, Mrows / 128), dim3(256), 0, stream>>>(
            Dah, Wth, Ybh, Dbh);                                               // D2 (mask Y2)
        gemm_y<<<dim3(CH / 128, 8), dim3(256), 0, stream>>>(
            Ybh, Ybl, Wth, Wtl, b_h, Yah, Yal);                                // Y3
        gemm_d3<<<dim3(8, Mrows / 128), dim3(256), 0, stream>>>(
            Dbh, Wth, Yah, Wch, Wcl, PDpart, Mrows);                           // D3 + PD partials
        reduce_pd<<<dim3((Mrows * 32 + 255) / 256), dim3(256), 0, stream>>>(PDpart, PD, Mrows);
        gemm_heady<<<dim3(CH / 128), dim3(256), 0, stream>>>(Yah, Yal, Wch, Wcl, PY);
        finalize_k<<<dim3(CH), dim3(64), 0, stream>>>(PY, PD, vel, accel, b_ld, b_lo,
                                                      outp, c * CH);
    }
    (void)in_sizes; (void)n_in; (void)out_size;
}

// Round 12
// 673.869 us; speedup vs baseline: 3.2674x; 1.0626x over previous
//
#include <hip/hip_runtime.h>
#include <hip/hip_bf16.h>

#define WIDTH 1024
#define BATCH 8192

typedef __attribute__((ext_vector_type(8))) short short8;
typedef __attribute__((ext_vector_type(4))) float floatx4;

typedef __attribute__((address_space(1))) void gvoid;
typedef __attribute__((address_space(3))) void lvoid;

__device__ __forceinline__ void async_copy16(const void* g, void* l) {
    __builtin_amdgcn_global_load_lds((gvoid*)g, (lvoid*)l, 16, 0, 0);
}

__device__ __forceinline__ void split_store(float v, __hip_bfloat16* hi, __hip_bfloat16* lo, long idx) {
    __hip_bfloat16 h = __float2bfloat16(v);
    hi[idx] = h;
    lo[idx] = __float2bfloat16(v - __bfloat162float(h));
}

// ---------------- transpose W_h (fp32) -> Wt_hi/lo[n][k] bf16 ----------------
__global__ __launch_bounds__(256) void transpose_k(
    const float* __restrict__ W,
    __hip_bfloat16* __restrict__ Wth, __hip_bfloat16* __restrict__ Wtl)
{
    __shared__ float t[32][33];
    const int tx = threadIdx.x & 31, ty = threadIdx.x >> 5;
    const int bx = blockIdx.x << 5, by = blockIdx.y << 5;
#pragma unroll
    for (int r = 0; r < 32; r += 8)
        t[ty + r][tx] = W[(long)(by + ty + r) * WIDTH + bx + tx];
    __syncthreads();
#pragma unroll
    for (int r = 0; r < 32; r += 8)
        split_store(t[tx][ty + r], Wth, Wtl, (long)(bx + ty + r) * WIDTH + by + tx);
}

// ---------------- pack head weights: Wcat[32][1024] hi/lo ----------------
__global__ __launch_bounds__(256) void buildwcat_k(
    const float* __restrict__ W_ld, const float* __restrict__ W_lo,
    const float* __restrict__ W_g,
    __hip_bfloat16* __restrict__ Wch, __hip_bfloat16* __restrict__ Wcl)
{
    const int idx = blockIdx.x * 256 + threadIdx.x;   // 32*1024
    const int n = idx >> 10, k = idx & 1023;
    float v = 0.f;
    if (n < 7)       v = W_ld[k * 7 + n];
    else if (n < 28) v = W_lo[k * 21 + (n - 7)];
    else if (n == 28) v = W_g[k];
    split_store(v, Wch, Wcl, idx);
}

// ---------------- layer 1: Y1 split, D1 hi-only ----------------
__global__ __launch_bounds__(256) void prep_k(
    const float* __restrict__ state,
    const float* __restrict__ W_in,
    const float* __restrict__ b_in,
    __hip_bfloat16* __restrict__ Y1h, __hip_bfloat16* __restrict__ Y1l,
    __hip_bfloat16* __restrict__ D1h)
{
    const int b = blockIdx.x;
    const int j0 = threadIdx.x * 4;
    float s[7];
#pragma unroll
    for (int d = 0; d < 7; ++d) s[d] = state[b * 7 + d];
    float a[4];
#pragma unroll
    for (int q = 0; q < 4; ++q) a[q] = b_in[j0 + q];
    float w[7][4];
#pragma unroll
    for (int d = 0; d < 7; ++d)
#pragma unroll
        for (int q = 0; q < 4; ++q) {
            w[d][q] = W_in[d * WIDTH + j0 + q];
            a[q] += s[d] * w[d][q];
        }
    bool gp[4];
#pragma unroll
    for (int q = 0; q < 4; ++q) {
        gp[q] = a[q] > 0.f;
        split_store(gp[q] ? a[q] : 0.f, Y1h, Y1l, (long)b * WIDTH + j0 + q);
    }
    union { unsigned long long u64; unsigned short h[4]; } pk;
#pragma unroll
    for (int d = 0; d < 7; ++d) {
#pragma unroll
        for (int q = 0; q < 4; ++q) {
            __hip_bfloat16 v = __float2bfloat16(gp[q] ? w[d][q] : 0.f);
            pk.h[q] = *reinterpret_cast<unsigned short*>(&v);
        }
        *reinterpret_cast<unsigned long long*>(&D1h[((long)b * 7 + d) * WIDTH + j0]) = pk.u64;
    }
}

// ---------------- Y-GEMM body (3-pass split, relu+bias, split out) ----------------
__device__ __forceinline__ void y_gemm_body(
    short* SM,   // 16384 shorts
    int bm, int bn, int tid,
    const __hip_bfloat16* Ah, const __hip_bfloat16* Al,
    const __hip_bfloat16* Bh, const __hip_bfloat16* Bl,
    const float* bias,
    __hip_bfloat16* outh, __hip_bfloat16* outl)
{
    short* Ash = SM;          short* Asl = SM + 4096;
    short* Bsh = SM + 8192;   short* Bsl = SM + 12288;
    const int lane = tid & 63;
    const int wv = tid >> 6;
    const int wm = wv >> 1, wn = wv & 1;
    const int srow = tid >> 2;
    const int scol = (tid & 3) << 3;
    const short* pAh = (const short*)Ah + (long)(bm * 128 + srow) * WIDTH + scol;
    const short* pAl = (const short*)Al + (long)(bm * 128 + srow) * WIDTH + scol;
    const short* pBh = (const short*)Bh + (long)(bn * 128 + srow) * WIDTH + scol;
    const short* pBl = (const short*)Bl + (long)(bn * 128 + srow) * WIDTH + scol;
    const long half = 64l * WIDTH;

    floatx4 acc[4][4] = {};
    const int r = lane & 15;
    const int kq = (lane >> 4) << 3;

    for (int kt = 0; kt < WIDTH; kt += 32) {
        __syncthreads();
        async_copy16(pAh + kt,        Ash + wv * 512);
        async_copy16(pAh + half + kt, Ash + 2048 + wv * 512);
        async_copy16(pAl + kt,        Asl + wv * 512);
        async_copy16(pAl + half + kt, Asl + 2048 + wv * 512);
        async_copy16(pBh + kt,        Bsh + wv * 512);
        async_copy16(pBh + half + kt, Bsh + 2048 + wv * 512);
        async_copy16(pBl + kt,        Bsl + wv * 512);
        async_copy16(pBl + half + kt, Bsl + 2048 + wv * 512);
        __syncthreads();
        short8 afh[4], afl[4], bfh[4], bfl[4];
#pragma unroll
        for (int i = 0; i < 4; ++i) {
            const int ar = (wm * 64 + i * 16 + r) * 32 + kq;
            afh[i] = *reinterpret_cast<const short8*>(&Ash[ar]);
            afl[i] = *reinterpret_cast<const short8*>(&Asl[ar]);
        }
#pragma unroll
        for (int j = 0; j < 4; ++j) {
            const int br = (wn * 64 + j * 16 + r) * 32 + kq;
            bfh[j] = *reinterpret_cast<const short8*>(&Bsh[br]);
            bfl[j] = *reinterpret_cast<const short8*>(&Bsl[br]);
        }
#pragma unroll
        for (int i = 0; i < 4; ++i)
#pragma unroll
            for (int j = 0; j < 4; ++j) {
                acc[i][j] = __builtin_amdgcn_mfma_f32_16x16x32_bf16(afh[i], bfh[j], acc[i][j], 0, 0, 0);
                acc[i][j] = __builtin_amdgcn_mfma_f32_16x16x32_bf16(afh[i], bfl[j], acc[i][j], 0, 0, 0);
                acc[i][j] = __builtin_amdgcn_mfma_f32_16x16x32_bf16(afl[i], bfh[j], acc[i][j], 0, 0, 0);
            }
    }

    const int r4 = (lane >> 4) << 2;
#pragma unroll
    for (int i = 0; i < 4; ++i)
#pragma unroll
        for (int j = 0; j < 4; ++j) {
            const int col = bn * 128 + wn * 64 + j * 16 + r;
#pragma unroll
            for (int rr = 0; rr < 4; ++rr) {
                const int row = bm * 128 + wm * 64 + i * 16 + r4 + rr;
                float v = acc[i][j][rr] + bias[col];
                v = v > 0.f ? v : 0.f;
                split_store(v, outh, outl, (long)row * WIDTH + col);
            }
        }
}

// ---------------- Y2 GEMM (standalone) ----------------
__global__ __launch_bounds__(256) void gemm_y(
    const __hip_bfloat16* __restrict__ Ah, const __hip_bfloat16* __restrict__ Al,
    const __hip_bfloat16* __restrict__ Bh, const __hip_bfloat16* __restrict__ Bl,
    const float* __restrict__ bias,
    __hip_bfloat16* __restrict__ outh, __hip_bfloat16* __restrict__ outl)
{
    __shared__ __align__(16) short SM[16384];
    y_gemm_body(SM, blockIdx.x, blockIdx.y, threadIdx.x, Ah, Al, Bh, Bl, bias, outh, outl);
}

// ---------------- fused D2 + Y3 launch ----------------
// blocks x<nd: D2 1-pass bf16 BK=64 (bm=x fastest); x>=nd: Y3 3-pass (bm=x-nd).
__global__ __launch_bounds__(256) void d2y3_k(
    const __hip_bfloat16* __restrict__ D1,
    const __hip_bfloat16* __restrict__ Wth, const __hip_bfloat16* __restrict__ Wtl,
    const __hip_bfloat16* __restrict__ Y2h, const __hip_bfloat16* __restrict__ Y2l,
    const float* __restrict__ bias,
    __hip_bfloat16* __restrict__ D2out,
    __hip_bfloat16* __restrict__ Y3h, __hip_bfloat16* __restrict__ Y3l,
    int nd)
{
    __shared__ __align__(16) short SM[16384];
    const int tid = threadIdx.x;
    if ((int)blockIdx.x >= nd) {
        y_gemm_body(SM, blockIdx.x - nd, blockIdx.y, tid, Y2h, Y2l, Wth, Wtl, bias, Y3h, Y3l);
        return;
    }
    // ---- D2 body ----
    short* Ash0 = SM;         short* Ash1 = SM + 4096;
    short* Bsh0 = SM + 8192;  short* Bsh1 = SM + 12288;
    const int lane = tid & 63;
    const int wv = tid >> 6;
    const int wm = wv >> 1, wn = wv & 1;
    const int bm = blockIdx.x, bn = blockIdx.y;

    const int srow = tid >> 2;
    const int scol = (tid & 3) << 3;
    const short* pAh = (const short*)D1 + (long)(bm * 128 + srow) * WIDTH + scol;
    const short* pBh = (const short*)Wth + (long)(bn * 128 + srow) * WIDTH + scol;
    const long half = 64l * WIDTH;

    floatx4 acc[4][4] = {};
    const int r = lane & 15;
    const int kq = (lane >> 4) << 3;

    for (int kt = 0; kt < WIDTH; kt += 64) {
        __syncthreads();
        async_copy16(pAh + kt,             Ash0 + wv * 512);
        async_copy16(pAh + half + kt,      Ash0 + 2048 + wv * 512);
        async_copy16(pAh + kt + 32,        Ash1 + wv * 512);
        async_copy16(pAh + half + kt + 32, Ash1 + 2048 + wv * 512);
        async_copy16(pBh + kt,             Bsh0 + wv * 512);
        async_copy16(pBh + half + kt,      Bsh0 + 2048 + wv * 512);
        async_copy16(pBh + kt + 32,        Bsh1 + wv * 512);
        async_copy16(pBh + half + kt + 32, Bsh1 + 2048 + wv * 512);
        __syncthreads();
#pragma unroll
        for (int s = 0; s < 2; ++s) {
            const short* As = s ? Ash1 : Ash0;
            const short* Bs = s ? Bsh1 : Bsh0;
            short8 afh[4], bfh[4];
#pragma unroll
            for (int i = 0; i < 4; ++i)
                afh[i] = *reinterpret_cast<const short8*>(&As[(wm * 64 + i * 16 + r) * 32 + kq]);
#pragma unroll
            for (int j = 0; j < 4; ++j)
                bfh[j] = *reinterpret_cast<const short8*>(&Bs[(wn * 64 + j * 16 + r) * 32 + kq]);
#pragma unroll
            for (int i = 0; i < 4; ++i)
#pragma unroll
                for (int j = 0; j < 4; ++j)
                    acc[i][j] = __builtin_amdgcn_mfma_f32_16x16x32_bf16(afh[i], bfh[j], acc[i][j], 0, 0, 0);
        }
    }

    const int r4 = (lane >> 4) << 2;
#pragma unroll
    for (int i = 0; i < 4; ++i)
#pragma unroll
        for (int j = 0; j < 4; ++j) {
            const int col = bn * 128 + wn * 64 + j * 16 + r;
#pragma unroll
            for (int rr = 0; rr < 4; ++rr) {
                const int row = bm * 128 + wm * 64 + i * 16 + r4 + rr;
                float v = acc[i][j][rr];
                const unsigned brow = (unsigned)row / 7u;
                if (!(__bfloat162float(Y2h[(long)brow * WIDTH + col]) > 0.f)) v = 0.f;
                D2out[(long)row * WIDTH + col] = __float2bfloat16(v);
            }
        }
}

// ---------------- fused D3(+PD projection) + heady launch ----------------
// blocks x<nd: D3 with fused PD partial projection (bm=x fastest, bn=y);
// x>=nd && y==0: heady (Y3 projection, 3-pass); else idle.
__global__ __launch_bounds__(256) void d3heady_k(
    const __hip_bfloat16* __restrict__ D2,
    const __hip_bfloat16* __restrict__ Wth, const __hip_bfloat16* __restrict__ Wtl,
    const __hip_bfloat16* __restrict__ Y3h, const __hip_bfloat16* __restrict__ Y3l,
    const __hip_bfloat16* __restrict__ Wch, const __hip_bfloat16* __restrict__ Wcl,
    float* __restrict__ PDpart, float* __restrict__ PY,
    int nd, int Mrows)
{
    __shared__ __align__(16) short SM[26112];  // 52 KB
    const int tid = threadIdx.x;
    const int lane = tid & 63;
    const int wv = tid >> 6;
    const int r = lane & 15;
    const int kq = (lane >> 4) << 3;
    const int r4 = (lane >> 4) << 2;
    const int srow = tid >> 2;
    const int scol = (tid & 3) << 3;
    const long half = 64l * WIDTH;

    if ((int)blockIdx.x >= nd) {
        if (blockIdx.y != 0) return;
        // ---- heady body (3-pass Y3 @ Wcat^T) ----
        short* Ash = SM;          short* Asl = SM + 4096;
        short* Bsh = SM + 8192;   short* Bsl = SM + 9216;
        const int bm = blockIdx.x - nd;
        const short* pAh = (const short*)Y3h + (long)(bm * 128 + srow) * WIDTH + scol;
        const short* pAl = (const short*)Y3l + (long)(bm * 128 + srow) * WIDTH + scol;
        const long boff = (long)srow * WIDTH + scol;
        const short* pBh = (const short*)Wch;  const short* pBl = (const short*)Wcl;

        floatx4 acc[2][2] = {};
        for (int kt = 0; kt < WIDTH; kt += 32) {
            short8 gbh, gbl;
            if (tid < 128) {
                gbh = *reinterpret_cast<const short8*>(pBh + boff + kt);
                gbl = *reinterpret_cast<const short8*>(pBl + boff + kt);
            }
            __syncthreads();
            async_copy16(pAh + kt,        Ash + wv * 512);
            async_copy16(pAh + half + kt, Ash + 2048 + wv * 512);
            async_copy16(pAl + kt,        Asl + wv * 512);
            async_copy16(pAl + half + kt, Asl + 2048 + wv * 512);
            if (tid < 128) {
                *reinterpret_cast<short8*>(&Bsh[srow * 32 + scol]) = gbh;
                *reinterpret_cast<short8*>(&Bsl[srow * 32 + scol]) = gbl;
            }
            __syncthreads();
            short8 afh[2], afl[2], bfh[2], bfl[2];
#pragma unroll
            for (int i = 0; i < 2; ++i) {
                const int ar = (wv * 32 + i * 16 + r) * 32 + kq;
                afh[i] = *reinterpret_cast<const short8*>(&Ash[ar]);
                afl[i] = *reinterpret_cast<const short8*>(&Asl[ar]);
            }
#pragma unroll
            for (int j = 0; j < 2; ++j) {
                const int br = (j * 16 + r) * 32 + kq;
                bfh[j] = *reinterpret_cast<const short8*>(&Bsh[br]);
                bfl[j] = *reinterpret_cast<const short8*>(&Bsl[br]);
            }
#pragma unroll
            for (int i = 0; i < 2; ++i)
#pragma unroll
                for (int j = 0; j < 2; ++j) {
                    acc[i][j] = __builtin_amdgcn_mfma_f32_16x16x32_bf16(afh[i], bfh[j], acc[i][j], 0, 0, 0);
                    acc[i][j] = __builtin_amdgcn_mfma_f32_16x16x32_bf16(afh[i], bfl[j], acc[i][j], 0, 0, 0);
                    acc[i][j] = __builtin_amdgcn_mfma_f32_16x16x32_bf16(afl[i], bfh[j], acc[i][j], 0, 0, 0);
                }
        }
#pragma unroll
        for (int i = 0; i < 2; ++i)
#pragma unroll
            for (int j = 0; j < 2; ++j)
#pragma unroll
                for (int rr = 0; rr < 4; ++rr) {
                    const int row = bm * 128 + wv * 32 + i * 16 + r4 + rr;
                    PY[(long)row * 32 + j * 16 + r] = acc[i][j][rr];
                }
        return;
    }

    // ---- D3 body + fused PD projection ----
    short* Ash0 = SM;         short* Ash1 = SM + 4096;
    short* Bsh0 = SM + 8192;  short* Bsh1 = SM + 12288;
    short* T    = SM;            // 128 x 136
    short* WcH  = SM + 17408;    // 32 x 136
    short* WcL  = SM + 21760;    // 32 x 136

    const int wm = wv >> 1, wn = wv & 1;
    const int bm = blockIdx.x, bn = blockIdx.y;
    const short* pAh = (const short*)D2 + (long)(bm * 128 + srow) * WIDTH + scol;
    const short* pBh = (const short*)Wth + (long)(bn * 128 + srow) * WIDTH + scol;

    floatx4 acc[4][4] = {};
    for (int kt = 0; kt < WIDTH; kt += 64) {
        __syncthreads();
        async_copy16(pAh + kt,             Ash0 + wv * 512);
        async_copy16(pAh + half + kt,      Ash0 + 2048 + wv * 512);
        async_copy16(pAh + kt + 32,        Ash1 + wv * 512);
        async_copy16(pAh + half + kt + 32, Ash1 + 2048 + wv * 512);
        async_copy16(pBh + kt,             Bsh0 + wv * 512);
        async_copy16(pBh + half + kt,      Bsh0 + 2048 + wv * 512);
        async_copy16(pBh + kt + 32,        Bsh1 + wv * 512);
        async_copy16(pBh + half + kt + 32, Bsh1 + 2048 + wv * 512);
        __syncthreads();
#pragma unroll
        for (int s = 0; s < 2; ++s) {
            const short* As = s ? Ash1 : Ash0;
            const short* Bs = s ? Bsh1 : Bsh0;
            short8 afh[4], bfh[4];
#pragma unroll
            for (int i = 0; i < 4; ++i)
                afh[i] = *reinterpret_cast<const short8*>(&As[(wm * 64 + i * 16 + r) * 32 + kq]);
#pragma unroll
            for (int j = 0; j < 4; ++j)
                bfh[j] = *reinterpret_cast<const short8*>(&Bs[(wn * 64 + j * 16 + r) * 32 + kq]);
#pragma unroll
            for (int i = 0; i < 4; ++i)
#pragma unroll
                for (int j = 0; j < 4; ++j)
                    acc[i][j] = __builtin_amdgcn_mfma_f32_16x16x32_bf16(afh[i], bfh[j], acc[i][j], 0, 0, 0);
        }
    }

    __syncthreads();
#pragma unroll
    for (int i = 0; i < 4; ++i)
#pragma unroll
        for (int j = 0; j < 4; ++j) {
            const int coll = wn * 64 + j * 16 + r;
            const int colg = bn * 128 + coll;
#pragma unroll
            for (int rr = 0; rr < 4; ++rr) {
                const int rowl = wm * 64 + i * 16 + r4 + rr;
                const int rowg = bm * 128 + rowl;
                float v = acc[i][j][rr];
                const unsigned brow = (unsigned)rowg / 7u;
                if (!(__bfloat162float(Y3h[(long)brow * WIDTH + colg]) > 0.f)) v = 0.f;
                __hip_bfloat16 hb = __float2bfloat16(v);
                T[rowl * 136 + coll] = *reinterpret_cast<short*>(&hb);
            }
        }
    {
        const int n = tid >> 4, k8 = (tid & 15) * 8;
        const short* wh = (const short*)Wch;
        const short* wl = (const short*)Wcl;
        *reinterpret_cast<short8*>(&WcH[n * 136 + k8]) =
            *reinterpret_cast<const short8*>(wh + n * WIDTH + bn * 128 + k8);
        *reinterpret_cast<short8*>(&WcH[(n + 16) * 136 + k8]) =
            *reinterpret_cast<const short8*>(wh + (n + 16) * WIDTH + bn * 128 + k8);
        *reinterpret_cast<short8*>(&WcL[n * 136 + k8]) =
            *reinterpret_cast<const short8*>(wl + n * WIDTH + bn * 128 + k8);
        *reinterpret_cast<short8*>(&WcL[(n + 16) * 136 + k8]) =
            *reinterpret_cast<const short8*>(wl + (n + 16) * WIDTH + bn * 128 + k8);
    }
    __syncthreads();

    floatx4 accp[2][2] = {};
#pragma unroll
    for (int kk = 0; kk < 128; kk += 32) {
        short8 af[2], bh8[2], bl8[2];
#pragma unroll
        for (int i = 0; i < 2; ++i)
            af[i] = *reinterpret_cast<const short8*>(&T[(wv * 32 + i * 16 + r) * 136 + kk + kq]);
#pragma unroll
        for (int j = 0; j < 2; ++j) {
            bh8[j] = *reinterpret_cast<const short8*>(&WcH[(j * 16 + r) * 136 + kk + kq]);
            bl8[j] = *reinterpret_cast<const short8*>(&WcL[(j * 16 + r) * 136 + kk + kq]);
        }
#pragma unroll
        for (int i = 0; i < 2; ++i)
#pragma unroll
            for (int j = 0; j < 2; ++j) {
                accp[i][j] = __builtin_amdgcn_mfma_f32_16x16x32_bf16(af[i], bh8[j], accp[i][j], 0, 0, 0);
                accp[i][j] = __builtin_amdgcn_mfma_f32_16x16x32_bf16(af[i], bl8[j], accp[i][j], 0, 0, 0);
            }
    }
#pragma unroll
    for (int i = 0; i < 2; ++i)
#pragma unroll
        for (int j = 0; j < 2; ++j)
#pragma unroll
            for (int rr = 0; rr < 4; ++rr) {
                const int rowg = bm * 128 + wv * 32 + i * 16 + r4 + rr;
                PDpart[((long)bn * Mrows + rowg) * 32 + j * 16 + r] = accp[i][j][rr];
            }
}

// ---------------- finalize: 7x7 algebra; reduces PDpart inline ----------------
__device__ __forceinline__ int midx(int rr, int cc) {
    const int i = rr - cc;
    return i * 7 - (i * (i - 1)) / 2 + cc;
}

__global__ __launch_bounds__(64) void finalize_k(
    const float* __restrict__ PY,
    const float* __restrict__ PDpart,   // [8][Mrows][32]
    const float* __restrict__ vel_g,
    const float* __restrict__ acc_g,
    const float* __restrict__ b_ld,
    const float* __restrict__ b_lo,
    float* __restrict__ out,
    int b0, int Mrows)
{
    __shared__ float lval[28];
    __shared__ int gpv[7];
    __shared__ float derl[29 * 7];
    __shared__ float Lm[49], Mm[49], dLt[49], uu[49];
    __shared__ float wvv[7], pv[7], Cv[7], Gv[7], tauv[7], vl[7], ac[7];

    const int bl = blockIdx.x, tid = threadIdx.x;
    const int b = b0 + bl;
    if (tid < 28) {
        float s = PY[(long)bl * 32 + tid];
        if (tid < 7) {
            s += b_ld[tid];
            gpv[tid] = s > 0.f;
            lval[tid] = s > 0.f ? s : 0.f;
        } else {
            lval[tid] = s + b_lo[tid - 7];
        }
    }
    if (tid >= 28 && tid < 35) {
        vl[tid - 28] = vel_g[b * 7 + tid - 28];
        ac[tid - 28] = acc_g[b * 7 + tid - 28];
    }
    __syncthreads();
    for (int idx = tid; idx < 203; idx += 64) {
        const int m = idx / 7, d = idx % 7;
        float v = 0.f;
#pragma unroll
        for (int p = 0; p < 8; ++p)
            v += PDpart[((long)p * Mrows + bl * 7 + d) * 32 + m];
        if (m < 7 && !gpv[m]) v = 0.f;
        derl[m * 7 + d] = v;
    }
    __syncthreads();
    if (tid < 49) {
        const int rr = tid / 7, cc = tid % 7;
        Lm[tid] = (rr >= cc) ? lval[midx(rr, cc)] : 0.f;
    }
    __syncthreads();
    if (tid < 49) {
        const int rr = tid / 7, cc = tid % 7;
        float s = 0.f;
        for (int k = 0; k < 7; ++k) s += Lm[rr * 7 + k] * Lm[cc * 7 + k];
        if (rr == cc) s += 1e-5f;
        Mm[tid] = s;
        float t = 0.f;
        if (rr >= cc) {
            const int m = midx(rr, cc);
            for (int d = 0; d < 7; ++d) t += derl[m * 7 + d] * vl[d];
        }
        dLt[tid] = t;
        float u = 0.f;
        for (int r2 = cc; r2 < 7; ++r2) u += vl[r2] * derl[midx(r2, cc) * 7 + rr];
        uu[tid] = u;
    } else if (tid >= 49 && tid < 56) {
        const int j = tid - 49;
        float s = 0.f;
        for (int r2 = 0; r2 < 7; ++r2) s += Lm[r2 * 7 + j] * vl[r2];
        wvv[j] = s;
    }
    __syncthreads();
    if (tid < 7) {
        float s = 0.f;
        for (int r2 = 0; r2 < 7; ++r2) s += dLt[r2 * 7 + tid] * vl[r2];
        pv[tid] = s;
    }
    __syncthreads();
    if (tid < 7) {
        float s = 0.f, q = 0.f, md = 0.f;
        for (int c = 0; c < 7; ++c) {
            s += Lm[tid * 7 + c] * pv[c] + dLt[tid * 7 + c] * wvv[c];
            q += uu[tid * 7 + c] * wvv[c];
            md += Mm[tid * 7 + c] * ac[c];
        }
        Cv[tid] = s - q;
        Gv[tid] = derl[28 * 7 + tid];
        tauv[tid] = md + Cv[tid] + Gv[tid];
    }
    __syncthreads();
    if (tid < 49) out[57344 + (long)b * 49 + tid] = Mm[tid];
    if (tid < 7) {
        out[(long)b * 7 + tid] = tauv[tid];
        out[458752 + (long)b * 7 + tid] = Cv[tid];
        out[516096 + (long)b * 7 + tid] = Gv[tid];
    }
}

extern "C" void kernel_launch(void* const* d_in, const int* in_sizes, int n_in,
                              void* d_out, int out_size, void* d_ws, size_t ws_size,
                              hipStream_t stream)
{
    const float* state = (const float*)d_in[0];
    const float* vel   = (const float*)d_in[1];
    const float* accel = (const float*)d_in[2];
    const float* W_in  = (const float*)d_in[3];
    const float* b_in  = (const float*)d_in[4];
    const float* W_h   = (const float*)d_in[5];
    const float* b_h   = (const float*)d_in[6];
    const float* W_g   = (const float*)d_in[7];
    /* d_in[8] = b_g unused */
    const float* W_ld  = (const float*)d_in[9];
    const float* b_ld  = (const float*)d_in[10];
    const float* W_lo  = (const float*)d_in[11];
    const float* b_lo  = (const float*)d_in[12];
    float* outp = (float*)d_out;

    char* ws = (char*)d_ws;
    __hip_bfloat16* Wth = (__hip_bfloat16*)ws; ws += (size_t)WIDTH * WIDTH * 2;
    __hip_bfloat16* Wtl = (__hip_bfloat16*)ws; ws += (size_t)WIDTH * WIDTH * 2;
    __hip_bfloat16* Wch = (__hip_bfloat16*)ws; ws += 32 * WIDTH * 2;
    __hip_bfloat16* Wcl = (__hip_bfloat16*)ws; ws += 32 * WIDTH * 2;
    const size_t fixed = (size_t)(ws - (char*)d_ws);

    // per-sample: Y 4*2048 + D1 14336 + D2 14336 + PY 128 = 37120 B
    int CH = 128;
    for (int cand = 8192; cand >= 128; cand >>= 1) {
        size_t need = fixed + (size_t)cand * 37120;
        if (need <= ws_size) { CH = cand; break; }
    }
    const int NCH = BATCH / CH;

    const size_t YB = (size_t)CH * WIDTH * 2;
    const size_t DB = (size_t)CH * 7 * WIDTH * 2;
    __hip_bfloat16* Yah = (__hip_bfloat16*)ws; ws += YB;   // Y1 -> Y3
    __hip_bfloat16* Yal = (__hip_bfloat16*)ws; ws += YB;
    __hip_bfloat16* Ybh = (__hip_bfloat16*)ws; ws += YB;   // Y2
    __hip_bfloat16* Ybl = (__hip_bfloat16*)ws; ws += YB;
    __hip_bfloat16* Dah = (__hip_bfloat16*)ws; ws += DB;   // D1 (aliased as PDpart in D3 phase)
    __hip_bfloat16* Dbh = (__hip_bfloat16*)ws; ws += DB;   // D2
    float* PY = (float*)ws; ws += (size_t)CH * 32 * 4;
    float* PDpart = (float*)Dah;   // 8*(7*CH)*32*4 = CH*7168 B <= DB

    const int Mrows = CH * 7;
    const int nd = Mrows / 128;
    const int ny = CH / 128;

    transpose_k<<<dim3(32, 32), dim3(256), 0, stream>>>(W_h, Wth, Wtl);
    buildwcat_k<<<dim3(128), dim3(256), 0, stream>>>(W_ld, W_lo, W_g, Wch, Wcl);

    for (int c = 0; c < NCH; ++c) {
        prep_k<<<dim3(CH), dim3(256), 0, stream>>>(state + (size_t)c * CH * 7, W_in, b_in,
                                                   Yah, Yal, Dah);
        gemm_y<<<dim3(ny, 8), dim3(256), 0, stream>>>(
            Yah, Yal, Wth, Wtl, b_h, Ybh, Ybl);                                // Y2
        d2y3_k<<<dim3(nd + ny, 8), dim3(256), 0, stream>>>(
            Dah, Wth, Wtl, Ybh, Ybl, b_h, Dbh, Yah, Yal, nd);                  // D2 + Y3
        d3heady_k<<<dim3(nd + ny, 8), dim3(256), 0, stream>>>(
            Dbh, Wth, Wtl, Yah, Yal, Wch, Wcl, PDpart, PY, nd, Mrows);         // D3+PD + heady
        finalize_k<<<dim3(CH), dim3(64), 0, stream>>>(PY, PDpart, vel, accel, b_ld, b_lo,
                                                      outp, c * CH, Mrows);
    }
    (void)in_sizes; (void)n_in; (void)out_size;
}

// Round 14
// 666.099 us; speedup vs baseline: 3.3055x; 1.0117x over previous
//
#include <hip/hip_runtime.h>
#include <hip/hip_bf16.h>

#define WIDTH 1024
#define BATCH 8192

typedef __attribute__((ext_vector_type(8))) short short8;
typedef __attribute__((ext_vector_type(4))) float floatx4;

typedef __attribute__((address_space(1))) void gvoid;
typedef __attribute__((address_space(3))) void lvoid;

__device__ __forceinline__ void async_copy16(const void* g, void* l) {
    __builtin_amdgcn_global_load_lds((gvoid*)g, (lvoid*)l, 16, 0, 0);
}

__device__ __forceinline__ void split_store(float v, __hip_bfloat16* hi, __hip_bfloat16* lo, long idx) {
    __hip_bfloat16 h = __float2bfloat16(v);
    hi[idx] = h;
    lo[idx] = __float2bfloat16(v - __bfloat162float(h));
}

// ---------------- transpose W_h (fp32) -> Wt_hi/lo[n][k] bf16 ----------------
__global__ __launch_bounds__(256) void transpose_k(
    const float* __restrict__ W,
    __hip_bfloat16* __restrict__ Wth, __hip_bfloat16* __restrict__ Wtl)
{
    __shared__ float t[32][33];
    const int tx = threadIdx.x & 31, ty = threadIdx.x >> 5;
    const int bx = blockIdx.x << 5, by = blockIdx.y << 5;
#pragma unroll
    for (int r = 0; r < 32; r += 8)
        t[ty + r][tx] = W[(long)(by + ty + r) * WIDTH + bx + tx];
    __syncthreads();
#pragma unroll
    for (int r = 0; r < 32; r += 8)
        split_store(t[tx][ty + r], Wth, Wtl, (long)(bx + ty + r) * WIDTH + by + tx);
}

// ---------------- pack head weights: Wcat[32][1024] hi/lo ----------------
__global__ __launch_bounds__(256) void buildwcat_k(
    const float* __restrict__ W_ld, const float* __restrict__ W_lo,
    const float* __restrict__ W_g,
    __hip_bfloat16* __restrict__ Wch, __hip_bfloat16* __restrict__ Wcl)
{
    const int idx = blockIdx.x * 256 + threadIdx.x;   // 32*1024
    const int n = idx >> 10, k = idx & 1023;
    float v = 0.f;
    if (n < 7)       v = W_ld[k * 7 + n];
    else if (n < 28) v = W_lo[k * 21 + (n - 7)];
    else if (n == 28) v = W_g[k];
    split_store(v, Wch, Wcl, idx);
}

// ---------------- layer 1: Y1 split, D1 hi-only ----------------
__global__ __launch_bounds__(256) void prep_k(
    const float* __restrict__ state,
    const float* __restrict__ W_in,
    const float* __restrict__ b_in,
    __hip_bfloat16* __restrict__ Y1h, __hip_bfloat16* __restrict__ Y1l,
    __hip_bfloat16* __restrict__ D1h)
{
    const int b = blockIdx.x;
    const int j0 = threadIdx.x * 4;
    float s[7];
#pragma unroll
    for (int d = 0; d < 7; ++d) s[d] = state[b * 7 + d];
    float a[4];
#pragma unroll
    for (int q = 0; q < 4; ++q) a[q] = b_in[j0 + q];
    float w[7][4];
#pragma unroll
    for (int d = 0; d < 7; ++d)
#pragma unroll
        for (int q = 0; q < 4; ++q) {
            w[d][q] = W_in[d * WIDTH + j0 + q];
            a[q] += s[d] * w[d][q];
        }
    bool gp[4];
#pragma unroll
    for (int q = 0; q < 4; ++q) {
        gp[q] = a[q] > 0.f;
        split_store(gp[q] ? a[q] : 0.f, Y1h, Y1l, (long)b * WIDTH + j0 + q);
    }
    union { unsigned long long u64; unsigned short h[4]; } pk;
#pragma unroll
    for (int d = 0; d < 7; ++d) {
#pragma unroll
        for (int q = 0; q < 4; ++q) {
            __hip_bfloat16 v = __float2bfloat16(gp[q] ? w[d][q] : 0.f);
            pk.h[q] = *reinterpret_cast<unsigned short*>(&v);
        }
        *reinterpret_cast<unsigned long long*>(&D1h[((long)b * 7 + d) * WIDTH + j0]) = pk.u64;
    }
}

// ---------------- Y-GEMM body (3-pass split, relu+bias, split out) ----------------
__device__ __forceinline__ void y_gemm_body(
    short* SM,   // 16384 shorts
    int bm, int bn, int tid,
    const __hip_bfloat16* Ah, const __hip_bfloat16* Al,
    const __hip_bfloat16* Bh, const __hip_bfloat16* Bl,
    const float* bias,
    __hip_bfloat16* outh, __hip_bfloat16* outl)
{
    short* Ash = SM;          short* Asl = SM + 4096;
    short* Bsh = SM + 8192;   short* Bsl = SM + 12288;
    const int lane = tid & 63;
    const int wv = tid >> 6;
    const int wm = wv >> 1, wn = wv & 1;
    const int srow = tid >> 2;
    const int scol = (tid & 3) << 3;
    const short* pAh = (const short*)Ah + (long)(bm * 128 + srow) * WIDTH + scol;
    const short* pAl = (const short*)Al + (long)(bm * 128 + srow) * WIDTH + scol;
    const short* pBh = (const short*)Bh + (long)(bn * 128 + srow) * WIDTH + scol;
    const short* pBl = (const short*)Bl + (long)(bn * 128 + srow) * WIDTH + scol;
    const long half = 64l * WIDTH;

    floatx4 acc[4][4] = {};
    const int r = lane & 15;
    const int kq = (lane >> 4) << 3;

    for (int kt = 0; kt < WIDTH; kt += 32) {
        __syncthreads();
        async_copy16(pAh + kt,        Ash + wv * 512);
        async_copy16(pAh + half + kt, Ash + 2048 + wv * 512);
        async_copy16(pAl + kt,        Asl + wv * 512);
        async_copy16(pAl + half + kt, Asl + 2048 + wv * 512);
        async_copy16(pBh + kt,        Bsh + wv * 512);
        async_copy16(pBh + half + kt, Bsh + 2048 + wv * 512);
        async_copy16(pBl + kt,        Bsl + wv * 512);
        async_copy16(pBl + half + kt, Bsl + 2048 + wv * 512);
        __syncthreads();
        short8 afh[4], afl[4], bfh[4], bfl[4];
#pragma unroll
        for (int i = 0; i < 4; ++i) {
            const int ar = (wm * 64 + i * 16 + r) * 32 + kq;
            afh[i] = *reinterpret_cast<const short8*>(&Ash[ar]);
            afl[i] = *reinterpret_cast<const short8*>(&Asl[ar]);
        }
#pragma unroll
        for (int j = 0; j < 4; ++j) {
            const int br = (wn * 64 + j * 16 + r) * 32 + kq;
            bfh[j] = *reinterpret_cast<const short8*>(&Bsh[br]);
            bfl[j] = *reinterpret_cast<const short8*>(&Bsl[br]);
        }
#pragma unroll
        for (int i = 0; i < 4; ++i)
#pragma unroll
            for (int j = 0; j < 4; ++j) {
                acc[i][j] = __builtin_amdgcn_mfma_f32_16x16x32_bf16(afh[i], bfh[j], acc[i][j], 0, 0, 0);
                acc[i][j] = __builtin_amdgcn_mfma_f32_16x16x32_bf16(afh[i], bfl[j], acc[i][j], 0, 0, 0);
                acc[i][j] = __builtin_amdgcn_mfma_f32_16x16x32_bf16(afl[i], bfh[j], acc[i][j], 0, 0, 0);
            }
    }

    const int r4 = (lane >> 4) << 2;
#pragma unroll
    for (int i = 0; i < 4; ++i)
#pragma unroll
        for (int j = 0; j < 4; ++j) {
            const int col = bn * 128 + wn * 64 + j * 16 + r;
#pragma unroll
            for (int rr = 0; rr < 4; ++rr) {
                const int row = bm * 128 + wm * 64 + i * 16 + r4 + rr;
                float v = acc[i][j][rr] + bias[col];
                v = v > 0.f ? v : 0.f;
                split_store(v, outh, outl, (long)row * WIDTH + col);
            }
        }
}

// ---------------- Y2 GEMM (standalone) ----------------
__global__ __launch_bounds__(256) void gemm_y(
    const __hip_bfloat16* __restrict__ Ah, const __hip_bfloat16* __restrict__ Al,
    const __hip_bfloat16* __restrict__ Bh, const __hip_bfloat16* __restrict__ Bl,
    const float* __restrict__ bias,
    __hip_bfloat16* __restrict__ outh, __hip_bfloat16* __restrict__ outl)
{
    __shared__ __align__(16) short SM[16384];
    y_gemm_body(SM, blockIdx.x, blockIdx.y, threadIdx.x, Ah, Al, Bh, Bl, bias, outh, outl);
}

// ---------------- fused D2 + Y3 launch ----------------
// blocks x<nd: D2 1-pass bf16 BK=64 (bm=x fastest); x>=nd: Y3 3-pass (bm=x-nd).
__global__ __launch_bounds__(256) void d2y3_k(
    const __hip_bfloat16* __restrict__ D1,
    const __hip_bfloat16* __restrict__ Wth, const __hip_bfloat16* __restrict__ Wtl,
    const __hip_bfloat16* __restrict__ Y2h, const __hip_bfloat16* __restrict__ Y2l,
    const float* __restrict__ bias,
    __hip_bfloat16* __restrict__ D2out,
    __hip_bfloat16* __restrict__ Y3h, __hip_bfloat16* __restrict__ Y3l,
    int nd)
{
    __shared__ __align__(16) short SM[16384];
    const int tid = threadIdx.x;
    if ((int)blockIdx.x >= nd) {
        y_gemm_body(SM, blockIdx.x - nd, blockIdx.y, tid, Y2h, Y2l, Wth, Wtl, bias, Y3h, Y3l);
        return;
    }
    // ---- D2 body ----
    short* Ash0 = SM;         short* Ash1 = SM + 4096;
    short* Bsh0 = SM + 8192;  short* Bsh1 = SM + 12288;
    const int lane = tid & 63;
    const int wv = tid >> 6;
    const int wm = wv >> 1, wn = wv & 1;
    const int bm = blockIdx.x, bn = blockIdx.y;

    const int srow = tid >> 2;
    const int scol = (tid & 3) << 3;
    const short* pAh = (const short*)D1 + (long)(bm * 128 + srow) * WIDTH + scol;
    const short* pBh = (const short*)Wth + (long)(bn * 128 + srow) * WIDTH + scol;
    const long half = 64l * WIDTH;

    floatx4 acc[4][4] = {};
    const int r = lane & 15;
    const int kq = (lane >> 4) << 3;

    for (int kt = 0; kt < WIDTH; kt += 64) {
        __syncthreads();
        async_copy16(pAh + kt,             Ash0 + wv * 512);
        async_copy16(pAh + half + kt,      Ash0 + 2048 + wv * 512);
        async_copy16(pAh + kt + 32,        Ash1 + wv * 512);
        async_copy16(pAh + half + kt + 32, Ash1 + 2048 + wv * 512);
        async_copy16(pBh + kt,             Bsh0 + wv * 512);
        async_copy16(pBh + half + kt,      Bsh0 + 2048 + wv * 512);
        async_copy16(pBh + kt + 32,        Bsh1 + wv * 512);
        async_copy16(pBh + half + kt + 32, Bsh1 + 2048 + wv * 512);
        __syncthreads();
#pragma unroll
        for (int s = 0; s < 2; ++s) {
            const short* As = s ? Ash1 : Ash0;
            const short* Bs = s ? Bsh1 : Bsh0;
            short8 afh[4], bfh[4];
#pragma unroll
            for (int i = 0; i < 4; ++i)
                afh[i] = *reinterpret_cast<const short8*>(&As[(wm * 64 + i * 16 + r) * 32 + kq]);
#pragma unroll
            for (int j = 0; j < 4; ++j)
                bfh[j] = *reinterpret_cast<const short8*>(&Bs[(wn * 64 + j * 16 + r) * 32 + kq]);
#pragma unroll
            for (int i = 0; i < 4; ++i)
#pragma unroll
                for (int j = 0; j < 4; ++j)
                    acc[i][j] = __builtin_amdgcn_mfma_f32_16x16x32_bf16(afh[i], bfh[j], acc[i][j], 0, 0, 0);
        }
    }

    const int r4 = (lane >> 4) << 2;
#pragma unroll
    for (int i = 0; i < 4; ++i)
#pragma unroll
        for (int j = 0; j < 4; ++j) {
            const int col = bn * 128 + wn * 64 + j * 16 + r;
#pragma unroll
            for (int rr = 0; rr < 4; ++rr) {
                const int row = bm * 128 + wm * 64 + i * 16 + r4 + rr;
                float v = acc[i][j][rr];
                const unsigned brow = (unsigned)row / 7u;
                if (!(__bfloat162float(Y2h[(long)brow * WIDTH + col]) > 0.f)) v = 0.f;
                D2out[(long)row * WIDTH + col] = __float2bfloat16(v);
            }
        }
}

// ---------------- fused D3(+PD projection) + heady launch ----------------
// blocks x<nd: D3 with fused PD partial projection (bm=x fastest, bn=y);
// x>=nd && y==0: heady (Y3 projection, 3-pass); else idle.
__global__ __launch_bounds__(256) void d3heady_k(
    const __hip_bfloat16* __restrict__ D2,
    const __hip_bfloat16* __restrict__ Wth, const __hip_bfloat16* __restrict__ Wtl,
    const __hip_bfloat16* __restrict__ Y3h, const __hip_bfloat16* __restrict__ Y3l,
    const __hip_bfloat16* __restrict__ Wch, const __hip_bfloat16* __restrict__ Wcl,
    float* __restrict__ PDpart, float* __restrict__ PY,
    int nd, int Mrows)
{
    __shared__ __align__(16) short SM[26112];  // 52 KB
    const int tid = threadIdx.x;
    const int lane = tid & 63;
    const int wv = tid >> 6;
    const int r = lane & 15;
    const int kq = (lane >> 4) << 3;
    const int r4 = (lane >> 4) << 2;
    const int srow = tid >> 2;
    const int scol = (tid & 3) << 3;
    const long half = 64l * WIDTH;

    if ((int)blockIdx.x >= nd) {
        if (blockIdx.y != 0) return;
        // ---- heady body (3-pass Y3 @ Wcat^T) ----
        short* Ash = SM;          short* Asl = SM + 4096;
        short* Bsh = SM + 8192;   short* Bsl = SM + 9216;
        const int bm = blockIdx.x - nd;
        const short* pAh = (const short*)Y3h + (long)(bm * 128 + srow) * WIDTH + scol;
        const short* pAl = (const short*)Y3l + (long)(bm * 128 + srow) * WIDTH + scol;
        const long boff = (long)srow * WIDTH + scol;
        const short* pBh = (const short*)Wch;  const short* pBl = (const short*)Wcl;

        floatx4 acc[2][2] = {};
        for (int kt = 0; kt < WIDTH; kt += 32) {
            short8 gbh, gbl;
            if (tid < 128) {
                gbh = *reinterpret_cast<const short8*>(pBh + boff + kt);
                gbl = *reinterpret_cast<const short8*>(pBl + boff + kt);
            }
            __syncthreads();
            async_copy16(pAh + kt,        Ash + wv * 512);
            async_copy16(pAh + half + kt, Ash + 2048 + wv * 512);
            async_copy16(pAl + kt,        Asl + wv * 512);
            async_copy16(pAl + half + kt, Asl + 2048 + wv * 512);
            if (tid < 128) {
                *reinterpret_cast<short8*>(&Bsh[srow * 32 + scol]) = gbh;
                *reinterpret_cast<short8*>(&Bsl[srow * 32 + scol]) = gbl;
            }
            __syncthreads();
            short8 afh[2], afl[2], bfh[2], bfl[2];
#pragma unroll
            for (int i = 0; i < 2; ++i) {
                const int ar = (wv * 32 + i * 16 + r) * 32 + kq;
                afh[i] = *reinterpret_cast<const short8*>(&Ash[ar]);
                afl[i] = *reinterpret_cast<const short8*>(&Asl[ar]);
            }
#pragma unroll
            for (int j = 0; j < 2; ++j) {
                const int br = (j * 16 + r) * 32 + kq;
                bfh[j] = *reinterpret_cast<const short8*>(&Bsh[br]);
                bfl[j] = *reinterpret_cast<const short8*>(&Bsl[br]);
            }
#pragma unroll
            for (int i = 0; i < 2; ++i)
#pragma unroll
                for (int j = 0; j < 2; ++j) {
                    acc[i][j] = __builtin_amdgcn_mfma_f32_16x16x32_bf16(afh[i], bfh[j], acc[i][j], 0, 0, 0);
                    acc[i][j] = __builtin_amdgcn_mfma_f32_16x16x32_bf16(afh[i], bfl[j], acc[i][j], 0, 0, 0);
                    acc[i][j] = __builtin_amdgcn_mfma_f32_16x16x32_bf16(afl[i], bfh[j], acc[i][j], 0, 0, 0);
                }
        }
#pragma unroll
        for (int i = 0; i < 2; ++i)
#pragma unroll
            for (int j = 0; j < 2; ++j)
#pragma unroll
                for (int rr = 0; rr < 4; ++rr) {
                    const int row = bm * 128 + wv * 32 + i * 16 + r4 + rr;
                    PY[(long)row * 32 + j * 16 + r] = acc[i][j][rr];
                }
        return;
    }

    // ---- D3 body + fused PD projection ----
    short* Ash0 = SM;         short* Ash1 = SM + 4096;
    short* Bsh0 = SM + 8192;  short* Bsh1 = SM + 12288;
    short* T    = SM;            // 128 x 136
    short* WcH  = SM + 17408;    // 32 x 136
    short* WcL  = SM + 21760;    // 32 x 136

    const int wm = wv >> 1, wn = wv & 1;
    const int bm = blockIdx.x, bn = blockIdx.y;
    const short* pAh = (const short*)D2 + (long)(bm * 128 + srow) * WIDTH + scol;
    const short* pBh = (const short*)Wth + (long)(bn * 128 + srow) * WIDTH + scol;

    floatx4 acc[4][4] = {};
    for (int kt = 0; kt < WIDTH; kt += 64) {
        __syncthreads();
        async_copy16(pAh + kt,             Ash0 + wv * 512);
        async_copy16(pAh + half + kt,      Ash0 + 2048 + wv * 512);
        async_copy16(pAh + kt + 32,        Ash1 + wv * 512);
        async_copy16(pAh + half + kt + 32, Ash1 + 2048 + wv * 512);
        async_copy16(pBh + kt,             Bsh0 + wv * 512);
        async_copy16(pBh + half + kt,      Bsh0 + 2048 + wv * 512);
        async_copy16(pBh + kt + 32,        Bsh1 + wv * 512);
        async_copy16(pBh + half + kt + 32, Bsh1 + 2048 + wv * 512);
        __syncthreads();
#pragma unroll
        for (int s = 0; s < 2; ++s) {
            const short* As = s ? Ash1 : Ash0;
            const short* Bs = s ? Bsh1 : Bsh0;
            short8 afh[4], bfh[4];
#pragma unroll
            for (int i = 0; i < 4; ++i)
                afh[i] = *reinterpret_cast<const short8*>(&As[(wm * 64 + i * 16 + r) * 32 + kq]);
#pragma unroll
            for (int j = 0; j < 4; ++j)
                bfh[j] = *reinterpret_cast<const short8*>(&Bs[(wn * 64 + j * 16 + r) * 32 + kq]);
#pragma unroll
            for (int i = 0; i < 4; ++i)
#pragma unroll
                for (int j = 0; j < 4; ++j)
                    acc[i][j] = __builtin_amdgcn_mfma_f32_16x16x32_bf16(afh[i], bfh[j], acc[i][j], 0, 0, 0);
        }
    }

    __syncthreads();
#pragma unroll
    for (int i = 0; i < 4; ++i)
#pragma unroll
        for (int j = 0; j < 4; ++j) {
            const int coll = wn * 64 + j * 16 + r;
            const int colg = bn * 128 + coll;
#pragma unroll
            for (int rr = 0; rr < 4; ++rr) {
                const int rowl = wm * 64 + i * 16 + r4 + rr;
                const int rowg = bm * 128 + rowl;
                float v = acc[i][j][rr];
                const unsigned brow = (unsigned)rowg / 7u;
                if (!(__bfloat162float(Y3h[(long)brow * WIDTH + colg]) > 0.f)) v = 0.f;
                __hip_bfloat16 hb = __float2bfloat16(v);
                T[rowl * 136 + coll] = *reinterpret_cast<short*>(&hb);
            }
        }
    {
        const int n = tid >> 4, k8 = (tid & 15) * 8;
        const short* wh = (const short*)Wch;
        const short* wl = (const short*)Wcl;
        *reinterpret_cast<short8*>(&WcH[n * 136 + k8]) =
            *reinterpret_cast<const short8*>(wh + n * WIDTH + bn * 128 + k8);
        *reinterpret_cast<short8*>(&WcH[(n + 16) * 136 + k8]) =
            *reinterpret_cast<const short8*>(wh + (n + 16) * WIDTH + bn * 128 + k8);
        *reinterpret_cast<short8*>(&WcL[n * 136 + k8]) =
            *reinterpret_cast<const short8*>(wl + n * WIDTH + bn * 128 + k8);
        *reinterpret_cast<short8*>(&WcL[(n + 16) * 136 + k8]) =
            *reinterpret_cast<const short8*>(wl + (n + 16) * WIDTH + bn * 128 + k8);
    }
    __syncthreads();

    floatx4 accp[2][2] = {};
#pragma unroll
    for (int kk = 0; kk < 128; kk += 32) {
        short8 af[2], bh8[2], bl8[2];
#pragma unroll
        for (int i = 0; i < 2; ++i)
            af[i] = *reinterpret_cast<const short8*>(&T[(wv * 32 + i * 16 + r) * 136 + kk + kq]);
#pragma unroll
        for (int j = 0; j < 2; ++j) {
            bh8[j] = *reinterpret_cast<const short8*>(&WcH[(j * 16 + r) * 136 + kk + kq]);
            bl8[j] = *reinterpret_cast<const short8*>(&WcL[(j * 16 + r) * 136 + kk + kq]);
        }
#pragma unroll
        for (int i = 0; i < 2; ++i)
#pragma unroll
            for (int j = 0; j < 2; ++j) {
                accp[i][j] = __builtin_amdgcn_mfma_f32_16x16x32_bf16(af[i], bh8[j], accp[i][j], 0, 0, 0);
                accp[i][j] = __builtin_amdgcn_mfma_f32_16x16x32_bf16(af[i], bl8[j], accp[i][j], 0, 0, 0);
            }
    }
#pragma unroll
    for (int i = 0; i < 2; ++i)
#pragma unroll
        for (int j = 0; j < 2; ++j)
#pragma unroll
            for (int rr = 0; rr < 4; ++rr) {
                const int rowg = bm * 128 + wv * 32 + i * 16 + r4 + rr;
                PDpart[((long)bn * Mrows + rowg) * 32 + j * 16 + r] = accp[i][j][rr];
            }
}

// ---------------- finalize: 7x7 algebra; reduces PDpart inline ----------------
__device__ __forceinline__ int midx(int rr, int cc) {
    const int i = rr - cc;
    return i * 7 - (i * (i - 1)) / 2 + cc;
}

__global__ __launch_bounds__(64) void finalize_k(
    const float* __restrict__ PY,
    const float* __restrict__ PDpart,   // [8][Mrows][32]
    const float* __restrict__ vel_g,
    const float* __restrict__ acc_g,
    const float* __restrict__ b_ld,
    const float* __restrict__ b_lo,
    float* __restrict__ out,
    int b0, int Mrows)
{
    __shared__ float lval[28];
    __shared__ int gpv[7];
    __shared__ float derl[29 * 7];
    __shared__ float Lm[49], Mm[49], dLt[49], uu[49];
    __shared__ float wvv[7], pv[7], Cv[7], Gv[7], tauv[7], vl[7], ac[7];

    const int bl = blockIdx.x, tid = threadIdx.x;
    const int b = b0 + bl;
    if (tid < 28) {
        float s = PY[(long)bl * 32 + tid];
        if (tid < 7) {
            s += b_ld[tid];
            gpv[tid] = s > 0.f;
            lval[tid] = s > 0.f ? s : 0.f;
        } else {
            lval[tid] = s + b_lo[tid - 7];
        }
    }
    if (tid >= 28 && tid < 35) {
        vl[tid - 28] = vel_g[b * 7 + tid - 28];
        ac[tid - 28] = acc_g[b * 7 + tid - 28];
    }
    __syncthreads();
    for (int idx = tid; idx < 203; idx += 64) {
        const int m = idx / 7, d = idx % 7;
        float v = 0.f;
#pragma unroll
        for (int p = 0; p < 8; ++p)
            v += PDpart[((long)p * Mrows + bl * 7 + d) * 32 + m];
        if (m < 7 && !gpv[m]) v = 0.f;
        derl[m * 7 + d] = v;
    }
    __syncthreads();
    if (tid < 49) {
        const int rr = tid / 7, cc = tid % 7;
        Lm[tid] = (rr >= cc) ? lval[midx(rr, cc)] : 0.f;
    }
    __syncthreads();
    if (tid < 49) {
        const int rr = tid / 7, cc = tid % 7;
        float s = 0.f;
        for (int k = 0; k < 7; ++k) s += Lm[rr * 7 + k] * Lm[cc * 7 + k];
        if (rr == cc) s += 1e-5f;
        Mm[tid] = s;
        float t = 0.f;
        if (rr >= cc) {
            const int m = midx(rr, cc);
            for (int d = 0; d < 7; ++d) t += derl[m * 7 + d] * vl[d];
        }
        dLt[tid] = t;
        float u = 0.f;
        for (int r2 = cc; r2 < 7; ++r2) u += vl[r2] * derl[midx(r2, cc) * 7 + rr];
        uu[tid] = u;
    } else if (tid >= 49 && tid < 56) {
        const int j = tid - 49;
        float s = 0.f;
        for (int r2 = 0; r2 < 7; ++r2) s += Lm[r2 * 7 + j] * vl[r2];
        wvv[j] = s;
    }
    __syncthreads();
    if (tid < 7) {
        float s = 0.f;
        for (int r2 = 0; r2 < 7; ++r2) s += dLt[r2 * 7 + tid] * vl[r2];
        pv[tid] = s;
    }
    __syncthreads();
    if (tid < 7) {
        float s = 0.f, q = 0.f, md = 0.f;
        for (int c = 0; c < 7; ++c) {
            s += Lm[tid * 7 + c] * pv[c] + dLt[tid * 7 + c] * wvv[c];
            q += uu[tid * 7 + c] * wvv[c];
            md += Mm[tid * 7 + c] * ac[c];
        }
        Cv[tid] = s - q;
        Gv[tid] = derl[28 * 7 + tid];
        tauv[tid] = md + Cv[tid] + Gv[tid];
    }
    __syncthreads();
    if (tid < 49) out[57344 + (long)b * 49 + tid] = Mm[tid];
    if (tid < 7) {
        out[(long)b * 7 + tid] = tauv[tid];
        out[458752 + (long)b * 7 + tid] = Cv[tid];
        out[516096 + (long)b * 7 + tid] = Gv[tid];
    }
}

extern "C" void kernel_launch(void* const* d_in, const int* in_sizes, int n_in,
                              void* d_out, int out_size, void* d_ws, size_t ws_size,
                              hipStream_t stream)
{
    const float* state = (const float*)d_in[0];
    const float* vel   = (const float*)d_in[1];
    const float* accel = (const float*)d_in[2];
    const float* W_in  = (const float*)d_in[3];
    const float* b_in  = (const float*)d_in[4];
    const float* W_h   = (const float*)d_in[5];
    const float* b_h   = (const float*)d_in[6];
    const float* W_g   = (const float*)d_in[7];
    /* d_in[8] = b_g unused */
    const float* W_ld  = (const float*)d_in[9];
    const float* b_ld  = (const float*)d_in[10];
    const float* W_lo  = (const float*)d_in[11];
    const float* b_lo  = (const float*)d_in[12];
    float* outp = (float*)d_out;

    char* ws = (char*)d_ws;
    __hip_bfloat16* Wth = (__hip_bfloat16*)ws; ws += (size_t)WIDTH * WIDTH * 2;
    __hip_bfloat16* Wtl = (__hip_bfloat16*)ws; ws += (size_t)WIDTH * WIDTH * 2;
    __hip_bfloat16* Wch = (__hip_bfloat16*)ws; ws += 32 * WIDTH * 2;
    __hip_bfloat16* Wcl = (__hip_bfloat16*)ws; ws += 32 * WIDTH * 2;
    const size_t fixed = (size_t)(ws - (char*)d_ws);

    // per-sample: Y 4*2048 + D1 14336 + D2 14336 + PY 128 = 37120 B
    int CH = 128;
    for (int cand = 8192; cand >= 128; cand >>= 1) {
        size_t need = fixed + (size_t)cand * 37120;
        if (need <= ws_size) { CH = cand; break; }
    }
    const int NCH = BATCH / CH;

    const size_t YB = (size_t)CH * WIDTH * 2;
    const size_t DB = (size_t)CH * 7 * WIDTH * 2;
    __hip_bfloat16* Yah = (__hip_bfloat16*)ws; ws += YB;   // Y1 -> Y3
    __hip_bfloat16* Yal = (__hip_bfloat16*)ws; ws += YB;
    __hip_bfloat16* Ybh = (__hip_bfloat16*)ws; ws += YB;   // Y2
    __hip_bfloat16* Ybl = (__hip_bfloat16*)ws; ws += YB;
    __hip_bfloat16* Dah = (__hip_bfloat16*)ws; ws += DB;   // D1 (aliased as PDpart in D3 phase)
    __hip_bfloat16* Dbh = (__hip_bfloat16*)ws; ws += DB;   // D2
    float* PY = (float*)ws; ws += (size_t)CH * 32 * 4;
    float* PDpart = (float*)Dah;   // 8*(7*CH)*32*4 = CH*7168 B <= DB

    const int Mrows = CH * 7;
    const int nd = Mrows / 128;
    const int ny = CH / 128;

    transpose_k<<<dim3(32, 32), dim3(256), 0, stream>>>(W_h, Wth, Wtl);
    buildwcat_k<<<dim3(128), dim3(256), 0, stream>>>(W_ld, W_lo, W_g, Wch, Wcl);

    for (int c = 0; c < NCH; ++c) {
        prep_k<<<dim3(CH), dim3(256), 0, stream>>>(state + (size_t)c * CH * 7, W_in, b_in,
                                                   Yah, Yal, Dah);
        gemm_y<<<dim3(ny, 8), dim3(256), 0, stream>>>(
            Yah, Yal, Wth, Wtl, b_h, Ybh, Ybl);                                // Y2
        d2y3_k<<<dim3(nd + ny, 8), dim3(256), 0, stream>>>(
            Dah, Wth, Wtl, Ybh, Ybl, b_h, Dbh, Yah, Yal, nd);                  // D2 + Y3
        d3heady_k<<<dim3(nd + ny, 8), dim3(256), 0, stream>>>(
            Dbh, Wth, Wtl, Yah, Yal, Wch, Wcl, PDpart, PY, nd, Mrows);         // D3+PD + heady
        finalize_k<<<dim3(CH), dim3(64), 0, stream>>>(PY, PDpart, vel, accel, b_ld, b_lo,
                                                      outp, c * CH, Mrows);
    }
    (void)in_sizes; (void)n_in; (void)out_size;
}